// Round 1
// baseline (5298.609 us; speedup 1.0000x reference)
//
#include <hip/hip_runtime.h>

#define DIM 2560
#define T_TOK 2048
#define NHEADS 20
#define HD 128
#define HID_E 6912
#define SHID_E 3584

typedef short bf16x8 __attribute__((ext_vector_type(8)));
typedef float f32x4 __attribute__((ext_vector_type(4)));
typedef unsigned short u16x8 __attribute__((ext_vector_type(8)));

#define MFMA16(a, b, c) __builtin_amdgcn_mfma_f32_16x16x32_bf16((a), (b), (c), 0, 0, 0)

__device__ inline unsigned short f2bf(float f) {
  unsigned x = __builtin_bit_cast(unsigned, f);
  x += 0x7fffu + ((x >> 16) & 1u);           // RNE
  return (unsigned short)(x >> 16);
}
__device__ inline float bf2f(unsigned short u) {
  unsigned v = ((unsigned)u) << 16;
  return __builtin_bit_cast(float, v);
}
__device__ inline float wave_sum(float v) {
#pragma unroll
  for (int off = 32; off > 0; off >>= 1) v += __shfl_down(v, off, 64);
  return v;
}
__device__ inline float wave_max(float v) {
#pragma unroll
  for (int off = 32; off > 0; off >>= 1) v = fmaxf(v, __shfl_down(v, off, 64));
  return v;
}

// ---------------- tiny kernels ----------------

__global__ __launch_bounds__(256) void silu_k(const float* __restrict__ t,
                                              float* __restrict__ ss) {
  int i = blockIdx.x * 256 + threadIdx.x;
  if (i < DIM) {
    float v = t[i];
    ss[i] = v / (1.f + expf(-v));
  }
}

// mod[j] = dot(silu(temb), adaln_w[j]) + adaln_b[j]; one wave per output
__global__ __launch_bounds__(256) void adaln_gemv(const float* __restrict__ ss,
                                                  const float* __restrict__ W,
                                                  const float* __restrict__ bias,
                                                  float* __restrict__ mod) {
  const int lane = threadIdx.x & 63;
  const int j = blockIdx.x * 4 + (threadIdx.x >> 6);
  const float* wr = W + (size_t)j * DIM;
  float p = 0.f;
  for (int i = lane; i < 640; i += 64) {
    float4 w = *(const float4*)(wr + i * 4);
    float4 x = *(const float4*)(ss + i * 4);
    p += w.x * x.x + w.y * x.y + w.z * x.z + w.w * x.w;
  }
  p = wave_sum(p);
  if (lane == 0) mod[j] = p + bias[j];
}

// LN (no affine) then *(1+scale)+shift, write bf16 hi+lo. One block per row.
__global__ __launch_bounds__(256) void ln_mod(const float* __restrict__ x,
                                              const float* __restrict__ shift,
                                              const float* __restrict__ scale,
                                              unsigned short* __restrict__ hi,
                                              unsigned short* __restrict__ lo) {
  __shared__ float rbuf[8];
  const int t = blockIdx.x, tid = threadIdx.x, lane = tid & 63, wid = tid >> 6;
  const float* xr = x + (size_t)t * DIM;
  float s = 0.f, sq = 0.f;
  for (int i = tid; i < 640; i += 256) {
    float4 v = *(const float4*)(xr + i * 4);
    s += v.x + v.y + v.z + v.w;
    sq += v.x * v.x + v.y * v.y + v.z * v.z + v.w * v.w;
  }
  s = wave_sum(s);
  sq = wave_sum(sq);
  if (lane == 0) {
    rbuf[wid] = s;
    rbuf[4 + wid] = sq;
  }
  __syncthreads();
  float S = rbuf[0] + rbuf[1] + rbuf[2] + rbuf[3];
  float SQ = rbuf[4] + rbuf[5] + rbuf[6] + rbuf[7];
  float mean = S * (1.f / DIM);
  float rs = rsqrtf(SQ * (1.f / DIM) - mean * mean + 1e-6f);
  for (int i = tid; i < 640; i += 256) {
    float4 v = *(const float4*)(xr + i * 4);
    float4 sc4 = *(const float4*)(scale + i * 4);
    float4 sh4 = *(const float4*)(shift + i * 4);
    float y0 = (v.x - mean) * rs * (1.f + sc4.x) + sh4.x;
    float y1 = (v.y - mean) * rs * (1.f + sc4.y) + sh4.y;
    float y2 = (v.z - mean) * rs * (1.f + sc4.z) + sh4.z;
    float y3 = (v.w - mean) * rs * (1.f + sc4.w) + sh4.w;
    ushort4 uh, ul;
    uh.x = f2bf(y0); ul.x = f2bf(y0 - bf2f(uh.x));
    uh.y = f2bf(y1); ul.y = f2bf(y1 - bf2f(uh.y));
    uh.z = f2bf(y2); ul.z = f2bf(y2 - bf2f(uh.z));
    uh.w = f2bf(y3); ul.w = f2bf(y3 - bf2f(uh.w));
    *(ushort4*)&hi[(size_t)t * DIM + i * 4] = uh;
    *(ushort4*)&lo[(size_t)t * DIM + i * 4] = ul;
  }
}

// RMSNorm(q),(k) over full 2560 + weight + RoPE -> q_f32, krope_f32
__global__ __launch_bounds__(256) void rmsrope(const float* __restrict__ qkv,
                                               const float* __restrict__ qn,
                                               const float* __restrict__ kn,
                                               const float* __restrict__ rope,
                                               float* __restrict__ qf,
                                               float* __restrict__ kr) {
  __shared__ float rbuf[8];
  const int t = blockIdx.x, tid = threadIdx.x, lane = tid & 63, wid = tid >> 6;
  const float* row = qkv + (size_t)t * 7680;
  float sq = 0.f, sk = 0.f;
  for (int i = tid; i < 640; i += 256) {
    float4 qv = *(const float4*)(row + i * 4);
    float4 kv = *(const float4*)(row + DIM + i * 4);
    sq += qv.x * qv.x + qv.y * qv.y + qv.z * qv.z + qv.w * qv.w;
    sk += kv.x * kv.x + kv.y * kv.y + kv.z * kv.z + kv.w * kv.w;
  }
  sq = wave_sum(sq);
  sk = wave_sum(sk);
  if (lane == 0) {
    rbuf[wid] = sq;
    rbuf[4 + wid] = sk;
  }
  __syncthreads();
  float SQ = rbuf[0] + rbuf[1] + rbuf[2] + rbuf[3];
  float SK = rbuf[4] + rbuf[5] + rbuf[6] + rbuf[7];
  float rq = rsqrtf(SQ * (1.f / DIM) + 1e-6f);
  float rk = rsqrtf(SK * (1.f / DIM) + 1e-6f);
  for (int pp = tid; pp < 1280; pp += 256) {
    int c = pp * 2;
    float2 q2 = *(const float2*)(row + c);
    float2 k2 = *(const float2*)(row + DIM + c);
    float4 rr = *(const float4*)(rope + (size_t)t * 256 + (pp & 63) * 4);
    float qe = q2.x * rq * qn[c], qo = q2.y * rq * qn[c + 1];
    float ke = k2.x * rk * kn[c], ko = k2.y * rk * kn[c + 1];
    float2 qo2, ko2;
    qo2.x = rr.x * qe + rr.y * qo;  // [c, -s]
    qo2.y = rr.z * qe + rr.w * qo;  // [s,  c]
    ko2.x = rr.x * ke + rr.y * ko;
    ko2.y = rr.z * ke + rr.w * ko;
    *(float2*)(qf + (size_t)t * DIM + c) = qo2;
    *(float2*)(kr + (size_t)t * DIM + c) = ko2;
  }
}

// [2048][2560] -> [2560][2048]
__global__ void transpose_k(const float* __restrict__ in, float* __restrict__ outp) {
  __shared__ float tile[32][33];
  const int bx = blockIdx.x * 32;  // input col base
  const int by = blockIdx.y * 32;  // input row base
  const int tx = threadIdx.x, ty = threadIdx.y;
  for (int j = ty; j < 32; j += 8)
    tile[j][tx] = in[(size_t)(by + j) * DIM + bx + tx];
  __syncthreads();
  for (int j = ty; j < 32; j += 8)
    outp[(size_t)(bx + j) * T_TOK + by + tx] = tile[tx][j];
}

// f32 attention, 4 q-rows per block, full score row in LDS, two-pass softmax
__global__ __launch_bounds__(256) void attn_k(const float* __restrict__ qf,
                                              const float* __restrict__ ktp,
                                              const float* __restrict__ qkv,
                                              unsigned short* __restrict__ ohi,
                                              unsigned short* __restrict__ olo) {
  __shared__ float sc[4][2048];
  __shared__ float qs[4][128];
  __shared__ float red[4][4];
  __shared__ float fmx[4], fsm[4];
  const int tid = threadIdx.x, lane = tid & 63, wid = tid >> 6;
  const int h = blockIdx.y;
  const int t0 = blockIdx.x * 4;

  for (int i = tid; i < 512; i += 256)
    qs[i >> 7][i & 127] = qf[(size_t)(t0 + (i >> 7)) * DIM + h * HD + (i & 127)];
  __syncthreads();

  const float* kbase = ktp + (size_t)h * HD * T_TOK;
  float s[4][8];
#pragma unroll
  for (int r = 0; r < 4; ++r) {
#pragma unroll
    for (int j = 0; j < 8; ++j) s[r][j] = 0.f;
  }
  for (int d4 = 0; d4 < 32; ++d4) {
    float q0[4], q1[4], q2[4], q3[4];
    *(float4*)q0 = *(const float4*)&qs[0][d4 * 4];
    *(float4*)q1 = *(const float4*)&qs[1][d4 * 4];
    *(float4*)q2 = *(const float4*)&qs[2][d4 * 4];
    *(float4*)q3 = *(const float4*)&qs[3][d4 * 4];
    const float* krow = kbase + (size_t)d4 * 4 * T_TOK + tid;
#pragma unroll
    for (int dd = 0; dd < 4; ++dd) {
#pragma unroll
      for (int j = 0; j < 8; ++j) {
        float kv = krow[(size_t)dd * T_TOK + 256 * j];
        s[0][j] += q0[dd] * kv;
        s[1][j] += q1[dd] * kv;
        s[2][j] += q2[dd] * kv;
        s[3][j] += q3[dd] * kv;
      }
    }
  }
  const float scl = 0.08838834764831845f;  // 1/sqrt(128)
#pragma unroll
  for (int j = 0; j < 8; ++j) {
    int kk = tid + 256 * j;
    sc[0][kk] = s[0][j] * scl;
    sc[1][kk] = s[1][j] * scl;
    sc[2][kk] = s[2][j] * scl;
    sc[3][kk] = s[3][j] * scl;
  }
  __syncthreads();

  float lm[4] = {-3e38f, -3e38f, -3e38f, -3e38f};
  for (int kk = tid; kk < T_TOK; kk += 256) {
#pragma unroll
    for (int r = 0; r < 4; ++r) lm[r] = fmaxf(lm[r], sc[r][kk]);
  }
#pragma unroll
  for (int r = 0; r < 4; ++r) {
    float v = wave_max(lm[r]);
    if (lane == 0) red[wid][r] = v;
  }
  __syncthreads();
  if (tid < 4)
    fmx[tid] = fmaxf(fmaxf(red[0][tid], red[1][tid]), fmaxf(red[2][tid], red[3][tid]));
  __syncthreads();

  float ls[4] = {0.f, 0.f, 0.f, 0.f};
  for (int kk = tid; kk < T_TOK; kk += 256) {
#pragma unroll
    for (int r = 0; r < 4; ++r) {
      float e = expf(sc[r][kk] - fmx[r]);
      sc[r][kk] = e;
      ls[r] += e;
    }
  }
#pragma unroll
  for (int r = 0; r < 4; ++r) {
    float v = wave_sum(ls[r]);
    if (lane == 0) red[wid][r] = v;
  }
  __syncthreads();
  if (tid < 4) fsm[tid] = red[0][tid] + red[1][tid] + red[2][tid] + red[3][tid];
  __syncthreads();

  const int d = tid & 127, g = tid >> 7;
  const int r0 = 2 * g, r1 = r0 + 1;
  const float* vp = qkv + 2 * DIM + (size_t)h * HD + d;
  float a0 = 0.f, b0 = 0.f, a1 = 0.f, b1 = 0.f;
  for (int k4 = 0; k4 < 512; k4 += 2) {
    float4 pA0 = *(const float4*)&sc[r0][k4 * 4];
    float4 pB0 = *(const float4*)&sc[r1][k4 * 4];
    float4 pA1 = *(const float4*)&sc[r0][k4 * 4 + 4];
    float4 pB1 = *(const float4*)&sc[r1][k4 * 4 + 4];
    const float* vb = vp + (size_t)k4 * 4 * 7680;
    float v0 = vb[0], v1 = vb[7680], v2 = vb[2 * 7680], v3 = vb[3 * 7680];
    float v4 = vb[4 * 7680], v5 = vb[5 * 7680], v6 = vb[6 * 7680], v7 = vb[7 * 7680];
    a0 += pA0.x * v0 + pA0.y * v1 + pA0.z * v2 + pA0.w * v3;
    b0 += pA1.x * v4 + pA1.y * v5 + pA1.z * v6 + pA1.w * v7;
    a1 += pB0.x * v0 + pB0.y * v1 + pB0.z * v2 + pB0.w * v3;
    b1 += pB1.x * v4 + pB1.y * v5 + pB1.z * v6 + pB1.w * v7;
  }
  float o0 = (a0 + b0) / fsm[r0];
  float o1 = (a1 + b1) / fsm[r1];
  size_t i0 = (size_t)(t0 + r0) * DIM + h * HD + d;
  size_t i1 = (size_t)(t0 + r1) * DIM + h * HD + d;
  unsigned short hb;
  hb = f2bf(o0); ohi[i0] = hb; olo[i0] = f2bf(o0 - bf2f(hb));
  hb = f2bf(o1); ohi[i1] = hb; olo[i1] = f2bf(o1 - bf2f(hb));
}

// LN2 + modulate -> nh2 bf16, plus f32 routing (softmax over 4, top-2, unnormalized)
__global__ __launch_bounds__(256) void ln2_route(const float* __restrict__ x,
                                                 const float* __restrict__ shift,
                                                 const float* __restrict__ scale,
                                                 const float* __restrict__ gw,
                                                 unsigned short* __restrict__ nh2,
                                                 float* __restrict__ wd) {
  __shared__ float rbuf[8];
  __shared__ float gbuf[4][4];
  const int t = blockIdx.x, tid = threadIdx.x, lane = tid & 63, wid = tid >> 6;
  const float* xr = x + (size_t)t * DIM;
  float s = 0.f, sq = 0.f;
  for (int i = tid; i < 640; i += 256) {
    float4 v = *(const float4*)(xr + i * 4);
    s += v.x + v.y + v.z + v.w;
    sq += v.x * v.x + v.y * v.y + v.z * v.z + v.w * v.w;
  }
  s = wave_sum(s);
  sq = wave_sum(sq);
  if (lane == 0) {
    rbuf[wid] = s;
    rbuf[4 + wid] = sq;
  }
  __syncthreads();
  float S = rbuf[0] + rbuf[1] + rbuf[2] + rbuf[3];
  float SQ = rbuf[4] + rbuf[5] + rbuf[6] + rbuf[7];
  float mean = S * (1.f / DIM);
  float rs = rsqrtf(SQ * (1.f / DIM) - mean * mean + 1e-6f);
  float g0 = 0.f, g1 = 0.f, g2 = 0.f, g3 = 0.f;
  for (int i = tid; i < 640; i += 256) {
    float4 v = *(const float4*)(xr + i * 4);
    float4 sc4 = *(const float4*)(scale + i * 4);
    float4 sh4 = *(const float4*)(shift + i * 4);
    float y0 = (v.x - mean) * rs * (1.f + sc4.x) + sh4.x;
    float y1 = (v.y - mean) * rs * (1.f + sc4.y) + sh4.y;
    float y2 = (v.z - mean) * rs * (1.f + sc4.z) + sh4.z;
    float y3 = (v.w - mean) * rs * (1.f + sc4.w) + sh4.w;
    ushort4 u;
    u.x = f2bf(y0); u.y = f2bf(y1); u.z = f2bf(y2); u.w = f2bf(y3);
    *(ushort4*)&nh2[(size_t)t * DIM + i * 4] = u;
    float4 w0 = *(const float4*)(gw + i * 4);
    float4 w1 = *(const float4*)(gw + DIM + i * 4);
    float4 w2 = *(const float4*)(gw + 2 * DIM + i * 4);
    float4 w3 = *(const float4*)(gw + 3 * DIM + i * 4);
    g0 += y0 * w0.x + y1 * w0.y + y2 * w0.z + y3 * w0.w;
    g1 += y0 * w1.x + y1 * w1.y + y2 * w1.z + y3 * w1.w;
    g2 += y0 * w2.x + y1 * w2.y + y2 * w2.z + y3 * w2.w;
    g3 += y0 * w3.x + y1 * w3.y + y2 * w3.z + y3 * w3.w;
  }
  g0 = wave_sum(g0);
  g1 = wave_sum(g1);
  g2 = wave_sum(g2);
  g3 = wave_sum(g3);
  if (lane == 0) {
    gbuf[wid][0] = g0; gbuf[wid][1] = g1; gbuf[wid][2] = g2; gbuf[wid][3] = g3;
  }
  __syncthreads();
  if (tid == 0) {
    float l[4];
#pragma unroll
    for (int e = 0; e < 4; ++e) l[e] = gbuf[0][e] + gbuf[1][e] + gbuf[2][e] + gbuf[3][e];
    float mx = fmaxf(fmaxf(l[0], l[1]), fmaxf(l[2], l[3]));
    float ex[4], sum = 0.f;
#pragma unroll
    for (int e = 0; e < 4; ++e) { ex[e] = expf(l[e] - mx); sum += ex[e]; }
    float p[4];
#pragma unroll
    for (int e = 0; e < 4; ++e) p[e] = ex[e] / sum;
    int i1 = 0;
    for (int e = 1; e < 4; ++e)
      if (p[e] > p[i1]) i1 = e;
    int i2 = -1;
    for (int e = 0; e < 4; ++e) {
      if (e == i1) continue;
      if (i2 < 0 || p[e] > p[i2]) i2 = e;
    }
    float w[4] = {0.f, 0.f, 0.f, 0.f};
    w[i1] = p[i1];
    w[i2] = p[i2];
    *(float4*)&wd[(size_t)t * 4] = make_float4(w[0], w[1], w[2], w[3]);
  }
}

__global__ __launch_bounds__(256) void swiglu_mul(const float* __restrict__ h1,
                                                  const float* __restrict__ h3,
                                                  unsigned short* __restrict__ outp,
                                                  int n4) {
  const int stride = gridDim.x * 256;
  for (int i = blockIdx.x * 256 + threadIdx.x; i < n4; i += stride) {
    float4 a = *(const float4*)(h1 + (size_t)i * 4);
    float4 b = *(const float4*)(h3 + (size_t)i * 4);
    float y0 = a.x / (1.f + expf(-a.x)) * b.x;
    float y1 = a.y / (1.f + expf(-a.y)) * b.y;
    float y2 = a.z / (1.f + expf(-a.z)) * b.z;
    float y3 = a.w / (1.f + expf(-a.w)) * b.w;
    ushort4 u;
    u.x = f2bf(y0); u.y = f2bf(y1); u.z = f2bf(y2); u.w = f2bf(y3);
    *(ushort4*)&outp[(size_t)i * 4] = u;
  }
}

// ---------------- GEMM: C[M,N] = A[M,K](bf16 hi[+lo]) @ B[N,K](f32->bf16)^T ----------------
// 128x128 tile, BK=32, 4 waves (2x2 of 64x64), mfma_f32_16x16x32_bf16.
// LDS slot-swizzle: 16B chunk c of row r stored at slot c ^ ((r>>1)&3).
// EPI: 0 = (+bias) store f32    1 = h2 = aux0[n]*(v+bias[n]) + aux1[idx]
//      2 = C[idx] += aux0[m*4]*v (MoE accumulate)   3 = C = aux0[n]*(aux2+v) + aux1
template <int SPLIT, int EPI>
__global__ __launch_bounds__(256) void gemm128(
    const unsigned short* __restrict__ Ah, const unsigned short* __restrict__ Al,
    const float* __restrict__ B, const float* __restrict__ bias,
    float* __restrict__ C, const float* __restrict__ aux0,
    const float* __restrict__ aux1, const float* __restrict__ aux2,
    int M, int N, int K) {
  __shared__ unsigned short smem[(SPLIT ? 4 : 2) * 4096];
  unsigned short* sAh = smem;
  unsigned short* sAl = smem + (SPLIT ? 4096 : 0);
  unsigned short* sBh = smem + (SPLIT ? 8192 : 4096);
  unsigned short* sBl = smem + (SPLIT ? 12288 : 0);
  const int tid = threadIdx.x;
  const int lane = tid & 63;
  const int wid = tid >> 6;
  const int m0 = blockIdx.y * 128, n0 = blockIdx.x * 128;
  const int wm = (wid >> 1) * 64, wn = (wid & 1) * 64;
  const int fr = lane & 15, fc = lane >> 4;
  const int sr = tid >> 1, sh = tid & 1;
  const int swz = (sr >> 1) & 3;
  const int sl0 = (2 * sh + 0) ^ swz;
  const int sl1 = (2 * sh + 1) ^ swz;

  f32x4 acc[4][4];
  f32x4 zero = {0.f, 0.f, 0.f, 0.f};
#pragma unroll
  for (int i = 0; i < 4; ++i) {
#pragma unroll
    for (int j = 0; j < 4; ++j) acc[i][j] = zero;
  }

  const size_t arow = (size_t)(m0 + sr) * K;
  const size_t brow = (size_t)(n0 + sr) * K;

  for (int kt = 0; kt < K; kt += 32) {
    if (kt) __syncthreads();
    {  // A staging (bf16 copy)
      const unsigned short* ga = Ah + arow + kt + sh * 16;
      uint4 v0 = *(const uint4*)ga;
      uint4 v1 = *(const uint4*)(ga + 8);
      *(uint4*)&sAh[sr * 32 + sl0 * 8] = v0;
      *(uint4*)&sAh[sr * 32 + sl1 * 8] = v1;
      if constexpr (SPLIT) {
        const unsigned short* gal = Al + arow + kt + sh * 16;
        uint4 w0 = *(const uint4*)gal;
        uint4 w1 = *(const uint4*)(gal + 8);
        *(uint4*)&sAl[sr * 32 + sl0 * 8] = w0;
        *(uint4*)&sAl[sr * 32 + sl1 * 8] = w1;
      }
    }
    {  // B staging (f32 -> bf16 [+lo])
      const float* gb = B + brow + kt + sh * 16;
      float bv[16];
      *(float4*)&bv[0] = *(const float4*)gb;
      *(float4*)&bv[4] = *(const float4*)(gb + 4);
      *(float4*)&bv[8] = *(const float4*)(gb + 8);
      *(float4*)&bv[12] = *(const float4*)(gb + 12);
      u16x8 h0, h1;
#pragma unroll
      for (int j = 0; j < 8; ++j) {
        h0[j] = f2bf(bv[j]);
        h1[j] = f2bf(bv[8 + j]);
      }
      *(u16x8*)&sBh[sr * 32 + sl0 * 8] = h0;
      *(u16x8*)&sBh[sr * 32 + sl1 * 8] = h1;
      if constexpr (SPLIT) {
        u16x8 l0, l1;
#pragma unroll
        for (int j = 0; j < 8; ++j) {
          l0[j] = f2bf(bv[j] - bf2f((unsigned short)h0[j]));
          l1[j] = f2bf(bv[8 + j] - bf2f((unsigned short)h1[j]));
        }
        *(u16x8*)&sBl[sr * 32 + sl0 * 8] = l0;
        *(u16x8*)&sBl[sr * 32 + sl1 * 8] = l1;
      }
    }
    __syncthreads();
    bf16x8 a[4], b[4];
#pragma unroll
    for (int mi = 0; mi < 4; ++mi) {
      int r = wm + mi * 16 + fr;
      a[mi] = *(const bf16x8*)&sAh[r * 32 + (fc ^ ((r >> 1) & 3)) * 8];
    }
#pragma unroll
    for (int ni = 0; ni < 4; ++ni) {
      int r = wn + ni * 16 + fr;
      b[ni] = *(const bf16x8*)&sBh[r * 32 + (fc ^ ((r >> 1) & 3)) * 8];
    }
#pragma unroll
    for (int mi = 0; mi < 4; ++mi) {
#pragma unroll
      for (int ni = 0; ni < 4; ++ni) acc[mi][ni] = MFMA16(a[mi], b[ni], acc[mi][ni]);
    }
    if constexpr (SPLIT) {
      bf16x8 al[4], bl[4];
#pragma unroll
      for (int mi = 0; mi < 4; ++mi) {
        int r = wm + mi * 16 + fr;
        al[mi] = *(const bf16x8*)&sAl[r * 32 + (fc ^ ((r >> 1) & 3)) * 8];
      }
#pragma unroll
      for (int ni = 0; ni < 4; ++ni) {
        int r = wn + ni * 16 + fr;
        bl[ni] = *(const bf16x8*)&sBl[r * 32 + (fc ^ ((r >> 1) & 3)) * 8];
      }
#pragma unroll
      for (int mi = 0; mi < 4; ++mi) {
#pragma unroll
        for (int ni = 0; ni < 4; ++ni) {
          acc[mi][ni] = MFMA16(a[mi], bl[ni], acc[mi][ni]);
          acc[mi][ni] = MFMA16(al[mi], b[ni], acc[mi][ni]);
        }
      }
    }
  }
  // epilogue: D[row=(lane>>4)*4+i][col=lane&15] per 16x16 frag
#pragma unroll
  for (int mi = 0; mi < 4; ++mi) {
#pragma unroll
    for (int ni = 0; ni < 4; ++ni) {
      const int n = n0 + wn + ni * 16 + fr;
      const int mb = m0 + wm + mi * 16 + fc * 4;
#pragma unroll
      for (int i = 0; i < 4; ++i) {
        const int m = mb + i;
        float v = acc[mi][ni][i];
        const size_t idx = (size_t)m * N + n;
        if constexpr (EPI == 0) {
          if (bias) v += bias[n];
          C[idx] = v;
        } else if constexpr (EPI == 1) {
          C[idx] = aux0[n] * (v + bias[n]) + aux1[idx];
        } else if constexpr (EPI == 2) {
          C[idx] += aux0[(size_t)m * 4] * v;
        } else {
          C[idx] = aux0[n] * (aux2[idx] + v) + aux1[idx];
        }
      }
    }
  }
}

// ---------------- host ----------------

extern "C" void kernel_launch(void* const* d_in, const int* in_sizes, int n_in,
                              void* d_out, int out_size, void* d_ws, size_t ws_size,
                              hipStream_t stream) {
  (void)in_sizes; (void)n_in; (void)out_size; (void)ws_size;
  const float* hs = (const float*)d_in[0];
  const float* temb = (const float*)d_in[1];
  const float* rope = (const float*)d_in[2];
  const float* adaw = (const float*)d_in[3];
  const float* adab = (const float*)d_in[4];
  const float* qkvw = (const float*)d_in[5];
  const float* qkvb = (const float*)d_in[6];
  const float* qnw = (const float*)d_in[7];
  const float* knw = (const float*)d_in[8];
  const float* outw = (const float*)d_in[9];
  const float* outb = (const float*)d_in[10];
  const float* gatew = (const float*)d_in[11];
  const float* ew1 = (const float*)d_in[12];
  const float* ew2 = (const float*)d_in[13];
  const float* ew3 = (const float*)d_in[14];
  const float* sw1 = (const float*)d_in[15];
  const float* sw2 = (const float*)d_in[16];
  const float* sw3 = (const float*)d_in[17];
  float* out = (float*)d_out;
  char* ws = (char*)d_ws;

  size_t off = 0;
  auto give = [&](size_t nbytes) {
    size_t r = off;
    off += (nbytes + 255) & ~(size_t)255;
    return r;
  };
  const size_t T = T_TOK, D = DIM;
  size_t o_mod = give(15360 * 4);
  size_t o_ss = give(D * 4);
  size_t o_wd = give(T * 4 * 4);
  size_t o_nh = give(T * D * 2);     // nh_hi; later nh2_bf16
  size_t o_nhlo = give(T * D * 2);   // nh_lo
  size_t o_qkv = give(T * 7680 * 4); // qkv f32; later h1 (56.6MB <= 62.9MB)
  size_t o_qf = give(T * D * 4);     // q rope'd; (qf..kt 63MB) later h3
  size_t o_krope = give(T * D * 4);
  size_t o_kt = give(T * D * 4);
  size_t o_ohi = give(T * D * 2);
  size_t o_olo = give(T * D * 2);
  size_t o_h2 = give(T * D * 4);
  size_t o_y = give(T * D * 4);
  size_t o_hmid = give(T * HID_E * 2);

  float* mod = (float*)(ws + o_mod);
  float* ss = (float*)(ws + o_ss);
  float* wd = (float*)(ws + o_wd);
  unsigned short* nh_hi = (unsigned short*)(ws + o_nh);
  unsigned short* nh_lo = (unsigned short*)(ws + o_nhlo);
  float* qkvbuf = (float*)(ws + o_qkv);
  float* qf = (float*)(ws + o_qf);
  float* krope = (float*)(ws + o_krope);
  float* ktb = (float*)(ws + o_kt);
  unsigned short* ohi = (unsigned short*)(ws + o_ohi);
  unsigned short* olo = (unsigned short*)(ws + o_olo);
  float* h2 = (float*)(ws + o_h2);
  float* ybuf = (float*)(ws + o_y);
  unsigned short* hmid = (unsigned short*)(ws + o_hmid);
  unsigned short* nh2bf = nh_hi;   // reuse after qkv GEMM
  float* h1buf = qkvbuf;           // reuse after attention
  float* h3buf = qf;               // reuse (spans qf+krope+kt)

  // 1) adaLN modulation
  silu_k<<<10, 256, 0, stream>>>(temb, ss);
  adaln_gemv<<<3840, 256, 0, stream>>>(ss, adaw, adab, mod);
  // 2) LN1 + modulate
  ln_mod<<<T, 256, 0, stream>>>(hs, mod, mod + D, nh_hi, nh_lo);
  // 3) qkv GEMM (split precision: routing-critical path)
  gemm128<1, 0><<<dim3(60, 16), 256, 0, stream>>>(nh_hi, nh_lo, qkvw, qkvb, qkvbuf,
                                                  nullptr, nullptr, nullptr, 2048, 7680, 2560);
  // 4) RMSNorm + RoPE
  rmsrope<<<T, 256, 0, stream>>>(qkvbuf, qnw, knw, rope, qf, krope);
  // 5) K transpose -> [H][128][S]
  transpose_k<<<dim3(80, 64), dim3(32, 8), 0, stream>>>(krope, ktb);
  // 6) attention (f32)
  attn_k<<<dim3(512, 20), 256, 0, stream>>>(qf, ktb, qkvbuf, ohi, olo);
  // 7) out proj (split) + gate_msa residual
  gemm128<1, 1><<<dim3(20, 16), 256, 0, stream>>>(ohi, olo, outw, outb, h2,
                                                  mod + 2 * D, hs, nullptr, 2048, 2560, 2560);
  // 8) LN2 + modulate + routing
  ln2_route<<<T, 256, 0, stream>>>(h2, mod + 3 * D, mod + 4 * D, gatew, nh2bf, wd);
  // 9) MoE experts (dense over 4 experts this round)
  hipMemsetAsync(ybuf, 0, T * D * 4, stream);
  for (int e = 0; e < 4; ++e) {
    const float* w1 = ew1 + (size_t)e * HID_E * DIM;
    const float* w3 = ew3 + (size_t)e * HID_E * DIM;
    const float* w2 = ew2 + (size_t)e * DIM * HID_E;
    gemm128<0, 0><<<dim3(54, 16), 256, 0, stream>>>(nh2bf, nullptr, w1, nullptr, h1buf,
                                                    nullptr, nullptr, nullptr, 2048, 6912, 2560);
    gemm128<0, 0><<<dim3(54, 16), 256, 0, stream>>>(nh2bf, nullptr, w3, nullptr, h3buf,
                                                    nullptr, nullptr, nullptr, 2048, 6912, 2560);
    swiglu_mul<<<2048, 256, 0, stream>>>(h1buf, h3buf, hmid, (int)(T * HID_E / 4));
    gemm128<0, 2><<<dim3(20, 16), 256, 0, stream>>>(hmid, nullptr, w2, nullptr, ybuf,
                                                    wd + e, nullptr, nullptr, 2048, 2560, 6912);
  }
  // 10) shared expert + final combine
  gemm128<0, 0><<<dim3(28, 16), 256, 0, stream>>>(nh2bf, nullptr, sw1, nullptr, h1buf,
                                                  nullptr, nullptr, nullptr, 2048, 3584, 2560);
  gemm128<0, 0><<<dim3(28, 16), 256, 0, stream>>>(nh2bf, nullptr, sw3, nullptr, h3buf,
                                                  nullptr, nullptr, nullptr, 2048, 3584, 2560);
  swiglu_mul<<<2048, 256, 0, stream>>>(h1buf, h3buf, hmid, (int)(T * SHID_E / 4));
  gemm128<0, 3><<<dim3(20, 16), 256, 0, stream>>>(hmid, nullptr, sw2, nullptr, out,
                                                  mod + 5 * D, h2, ybuf, 2048, 2560, 3584);
}

// Round 2
// 3642.559 us; speedup vs baseline: 1.4546x; 1.4546x over previous
//
#include <hip/hip_runtime.h>

#define DIM 2560
#define T_TOK 2048
#define NHEADS 20
#define HD 128
#define HID_E 6912
#define SHID_E 3584

typedef _Float16 f16x8 __attribute__((ext_vector_type(8)));
typedef float f32x4 __attribute__((ext_vector_type(4)));
typedef unsigned short u16x8 __attribute__((ext_vector_type(8)));

#define MFMA16(a, b, c) __builtin_amdgcn_mfma_f32_16x16x32_f16((a), (b), (c), 0, 0, 0)

__device__ inline unsigned short f2h(float f) {
  return __builtin_bit_cast(unsigned short, (_Float16)f);
}
__device__ inline float h2f(unsigned short u) {
  return (float)__builtin_bit_cast(_Float16, u);
}
__device__ inline float wave_sum(float v) {
#pragma unroll
  for (int off = 32; off > 0; off >>= 1) v += __shfl_down(v, off, 64);
  return v;
}

// ---------------- tiny kernels ----------------

__global__ __launch_bounds__(256) void silu_k(const float* __restrict__ t,
                                              float* __restrict__ ss) {
  int i = blockIdx.x * 256 + threadIdx.x;
  if (i < DIM) {
    float v = t[i];
    ss[i] = v / (1.f + expf(-v));
  }
}

// mod[j] = dot(silu(temb), adaln_w[j]) + adaln_b[j]; one wave per output
__global__ __launch_bounds__(256) void adaln_gemv(const float* __restrict__ ss,
                                                  const float* __restrict__ W,
                                                  const float* __restrict__ bias,
                                                  float* __restrict__ mod) {
  const int lane = threadIdx.x & 63;
  const int j = blockIdx.x * 4 + (threadIdx.x >> 6);
  const float* wr = W + (size_t)j * DIM;
  float p = 0.f;
  for (int i = lane; i < 640; i += 64) {
    float4 w = *(const float4*)(wr + i * 4);
    float4 x = *(const float4*)(ss + i * 4);
    p += w.x * x.x + w.y * x.y + w.z * x.z + w.w * x.w;
  }
  p = wave_sum(p);
  if (lane == 0) mod[j] = p + bias[j];
}

// LN (no affine) then *(1+scale)+shift, write fp16. One block per row.
__global__ __launch_bounds__(256) void ln_mod(const float* __restrict__ x,
                                              const float* __restrict__ shift,
                                              const float* __restrict__ scale,
                                              unsigned short* __restrict__ outp) {
  __shared__ float rbuf[8];
  const int t = blockIdx.x, tid = threadIdx.x, lane = tid & 63, wid = tid >> 6;
  const float* xr = x + (size_t)t * DIM;
  float s = 0.f, sq = 0.f;
  for (int i = tid; i < 640; i += 256) {
    float4 v = *(const float4*)(xr + i * 4);
    s += v.x + v.y + v.z + v.w;
    sq += v.x * v.x + v.y * v.y + v.z * v.z + v.w * v.w;
  }
  s = wave_sum(s);
  sq = wave_sum(sq);
  if (lane == 0) {
    rbuf[wid] = s;
    rbuf[4 + wid] = sq;
  }
  __syncthreads();
  float S = rbuf[0] + rbuf[1] + rbuf[2] + rbuf[3];
  float SQ = rbuf[4] + rbuf[5] + rbuf[6] + rbuf[7];
  float mean = S * (1.f / DIM);
  float rs = rsqrtf(SQ * (1.f / DIM) - mean * mean + 1e-6f);
  for (int i = tid; i < 640; i += 256) {
    float4 v = *(const float4*)(xr + i * 4);
    float4 sc4 = *(const float4*)(scale + i * 4);
    float4 sh4 = *(const float4*)(shift + i * 4);
    ushort4 u;
    u.x = f2h((v.x - mean) * rs * (1.f + sc4.x) + sh4.x);
    u.y = f2h((v.y - mean) * rs * (1.f + sc4.y) + sh4.y);
    u.z = f2h((v.z - mean) * rs * (1.f + sc4.z) + sh4.z);
    u.w = f2h((v.w - mean) * rs * (1.f + sc4.w) + sh4.w);
    *(ushort4*)&outp[(size_t)t * DIM + i * 4] = u;
  }
}

// RMSNorm(q),(k) over full 2560 + weight + RoPE -> qh (scaled by 1/sqrt(128)), kh
__global__ __launch_bounds__(256) void rmsrope(const unsigned short* __restrict__ qkv,
                                               const float* __restrict__ qn,
                                               const float* __restrict__ kn,
                                               const float* __restrict__ rope,
                                               unsigned short* __restrict__ qh,
                                               unsigned short* __restrict__ kh) {
  __shared__ float rbuf[8];
  const int t = blockIdx.x, tid = threadIdx.x, lane = tid & 63, wid = tid >> 6;
  const unsigned short* row = qkv + (size_t)t * 7680;
  float sq = 0.f, sk = 0.f;
  for (int i = tid; i < 320; i += 256) {
    f16x8 qv = *(const f16x8*)(row + i * 8);
    f16x8 kv = *(const f16x8*)(row + DIM + i * 8);
#pragma unroll
    for (int j = 0; j < 8; ++j) {
      float q = (float)qv[j], k = (float)kv[j];
      sq += q * q;
      sk += k * k;
    }
  }
  sq = wave_sum(sq);
  sk = wave_sum(sk);
  if (lane == 0) {
    rbuf[wid] = sq;
    rbuf[4 + wid] = sk;
  }
  __syncthreads();
  float SQ = rbuf[0] + rbuf[1] + rbuf[2] + rbuf[3];
  float SK = rbuf[4] + rbuf[5] + rbuf[6] + rbuf[7];
  float rq = rsqrtf(SQ * (1.f / DIM) + 1e-6f) * 0.08838834764831845f;
  float rk = rsqrtf(SK * (1.f / DIM) + 1e-6f);
  for (int pp = tid; pp < 1280; pp += 256) {
    int c = pp * 2;
    float qe = h2f(row[c]) * rq * qn[c], qo = h2f(row[c + 1]) * rq * qn[c + 1];
    float ke = h2f(row[DIM + c]) * rk * kn[c], ko = h2f(row[DIM + c + 1]) * rk * kn[c + 1];
    float4 rr = *(const float4*)(rope + (size_t)t * 256 + (pp & 63) * 4);
    unsigned qp = (unsigned)f2h(rr.x * qe + rr.y * qo) |
                  ((unsigned)f2h(rr.z * qe + rr.w * qo) << 16);
    unsigned kp = (unsigned)f2h(rr.x * ke + rr.y * ko) |
                  ((unsigned)f2h(rr.z * ke + rr.w * ko) << 16);
    *(unsigned*)&qh[(size_t)t * DIM + c] = qp;
    *(unsigned*)&kh[(size_t)t * DIM + c] = kp;
  }
}

// V part of qkv (fp16 [2048][7680] at col 5120) -> vt fp16 [2560][2048]
__global__ void transpose_v(const unsigned short* __restrict__ in,
                            unsigned short* __restrict__ outp) {
  __shared__ unsigned short tile[32][33];
  const int bx = blockIdx.x * 32;  // channel
  const int by = blockIdx.y * 32;  // token
  const int tx = threadIdx.x, ty = threadIdx.y;
  for (int j = ty; j < 32; j += 8)
    tile[j][tx] = in[(size_t)(by + j) * 7680 + 5120 + bx + tx];
  __syncthreads();
  for (int j = ty; j < 32; j += 8)
    outp[(size_t)(bx + j) * T_TOK + by + tx] = tile[tx][j];
}

// ---------------- MFMA flash attention ----------------
// QBLK=64, KBLK=64, 4 waves. S^T = mfma(K,Q) so k is in registers per lane.
// grid (32, 20). qh pre-scaled by 1/sqrt(128).
__global__ __launch_bounds__(256) void fattn(const unsigned short* __restrict__ qh,
                                             const unsigned short* __restrict__ kh,
                                             const unsigned short* __restrict__ vt,
                                             unsigned short* __restrict__ obuf) {
  __shared__ unsigned short sK[64 * 128];  // [k][d], slot = c ^ (r&15)
  __shared__ unsigned short sV[128 * 64];  // [d][k], slot = c ^ (r&7)
  __shared__ unsigned short sP[64 * 64];   // [q][k], slot = c ^ (r&7)
  __shared__ float sRedM[4][64];
  __shared__ float sRedL[4][64];
  __shared__ float sM[64];
  __shared__ float sL[64];
  const int tid = threadIdx.x, lane = tid & 63, wv = tid >> 6;
  const int g = lane >> 4, fr = lane & 15;
  const int h = blockIdx.y;
  const int q0 = blockIdx.x * 64;

  // ---- stage Q tile into sK area, load Q fragments (B-operand) ----
  {
    const int r = tid >> 2, qt = tid & 3;
    const unsigned short* gp = qh + (size_t)(q0 + r) * DIM + h * HD + qt * 32;
    uint4 v0 = ((const uint4*)gp)[0];
    uint4 v1 = ((const uint4*)gp)[1];
    uint4 v2 = ((const uint4*)gp)[2];
    uint4 v3 = ((const uint4*)gp)[3];
    unsigned short* dst = &sK[r * 128];
    const int cb = qt * 4, rs = r & 15;
    *(uint4*)&dst[((cb + 0) ^ rs) * 8] = v0;
    *(uint4*)&dst[((cb + 1) ^ rs) * 8] = v1;
    *(uint4*)&dst[((cb + 2) ^ rs) * 8] = v2;
    *(uint4*)&dst[((cb + 3) ^ rs) * 8] = v3;
  }
  __syncthreads();
  f16x8 qfrag[4][4];
#pragma unroll
  for (int ni = 0; ni < 4; ++ni) {
#pragma unroll
    for (int kt = 0; kt < 4; ++kt) {
      int r = ni * 16 + fr;
      qfrag[ni][kt] = *(const f16x8*)&sK[r * 128 + (((kt * 4 + g) ^ (r & 15)) << 3)];
    }
  }
  __syncthreads();

  f32x4 acco[4][2];
  f32x4 mprev[4];
  float mrun[4], lrun[4];
#pragma unroll
  for (int i = 0; i < 4; ++i) {
    acco[i][0] = (f32x4)0.f;
    acco[i][1] = (f32x4)0.f;
    mprev[i] = (f32x4)(-1e30f);
    mrun[i] = -1e30f;
    lrun[i] = 0.f;
  }

  for (int kt0 = 0; kt0 < T_TOK; kt0 += 64) {
    {  // stage K tile [64][128]
      const int r = tid >> 2, qt = tid & 3;
      const unsigned short* gp = kh + (size_t)(kt0 + r) * DIM + h * HD + qt * 32;
      uint4 v0 = ((const uint4*)gp)[0];
      uint4 v1 = ((const uint4*)gp)[1];
      uint4 v2 = ((const uint4*)gp)[2];
      uint4 v3 = ((const uint4*)gp)[3];
      unsigned short* dst = &sK[r * 128];
      const int cb = qt * 4, rs = r & 15;
      *(uint4*)&dst[((cb + 0) ^ rs) * 8] = v0;
      *(uint4*)&dst[((cb + 1) ^ rs) * 8] = v1;
      *(uint4*)&dst[((cb + 2) ^ rs) * 8] = v2;
      *(uint4*)&dst[((cb + 3) ^ rs) * 8] = v3;
      // stage V tile [128][64]
      const int rv = tid >> 1, hf = tid & 1;
      const unsigned short* gv = vt + (size_t)(h * HD + rv) * T_TOK + kt0 + hf * 32;
      uint4 w0 = ((const uint4*)gv)[0];
      uint4 w1 = ((const uint4*)gv)[1];
      uint4 w2 = ((const uint4*)gv)[2];
      uint4 w3 = ((const uint4*)gv)[3];
      unsigned short* dv = &sV[rv * 64];
      const int cv = hf * 4, rvs = rv & 7;
      *(uint4*)&dv[((cv + 0) ^ rvs) * 8] = w0;
      *(uint4*)&dv[((cv + 1) ^ rvs) * 8] = w1;
      *(uint4*)&dv[((cv + 2) ^ rvs) * 8] = w2;
      *(uint4*)&dv[((cv + 3) ^ rvs) * 8] = w3;
    }
    __syncthreads();  // B0

    // ---- S^T = K · Q^T : wave wv covers k rows [wv*16, wv*16+16) ----
    f32x4 accs[4] = {(f32x4)0.f, (f32x4)0.f, (f32x4)0.f, (f32x4)0.f};
#pragma unroll
    for (int kt = 0; kt < 4; ++kt) {
      int r = wv * 16 + fr;
      f16x8 ak = *(const f16x8*)&sK[r * 128 + (((kt * 4 + g) ^ (r & 15)) << 3)];
#pragma unroll
      for (int ni = 0; ni < 4; ++ni) accs[ni] = MFMA16(ak, qfrag[ni][kt], accs[ni]);
    }

    // ---- softmax ----
    float pm[4];
#pragma unroll
    for (int ni = 0; ni < 4; ++ni) {
      float m = fmaxf(fmaxf(accs[ni][0], accs[ni][1]), fmaxf(accs[ni][2], accs[ni][3]));
      m = fmaxf(m, __shfl_xor(m, 16));
      m = fmaxf(m, __shfl_xor(m, 32));
      pm[ni] = m;
    }
    if (g == 0) {
#pragma unroll
      for (int ni = 0; ni < 4; ++ni) sRedM[wv][ni * 16 + fr] = pm[ni];
    }
    __syncthreads();  // B1
    float mnew[4];
#pragma unroll
    for (int ni = 0; ni < 4; ++ni) {
      int q = ni * 16 + fr;
      float mt = fmaxf(fmaxf(sRedM[0][q], sRedM[1][q]), fmaxf(sRedM[2][q], sRedM[3][q]));
      mnew[ni] = fmaxf(mrun[ni], mt);
    }
    float lsum[4];
#pragma unroll
    for (int ni = 0; ni < 4; ++ni) {
      float l0 = 0.f;
#pragma unroll
      for (int i = 0; i < 4; ++i) {
        float p = __expf(accs[ni][i] - mnew[ni]);
        accs[ni][i] = p;
        l0 += p;
      }
      l0 += __shfl_xor(l0, 16);
      l0 += __shfl_xor(l0, 32);
      lsum[ni] = l0;
    }
    if (g == 0) {
#pragma unroll
      for (int ni = 0; ni < 4; ++ni) sRedL[wv][ni * 16 + fr] = lsum[ni];
      if (wv == 0) {
#pragma unroll
        for (int ni = 0; ni < 4; ++ni) sM[ni * 16 + fr] = mnew[ni];
      }
    }
    // P -> sP (fp16, packed 4 along k): q = ni*16+fr, k = wv*16 + g*4 + i
#pragma unroll
    for (int ni = 0; ni < 4; ++ni) {
      int q = ni * 16 + fr;
      unsigned p01 = (unsigned)f2h(accs[ni][0]) | ((unsigned)f2h(accs[ni][1]) << 16);
      unsigned p23 = (unsigned)f2h(accs[ni][2]) | ((unsigned)f2h(accs[ni][3]) << 16);
      uint2 pk;
      pk.x = p01;
      pk.y = p23;
      *(uint2*)&sP[q * 64 + ((((wv << 1) | (g >> 1)) ^ (q & 7)) << 3) + ((g & 1) << 2)] = pk;
    }
    __syncthreads();  // B2
#pragma unroll
    for (int ni = 0; ni < 4; ++ni) {
      int q = ni * 16 + fr;
      float lt = sRedL[0][q] + sRedL[1][q] + sRedL[2][q] + sRedL[3][q];
      lrun[ni] = lrun[ni] * __expf(mrun[ni] - mnew[ni]) + lt;
      mrun[ni] = mnew[ni];
    }

    // ---- PV: wave wv covers d in [wv*32, wv*32+32) ----
#pragma unroll
    for (int mi = 0; mi < 4; ++mi) {
      f32x4 mn = *(const f32x4*)&sM[mi * 16 + g * 4];
      f32x4 sc;
#pragma unroll
      for (int i = 0; i < 4; ++i) sc[i] = __expf(mprev[mi][i] - mn[i]);
      acco[mi][0] *= sc;
      acco[mi][1] *= sc;
      mprev[mi] = mn;
    }
#pragma unroll
    for (int ktp = 0; ktp < 2; ++ktp) {
      f16x8 bv[2];
#pragma unroll
      for (int nd = 0; nd < 2; ++nd) {
        int r = wv * 32 + nd * 16 + fr;
        bv[nd] = *(const f16x8*)&sV[r * 64 + (((ktp * 4 + g) ^ (r & 7)) << 3)];
      }
#pragma unroll
      for (int mi = 0; mi < 4; ++mi) {
        int r = mi * 16 + fr;
        f16x8 ap = *(const f16x8*)&sP[r * 64 + (((ktp * 4 + g) ^ (r & 7)) << 3)];
        acco[mi][0] = MFMA16(ap, bv[0], acco[mi][0]);
        acco[mi][1] = MFMA16(ap, bv[1], acco[mi][1]);
      }
    }
    __syncthreads();  // B3
  }

  if (wv == 0 && g == 0) {
#pragma unroll
    for (int ni = 0; ni < 4; ++ni) sL[ni * 16 + fr] = 1.f / lrun[ni];
  }
  __syncthreads();
#pragma unroll
  for (int mi = 0; mi < 4; ++mi) {
    f32x4 li = *(const f32x4*)&sL[mi * 16 + g * 4];
#pragma unroll
    for (int nd = 0; nd < 2; ++nd) {
#pragma unroll
      for (int i = 0; i < 4; ++i) {
        float o = acco[mi][nd][i] * li[i];
        obuf[(size_t)(q0 + mi * 16 + g * 4 + i) * DIM + h * HD + wv * 32 + nd * 16 + fr] =
            f2h(o);
      }
    }
  }
}

// LN2 + modulate -> nh2 fp16, plus f32 routing (softmax over 4, top-2, unnormalized)
__global__ __launch_bounds__(256) void ln2_route(const float* __restrict__ x,
                                                 const float* __restrict__ shift,
                                                 const float* __restrict__ scale,
                                                 const float* __restrict__ gw,
                                                 unsigned short* __restrict__ nh2,
                                                 float* __restrict__ wd) {
  __shared__ float rbuf[8];
  __shared__ float gbuf[4][4];
  const int t = blockIdx.x, tid = threadIdx.x, lane = tid & 63, wid = tid >> 6;
  const float* xr = x + (size_t)t * DIM;
  float s = 0.f, sq = 0.f;
  for (int i = tid; i < 640; i += 256) {
    float4 v = *(const float4*)(xr + i * 4);
    s += v.x + v.y + v.z + v.w;
    sq += v.x * v.x + v.y * v.y + v.z * v.z + v.w * v.w;
  }
  s = wave_sum(s);
  sq = wave_sum(sq);
  if (lane == 0) {
    rbuf[wid] = s;
    rbuf[4 + wid] = sq;
  }
  __syncthreads();
  float S = rbuf[0] + rbuf[1] + rbuf[2] + rbuf[3];
  float SQ = rbuf[4] + rbuf[5] + rbuf[6] + rbuf[7];
  float mean = S * (1.f / DIM);
  float rs = rsqrtf(SQ * (1.f / DIM) - mean * mean + 1e-6f);
  float g0 = 0.f, g1 = 0.f, g2 = 0.f, g3 = 0.f;
  for (int i = tid; i < 640; i += 256) {
    float4 v = *(const float4*)(xr + i * 4);
    float4 sc4 = *(const float4*)(scale + i * 4);
    float4 sh4 = *(const float4*)(shift + i * 4);
    float y0 = (v.x - mean) * rs * (1.f + sc4.x) + sh4.x;
    float y1 = (v.y - mean) * rs * (1.f + sc4.y) + sh4.y;
    float y2 = (v.z - mean) * rs * (1.f + sc4.z) + sh4.z;
    float y3 = (v.w - mean) * rs * (1.f + sc4.w) + sh4.w;
    ushort4 u;
    u.x = f2h(y0); u.y = f2h(y1); u.z = f2h(y2); u.w = f2h(y3);
    *(ushort4*)&nh2[(size_t)t * DIM + i * 4] = u;
    float4 w0 = *(const float4*)(gw + i * 4);
    float4 w1 = *(const float4*)(gw + DIM + i * 4);
    float4 w2 = *(const float4*)(gw + 2 * DIM + i * 4);
    float4 w3 = *(const float4*)(gw + 3 * DIM + i * 4);
    g0 += y0 * w0.x + y1 * w0.y + y2 * w0.z + y3 * w0.w;
    g1 += y0 * w1.x + y1 * w1.y + y2 * w1.z + y3 * w1.w;
    g2 += y0 * w2.x + y1 * w2.y + y2 * w2.z + y3 * w2.w;
    g3 += y0 * w3.x + y1 * w3.y + y2 * w3.z + y3 * w3.w;
  }
  g0 = wave_sum(g0);
  g1 = wave_sum(g1);
  g2 = wave_sum(g2);
  g3 = wave_sum(g3);
  if (lane == 0) {
    gbuf[wid][0] = g0; gbuf[wid][1] = g1; gbuf[wid][2] = g2; gbuf[wid][3] = g3;
  }
  __syncthreads();
  if (tid == 0) {
    float l[4];
#pragma unroll
    for (int e = 0; e < 4; ++e) l[e] = gbuf[0][e] + gbuf[1][e] + gbuf[2][e] + gbuf[3][e];
    float mx = fmaxf(fmaxf(l[0], l[1]), fmaxf(l[2], l[3]));
    float ex[4], sum = 0.f;
#pragma unroll
    for (int e = 0; e < 4; ++e) { ex[e] = expf(l[e] - mx); sum += ex[e]; }
    float p[4];
#pragma unroll
    for (int e = 0; e < 4; ++e) p[e] = ex[e] / sum;
    int i1 = 0;
    for (int e = 1; e < 4; ++e)
      if (p[e] > p[i1]) i1 = e;
    int i2 = -1;
    for (int e = 0; e < 4; ++e) {
      if (e == i1) continue;
      if (i2 < 0 || p[e] > p[i2]) i2 = e;
    }
    float w[4] = {0.f, 0.f, 0.f, 0.f};
    w[i1] = p[i1];
    w[i2] = p[i2];
    *(float4*)&wd[(size_t)t * 4] = make_float4(w[0], w[1], w[2], w[3]);
  }
}

__global__ __launch_bounds__(256) void swiglu_mul(const unsigned short* __restrict__ h1,
                                                  const unsigned short* __restrict__ h3,
                                                  unsigned short* __restrict__ outp,
                                                  int n8) {
  const int stride = gridDim.x * 256;
  for (int i = blockIdx.x * 256 + threadIdx.x; i < n8; i += stride) {
    f16x8 a = *(const f16x8*)&h1[(size_t)i * 8];
    f16x8 b = *(const f16x8*)&h3[(size_t)i * 8];
    u16x8 u;
#pragma unroll
    for (int j = 0; j < 8; ++j) {
      float x = (float)a[j];
      float y = x / (1.f + __expf(-x)) * (float)b[j];
      u[j] = f2h(y);
    }
    *(u16x8*)&outp[(size_t)i * 8] = u;
  }
}

// ---------------- GEMM: C[M,N] = A[M,K](fp16) @ B[N,K](f32->fp16)^T ----------------
// 128x128 tile, BK=32, 4 waves, mfma_f32_16x16x32_f16, slot-swizzled LDS.
// EPI: 0 = f32 store (+bias)         1 = f32: aux0[n]*(v+bias[n]) + aux1[idx]
//      2 = f32: C[idx] += aux0[m*4]*v    3 = f32: aux0[n]*(aux2+v) + aux1
//      4 = fp16 store (+bias)
template <int EPI>
__global__ __launch_bounds__(256) void gemm128(
    const unsigned short* __restrict__ A, const float* __restrict__ B,
    const float* __restrict__ bias, void* __restrict__ Cv,
    const float* __restrict__ aux0, const float* __restrict__ aux1,
    const float* __restrict__ aux2, int M, int N, int K) {
  __shared__ unsigned short smem[2 * 4096];
  unsigned short* sA = smem;
  unsigned short* sB = smem + 4096;
  const int tid = threadIdx.x;
  const int lane = tid & 63;
  const int wid = tid >> 6;
  const int m0 = blockIdx.y * 128, n0 = blockIdx.x * 128;
  const int wm = (wid >> 1) * 64, wn = (wid & 1) * 64;
  const int fr = lane & 15, fc = lane >> 4;
  const int sr = tid >> 1, sh = tid & 1;
  const int swz = (sr >> 1) & 3;
  const int sl0 = (2 * sh + 0) ^ swz;
  const int sl1 = (2 * sh + 1) ^ swz;

  f32x4 acc[4][4];
#pragma unroll
  for (int i = 0; i < 4; ++i) {
#pragma unroll
    for (int j = 0; j < 4; ++j) acc[i][j] = (f32x4)0.f;
  }

  const size_t arow = (size_t)(m0 + sr) * K;
  const size_t brow = (size_t)(n0 + sr) * K;

  for (int kt = 0; kt < K; kt += 32) {
    if (kt) __syncthreads();
    {  // A staging (fp16 copy)
      const unsigned short* ga = A + arow + kt + sh * 16;
      uint4 v0 = *(const uint4*)ga;
      uint4 v1 = *(const uint4*)(ga + 8);
      *(uint4*)&sA[sr * 32 + sl0 * 8] = v0;
      *(uint4*)&sA[sr * 32 + sl1 * 8] = v1;
    }
    {  // B staging (f32 -> fp16)
      const float* gb = B + brow + kt + sh * 16;
      float bv[16];
      *(float4*)&bv[0] = *(const float4*)gb;
      *(float4*)&bv[4] = *(const float4*)(gb + 4);
      *(float4*)&bv[8] = *(const float4*)(gb + 8);
      *(float4*)&bv[12] = *(const float4*)(gb + 12);
      u16x8 h0, h1;
#pragma unroll
      for (int j = 0; j < 8; ++j) {
        h0[j] = f2h(bv[j]);
        h1[j] = f2h(bv[8 + j]);
      }
      *(u16x8*)&sB[sr * 32 + sl0 * 8] = h0;
      *(u16x8*)&sB[sr * 32 + sl1 * 8] = h1;
    }
    __syncthreads();
    f16x8 a[4], b[4];
#pragma unroll
    for (int mi = 0; mi < 4; ++mi) {
      int r = wm + mi * 16 + fr;
      a[mi] = *(const f16x8*)&sA[r * 32 + (fc ^ ((r >> 1) & 3)) * 8];
    }
#pragma unroll
    for (int ni = 0; ni < 4; ++ni) {
      int r = wn + ni * 16 + fr;
      b[ni] = *(const f16x8*)&sB[r * 32 + (fc ^ ((r >> 1) & 3)) * 8];
    }
#pragma unroll
    for (int mi = 0; mi < 4; ++mi) {
#pragma unroll
      for (int ni = 0; ni < 4; ++ni) acc[mi][ni] = MFMA16(a[mi], b[ni], acc[mi][ni]);
    }
  }
  // epilogue: D[row=(lane>>4)*4+i][col=lane&15] per 16x16 frag
#pragma unroll
  for (int mi = 0; mi < 4; ++mi) {
#pragma unroll
    for (int ni = 0; ni < 4; ++ni) {
      const int n = n0 + wn + ni * 16 + fr;
      const int mb = m0 + wm + mi * 16 + fc * 4;
#pragma unroll
      for (int i = 0; i < 4; ++i) {
        const int m = mb + i;
        float v = acc[mi][ni][i];
        const size_t idx = (size_t)m * N + n;
        if constexpr (EPI == 0) {
          if (bias) v += bias[n];
          ((float*)Cv)[idx] = v;
        } else if constexpr (EPI == 1) {
          ((float*)Cv)[idx] = aux0[n] * (v + bias[n]) + aux1[idx];
        } else if constexpr (EPI == 2) {
          ((float*)Cv)[idx] += aux0[(size_t)m * 4] * v;
        } else if constexpr (EPI == 3) {
          ((float*)Cv)[idx] = aux0[n] * (aux2[idx] + v) + aux1[idx];
        } else {
          if (bias) v += bias[n];
          ((unsigned short*)Cv)[idx] = f2h(v);
        }
      }
    }
  }
}

// ---------------- host ----------------

extern "C" void kernel_launch(void* const* d_in, const int* in_sizes, int n_in,
                              void* d_out, int out_size, void* d_ws, size_t ws_size,
                              hipStream_t stream) {
  (void)in_sizes; (void)n_in; (void)out_size; (void)ws_size;
  const float* hs = (const float*)d_in[0];
  const float* temb = (const float*)d_in[1];
  const float* rope = (const float*)d_in[2];
  const float* adaw = (const float*)d_in[3];
  const float* adab = (const float*)d_in[4];
  const float* qkvw = (const float*)d_in[5];
  const float* qkvb = (const float*)d_in[6];
  const float* qnw = (const float*)d_in[7];
  const float* knw = (const float*)d_in[8];
  const float* outw = (const float*)d_in[9];
  const float* outb = (const float*)d_in[10];
  const float* gatew = (const float*)d_in[11];
  const float* ew1 = (const float*)d_in[12];
  const float* ew2 = (const float*)d_in[13];
  const float* ew3 = (const float*)d_in[14];
  const float* sw1 = (const float*)d_in[15];
  const float* sw2 = (const float*)d_in[16];
  const float* sw3 = (const float*)d_in[17];
  float* out = (float*)d_out;
  char* ws = (char*)d_ws;

  size_t off = 0;
  auto give = [&](size_t nbytes) {
    size_t r = off;
    off += (nbytes + 255) & ~(size_t)255;
    return r;
  };
  const size_t T = T_TOK, D = DIM;
  size_t o_mod = give(15360 * 4);
  size_t o_ss = give(D * 4);
  size_t o_wd = give(T * 4 * 4);
  size_t o_nh = give(T * D * 2);      // nh fp16; later nh2
  size_t o_qkvh = give(T * 7680 * 2); // qkv fp16; later h1 (fp16 T*HID_E*2 = 28.3MB)
  size_t o_qh = give(T * D * 2);      // q rope'd fp16; qh..vt later h3
  size_t o_kh = give(T * D * 2);
  size_t o_vt = give(T * D * 2);
  size_t o_obf = give(T * D * 2);
  size_t o_h2 = give(T * D * 4);
  size_t o_y = give(T * D * 4);
  size_t o_hmid = give(T * HID_E * 2);

  float* mod = (float*)(ws + o_mod);
  float* ss = (float*)(ws + o_ss);
  float* wd = (float*)(ws + o_wd);
  unsigned short* nh_h = (unsigned short*)(ws + o_nh);
  unsigned short* qkvh = (unsigned short*)(ws + o_qkvh);
  unsigned short* qh = (unsigned short*)(ws + o_qh);
  unsigned short* kh = (unsigned short*)(ws + o_kh);
  unsigned short* vt = (unsigned short*)(ws + o_vt);
  unsigned short* obf = (unsigned short*)(ws + o_obf);
  float* h2 = (float*)(ws + o_h2);
  float* ybuf = (float*)(ws + o_y);
  unsigned short* hmid = (unsigned short*)(ws + o_hmid);
  unsigned short* nh2 = nh_h;                      // reuse after qkv GEMM
  unsigned short* h1buf = qkvh;                    // reuse after attention
  unsigned short* h3buf = qh;                      // reuse (spans qh+kh+vt)

  // 1) adaLN modulation
  silu_k<<<10, 256, 0, stream>>>(temb, ss);
  adaln_gemv<<<3840, 256, 0, stream>>>(ss, adaw, adab, mod);
  // 2) LN1 + modulate (fp16)
  ln_mod<<<T, 256, 0, stream>>>(hs, mod, mod + D, nh_h);
  // 3) qkv GEMM -> fp16
  gemm128<4><<<dim3(60, 16), 256, 0, stream>>>(nh_h, qkvw, qkvb, qkvh,
                                               nullptr, nullptr, nullptr, 2048, 7680, 2560);
  // 4) RMSNorm + RoPE (fp16 out, q pre-scaled)
  rmsrope<<<T, 256, 0, stream>>>(qkvh, qnw, knw, rope, qh, kh);
  // 5) V transpose -> [2560][2048] fp16
  transpose_v<<<dim3(80, 64), dim3(32, 8), 0, stream>>>(qkvh, vt);
  // 6) MFMA flash attention
  fattn<<<dim3(32, 20), 256, 0, stream>>>(qh, kh, vt, obf);
  // 7) out proj + gate_msa residual -> h2 f32
  gemm128<1><<<dim3(20, 16), 256, 0, stream>>>(obf, outw, outb, h2,
                                               mod + 2 * D, hs, nullptr, 2048, 2560, 2560);
  // 8) LN2 + modulate + routing
  ln2_route<<<T, 256, 0, stream>>>(h2, mod + 3 * D, mod + 4 * D, gatew, nh2, wd);
  // 9) MoE experts (dense over 4 experts)
  hipMemsetAsync(ybuf, 0, T * D * 4, stream);
  for (int e = 0; e < 4; ++e) {
    const float* w1 = ew1 + (size_t)e * HID_E * DIM;
    const float* w3 = ew3 + (size_t)e * HID_E * DIM;
    const float* w2 = ew2 + (size_t)e * DIM * HID_E;
    gemm128<4><<<dim3(54, 16), 256, 0, stream>>>(nh2, w1, nullptr, h1buf,
                                                 nullptr, nullptr, nullptr, 2048, 6912, 2560);
    gemm128<4><<<dim3(54, 16), 256, 0, stream>>>(nh2, w3, nullptr, h3buf,
                                                 nullptr, nullptr, nullptr, 2048, 6912, 2560);
    swiglu_mul<<<2048, 256, 0, stream>>>(h1buf, h3buf, hmid, (int)(T * HID_E / 8));
    gemm128<2><<<dim3(20, 16), 256, 0, stream>>>(hmid, w2, nullptr, ybuf,
                                                 wd + e, nullptr, nullptr, 2048, 2560, 6912);
  }
  // 10) shared expert + final combine
  gemm128<4><<<dim3(28, 16), 256, 0, stream>>>(nh2, sw1, nullptr, h1buf,
                                               nullptr, nullptr, nullptr, 2048, 3584, 2560);
  gemm128<4><<<dim3(28, 16), 256, 0, stream>>>(nh2, sw3, nullptr, h3buf,
                                               nullptr, nullptr, nullptr, 2048, 3584, 2560);
  swiglu_mul<<<2048, 256, 0, stream>>>(h1buf, h3buf, hmid, (int)(T * SHID_E / 8));
  gemm128<3><<<dim3(20, 16), 256, 0, stream>>>(hmid, sw2, nullptr, out,
                                               mod + 5 * D, h2, ybuf, 2048, 2560, 3584);
}

// Round 3
// 2891.506 us; speedup vs baseline: 1.8325x; 1.2597x over previous
//
#include <hip/hip_runtime.h>

#define DIM 2560
#define T_TOK 2048
#define NHEADS 20
#define HD 128
#define HID_E 6912
#define SHID_E 3584

typedef _Float16 f16x8 __attribute__((ext_vector_type(8)));
typedef float f32x4 __attribute__((ext_vector_type(4)));
typedef unsigned short u16x8 __attribute__((ext_vector_type(8)));

#define MFMA16(a, b, c) __builtin_amdgcn_mfma_f32_16x16x32_f16((a), (b), (c), 0, 0, 0)

__device__ inline unsigned short f2h(float f) {
  return __builtin_bit_cast(unsigned short, (_Float16)f);
}
__device__ inline float h2f(unsigned short u) {
  return (float)__builtin_bit_cast(_Float16, u);
}
__device__ inline float wave_sum(float v) {
#pragma unroll
  for (int off = 32; off > 0; off >>= 1) v += __shfl_down(v, off, 64);
  return v;
}
// async global->LDS, 16B per lane; LDS dest = wave-uniform base + lane*16
__device__ inline void gld16(const void* g, void* l) {
  __builtin_amdgcn_global_load_lds((const __attribute__((address_space(1))) void*)g,
                                   (__attribute__((address_space(3))) void*)l, 16, 0, 0);
}

// ---------------- tiny kernels ----------------

__global__ __launch_bounds__(256) void silu_k(const float* __restrict__ t,
                                              float* __restrict__ ss) {
  int i = blockIdx.x * 256 + threadIdx.x;
  if (i < DIM) {
    float v = t[i];
    ss[i] = v / (1.f + expf(-v));
  }
}

__global__ __launch_bounds__(256) void cvt_f16(const float* __restrict__ in,
                                               unsigned short* __restrict__ outp, int n8) {
  const int stride = gridDim.x * 256;
  for (int i = blockIdx.x * 256 + threadIdx.x; i < n8; i += stride) {
    float4 a = *(const float4*)(in + (size_t)i * 8);
    float4 b = *(const float4*)(in + (size_t)i * 8 + 4);
    u16x8 u;
    u[0] = f2h(a.x); u[1] = f2h(a.y); u[2] = f2h(a.z); u[3] = f2h(a.w);
    u[4] = f2h(b.x); u[5] = f2h(b.y); u[6] = f2h(b.z); u[7] = f2h(b.w);
    *(u16x8*)&outp[(size_t)i * 8] = u;
  }
}

// mod[j] = dot(silu(temb), adaln_w[j]) + adaln_b[j]; one wave per output
__global__ __launch_bounds__(256) void adaln_gemv(const float* __restrict__ ss,
                                                  const float* __restrict__ W,
                                                  const float* __restrict__ bias,
                                                  float* __restrict__ mod) {
  const int lane = threadIdx.x & 63;
  const int j = blockIdx.x * 4 + (threadIdx.x >> 6);
  const float* wr = W + (size_t)j * DIM;
  float p = 0.f;
  for (int i = lane; i < 640; i += 64) {
    float4 w = *(const float4*)(wr + i * 4);
    float4 x = *(const float4*)(ss + i * 4);
    p += w.x * x.x + w.y * x.y + w.z * x.z + w.w * x.w;
  }
  p = wave_sum(p);
  if (lane == 0) mod[j] = p + bias[j];
}

// LN (no affine) then *(1+scale)+shift, write fp16. One block per row.
__global__ __launch_bounds__(256) void ln_mod(const float* __restrict__ x,
                                              const float* __restrict__ shift,
                                              const float* __restrict__ scale,
                                              unsigned short* __restrict__ outp) {
  __shared__ float rbuf[8];
  const int t = blockIdx.x, tid = threadIdx.x, lane = tid & 63, wid = tid >> 6;
  const float* xr = x + (size_t)t * DIM;
  float s = 0.f, sq = 0.f;
  for (int i = tid; i < 640; i += 256) {
    float4 v = *(const float4*)(xr + i * 4);
    s += v.x + v.y + v.z + v.w;
    sq += v.x * v.x + v.y * v.y + v.z * v.z + v.w * v.w;
  }
  s = wave_sum(s);
  sq = wave_sum(sq);
  if (lane == 0) {
    rbuf[wid] = s;
    rbuf[4 + wid] = sq;
  }
  __syncthreads();
  float S = rbuf[0] + rbuf[1] + rbuf[2] + rbuf[3];
  float SQ = rbuf[4] + rbuf[5] + rbuf[6] + rbuf[7];
  float mean = S * (1.f / DIM);
  float rs = rsqrtf(SQ * (1.f / DIM) - mean * mean + 1e-6f);
  for (int i = tid; i < 640; i += 256) {
    float4 v = *(const float4*)(xr + i * 4);
    float4 sc4 = *(const float4*)(scale + i * 4);
    float4 sh4 = *(const float4*)(shift + i * 4);
    ushort4 u;
    u.x = f2h((v.x - mean) * rs * (1.f + sc4.x) + sh4.x);
    u.y = f2h((v.y - mean) * rs * (1.f + sc4.y) + sh4.y);
    u.z = f2h((v.z - mean) * rs * (1.f + sc4.z) + sh4.z);
    u.w = f2h((v.w - mean) * rs * (1.f + sc4.w) + sh4.w);
    *(ushort4*)&outp[(size_t)t * DIM + i * 4] = u;
  }
}

// RMSNorm(q),(k) over full 2560 + weight + RoPE -> qh (scaled by 1/sqrt(128)), kh
__global__ __launch_bounds__(256) void rmsrope(const unsigned short* __restrict__ qkv,
                                               const float* __restrict__ qn,
                                               const float* __restrict__ kn,
                                               const float* __restrict__ rope,
                                               unsigned short* __restrict__ qh,
                                               unsigned short* __restrict__ kh) {
  __shared__ float rbuf[8];
  const int t = blockIdx.x, tid = threadIdx.x, lane = tid & 63, wid = tid >> 6;
  const unsigned short* row = qkv + (size_t)t * 7680;
  float sq = 0.f, sk = 0.f;
  for (int i = tid; i < 320; i += 256) {
    f16x8 qv = *(const f16x8*)(row + i * 8);
    f16x8 kv = *(const f16x8*)(row + DIM + i * 8);
#pragma unroll
    for (int j = 0; j < 8; ++j) {
      float q = (float)qv[j], k = (float)kv[j];
      sq += q * q;
      sk += k * k;
    }
  }
  sq = wave_sum(sq);
  sk = wave_sum(sk);
  if (lane == 0) {
    rbuf[wid] = sq;
    rbuf[4 + wid] = sk;
  }
  __syncthreads();
  float SQ = rbuf[0] + rbuf[1] + rbuf[2] + rbuf[3];
  float SK = rbuf[4] + rbuf[5] + rbuf[6] + rbuf[7];
  float rq = rsqrtf(SQ * (1.f / DIM) + 1e-6f) * 0.08838834764831845f;
  float rk = rsqrtf(SK * (1.f / DIM) + 1e-6f);
  for (int pp = tid; pp < 1280; pp += 256) {
    int c = pp * 2;
    float qe = h2f(row[c]) * rq * qn[c], qo = h2f(row[c + 1]) * rq * qn[c + 1];
    float ke = h2f(row[DIM + c]) * rk * kn[c], ko = h2f(row[DIM + c + 1]) * rk * kn[c + 1];
    float4 rr = *(const float4*)(rope + (size_t)t * 256 + (pp & 63) * 4);
    unsigned qp = (unsigned)f2h(rr.x * qe + rr.y * qo) |
                  ((unsigned)f2h(rr.z * qe + rr.w * qo) << 16);
    unsigned kp = (unsigned)f2h(rr.x * ke + rr.y * ko) |
                  ((unsigned)f2h(rr.z * ke + rr.w * ko) << 16);
    *(unsigned*)&qh[(size_t)t * DIM + c] = qp;
    *(unsigned*)&kh[(size_t)t * DIM + c] = kp;
  }
}

// V part of qkv (fp16 [2048][7680] at col 5120) -> vt fp16 [2560][2048]
__global__ void transpose_v(const unsigned short* __restrict__ in,
                            unsigned short* __restrict__ outp) {
  __shared__ unsigned short tile[32][33];
  const int bx = blockIdx.x * 32;  // channel
  const int by = blockIdx.y * 32;  // token
  const int tx = threadIdx.x, ty = threadIdx.y;
  for (int j = ty; j < 32; j += 8)
    tile[j][tx] = in[(size_t)(by + j) * 7680 + 5120 + bx + tx];
  __syncthreads();
  for (int j = ty; j < 32; j += 8)
    outp[(size_t)(bx + j) * T_TOK + by + tx] = tile[tx][j];
}

// ---------------- MFMA flash attention ----------------
__global__ __launch_bounds__(256) void fattn(const unsigned short* __restrict__ qh,
                                             const unsigned short* __restrict__ kh,
                                             const unsigned short* __restrict__ vt,
                                             unsigned short* __restrict__ obuf) {
  __shared__ unsigned short sK[64 * 128];  // [k][d], slot = c ^ (r&15)
  __shared__ unsigned short sV[128 * 64];  // [d][k], slot = c ^ (r&7)
  __shared__ unsigned short sP[64 * 64];   // [q][k], slot = c ^ (r&7)
  __shared__ float sRedM[4][64];
  __shared__ float sRedL[4][64];
  __shared__ float sM[64];
  __shared__ float sL[64];
  const int tid = threadIdx.x, lane = tid & 63, wv = tid >> 6;
  const int g = lane >> 4, fr = lane & 15;
  const int h = blockIdx.y;
  const int q0 = blockIdx.x * 64;

  {
    const int r = tid >> 2, qt = tid & 3;
    const unsigned short* gp = qh + (size_t)(q0 + r) * DIM + h * HD + qt * 32;
    uint4 v0 = ((const uint4*)gp)[0];
    uint4 v1 = ((const uint4*)gp)[1];
    uint4 v2 = ((const uint4*)gp)[2];
    uint4 v3 = ((const uint4*)gp)[3];
    unsigned short* dst = &sK[r * 128];
    const int cb = qt * 4, rs = r & 15;
    *(uint4*)&dst[((cb + 0) ^ rs) * 8] = v0;
    *(uint4*)&dst[((cb + 1) ^ rs) * 8] = v1;
    *(uint4*)&dst[((cb + 2) ^ rs) * 8] = v2;
    *(uint4*)&dst[((cb + 3) ^ rs) * 8] = v3;
  }
  __syncthreads();
  f16x8 qfrag[4][4];
#pragma unroll
  for (int ni = 0; ni < 4; ++ni) {
#pragma unroll
    for (int kt = 0; kt < 4; ++kt) {
      int r = ni * 16 + fr;
      qfrag[ni][kt] = *(const f16x8*)&sK[r * 128 + (((kt * 4 + g) ^ (r & 15)) << 3)];
    }
  }
  __syncthreads();

  f32x4 acco[4][2];
  f32x4 mprev[4];
  float mrun[4], lrun[4];
#pragma unroll
  for (int i = 0; i < 4; ++i) {
    acco[i][0] = (f32x4)0.f;
    acco[i][1] = (f32x4)0.f;
    mprev[i] = (f32x4)(-1e30f);
    mrun[i] = -1e30f;
    lrun[i] = 0.f;
  }

  for (int kt0 = 0; kt0 < T_TOK; kt0 += 64) {
    {
      const int r = tid >> 2, qt = tid & 3;
      const unsigned short* gp = kh + (size_t)(kt0 + r) * DIM + h * HD + qt * 32;
      uint4 v0 = ((const uint4*)gp)[0];
      uint4 v1 = ((const uint4*)gp)[1];
      uint4 v2 = ((const uint4*)gp)[2];
      uint4 v3 = ((const uint4*)gp)[3];
      unsigned short* dst = &sK[r * 128];
      const int cb = qt * 4, rs = r & 15;
      *(uint4*)&dst[((cb + 0) ^ rs) * 8] = v0;
      *(uint4*)&dst[((cb + 1) ^ rs) * 8] = v1;
      *(uint4*)&dst[((cb + 2) ^ rs) * 8] = v2;
      *(uint4*)&dst[((cb + 3) ^ rs) * 8] = v3;
      const int rv = tid >> 1, hf = tid & 1;
      const unsigned short* gv = vt + (size_t)(h * HD + rv) * T_TOK + kt0 + hf * 32;
      uint4 w0 = ((const uint4*)gv)[0];
      uint4 w1 = ((const uint4*)gv)[1];
      uint4 w2 = ((const uint4*)gv)[2];
      uint4 w3 = ((const uint4*)gv)[3];
      unsigned short* dv = &sV[rv * 64];
      const int cv = hf * 4, rvs = rv & 7;
      *(uint4*)&dv[((cv + 0) ^ rvs) * 8] = w0;
      *(uint4*)&dv[((cv + 1) ^ rvs) * 8] = w1;
      *(uint4*)&dv[((cv + 2) ^ rvs) * 8] = w2;
      *(uint4*)&dv[((cv + 3) ^ rvs) * 8] = w3;
    }
    __syncthreads();  // B0

    f32x4 accs[4] = {(f32x4)0.f, (f32x4)0.f, (f32x4)0.f, (f32x4)0.f};
#pragma unroll
    for (int kt = 0; kt < 4; ++kt) {
      int r = wv * 16 + fr;
      f16x8 ak = *(const f16x8*)&sK[r * 128 + (((kt * 4 + g) ^ (r & 15)) << 3)];
#pragma unroll
      for (int ni = 0; ni < 4; ++ni) accs[ni] = MFMA16(ak, qfrag[ni][kt], accs[ni]);
    }

    float pm[4];
#pragma unroll
    for (int ni = 0; ni < 4; ++ni) {
      float m = fmaxf(fmaxf(accs[ni][0], accs[ni][1]), fmaxf(accs[ni][2], accs[ni][3]));
      m = fmaxf(m, __shfl_xor(m, 16));
      m = fmaxf(m, __shfl_xor(m, 32));
      pm[ni] = m;
    }
    if (g == 0) {
#pragma unroll
      for (int ni = 0; ni < 4; ++ni) sRedM[wv][ni * 16 + fr] = pm[ni];
    }
    __syncthreads();  // B1
    float mnew[4];
#pragma unroll
    for (int ni = 0; ni < 4; ++ni) {
      int q = ni * 16 + fr;
      float mt = fmaxf(fmaxf(sRedM[0][q], sRedM[1][q]), fmaxf(sRedM[2][q], sRedM[3][q]));
      mnew[ni] = fmaxf(mrun[ni], mt);
    }
    float lsum[4];
#pragma unroll
    for (int ni = 0; ni < 4; ++ni) {
      float l0 = 0.f;
#pragma unroll
      for (int i = 0; i < 4; ++i) {
        float p = __expf(accs[ni][i] - mnew[ni]);
        accs[ni][i] = p;
        l0 += p;
      }
      l0 += __shfl_xor(l0, 16);
      l0 += __shfl_xor(l0, 32);
      lsum[ni] = l0;
    }
    if (g == 0) {
#pragma unroll
      for (int ni = 0; ni < 4; ++ni) sRedL[wv][ni * 16 + fr] = lsum[ni];
      if (wv == 0) {
#pragma unroll
        for (int ni = 0; ni < 4; ++ni) sM[ni * 16 + fr] = mnew[ni];
      }
    }
#pragma unroll
    for (int ni = 0; ni < 4; ++ni) {
      int q = ni * 16 + fr;
      unsigned p01 = (unsigned)f2h(accs[ni][0]) | ((unsigned)f2h(accs[ni][1]) << 16);
      unsigned p23 = (unsigned)f2h(accs[ni][2]) | ((unsigned)f2h(accs[ni][3]) << 16);
      uint2 pk;
      pk.x = p01;
      pk.y = p23;
      *(uint2*)&sP[q * 64 + ((((wv << 1) | (g >> 1)) ^ (q & 7)) << 3) + ((g & 1) << 2)] = pk;
    }
    __syncthreads();  // B2
#pragma unroll
    for (int ni = 0; ni < 4; ++ni) {
      int q = ni * 16 + fr;
      float lt = sRedL[0][q] + sRedL[1][q] + sRedL[2][q] + sRedL[3][q];
      lrun[ni] = lrun[ni] * __expf(mrun[ni] - mnew[ni]) + lt;
      mrun[ni] = mnew[ni];
    }

#pragma unroll
    for (int mi = 0; mi < 4; ++mi) {
      f32x4 mn = *(const f32x4*)&sM[mi * 16 + g * 4];
      f32x4 sc;
#pragma unroll
      for (int i = 0; i < 4; ++i) sc[i] = __expf(mprev[mi][i] - mn[i]);
      acco[mi][0] *= sc;
      acco[mi][1] *= sc;
      mprev[mi] = mn;
    }
#pragma unroll
    for (int ktp = 0; ktp < 2; ++ktp) {
      f16x8 bv[2];
#pragma unroll
      for (int nd = 0; nd < 2; ++nd) {
        int r = wv * 32 + nd * 16 + fr;
        bv[nd] = *(const f16x8*)&sV[r * 64 + (((ktp * 4 + g) ^ (r & 7)) << 3)];
      }
#pragma unroll
      for (int mi = 0; mi < 4; ++mi) {
        int r = mi * 16 + fr;
        f16x8 ap = *(const f16x8*)&sP[r * 64 + (((ktp * 4 + g) ^ (r & 7)) << 3)];
        acco[mi][0] = MFMA16(ap, bv[0], acco[mi][0]);
        acco[mi][1] = MFMA16(ap, bv[1], acco[mi][1]);
      }
    }
    __syncthreads();  // B3
  }

  if (wv == 0 && g == 0) {
#pragma unroll
    for (int ni = 0; ni < 4; ++ni) sL[ni * 16 + fr] = 1.f / lrun[ni];
  }
  __syncthreads();
#pragma unroll
  for (int mi = 0; mi < 4; ++mi) {
    f32x4 li = *(const f32x4*)&sL[mi * 16 + g * 4];
#pragma unroll
    for (int nd = 0; nd < 2; ++nd) {
#pragma unroll
      for (int i = 0; i < 4; ++i) {
        float o = acco[mi][nd][i] * li[i];
        obuf[(size_t)(q0 + mi * 16 + g * 4 + i) * DIM + h * HD + wv * 32 + nd * 16 + fr] =
            f2h(o);
      }
    }
  }
}

// LN2 + modulate -> nh2 fp16, plus f32 routing (softmax over 4, top-2, unnormalized)
__global__ __launch_bounds__(256) void ln2_route(const float* __restrict__ x,
                                                 const float* __restrict__ shift,
                                                 const float* __restrict__ scale,
                                                 const float* __restrict__ gw,
                                                 unsigned short* __restrict__ nh2,
                                                 float* __restrict__ wd) {
  __shared__ float rbuf[8];
  __shared__ float gbuf[4][4];
  const int t = blockIdx.x, tid = threadIdx.x, lane = tid & 63, wid = tid >> 6;
  const float* xr = x + (size_t)t * DIM;
  float s = 0.f, sq = 0.f;
  for (int i = tid; i < 640; i += 256) {
    float4 v = *(const float4*)(xr + i * 4);
    s += v.x + v.y + v.z + v.w;
    sq += v.x * v.x + v.y * v.y + v.z * v.z + v.w * v.w;
  }
  s = wave_sum(s);
  sq = wave_sum(sq);
  if (lane == 0) {
    rbuf[wid] = s;
    rbuf[4 + wid] = sq;
  }
  __syncthreads();
  float S = rbuf[0] + rbuf[1] + rbuf[2] + rbuf[3];
  float SQ = rbuf[4] + rbuf[5] + rbuf[6] + rbuf[7];
  float mean = S * (1.f / DIM);
  float rs = rsqrtf(SQ * (1.f / DIM) - mean * mean + 1e-6f);
  float g0 = 0.f, g1 = 0.f, g2 = 0.f, g3 = 0.f;
  for (int i = tid; i < 640; i += 256) {
    float4 v = *(const float4*)(xr + i * 4);
    float4 sc4 = *(const float4*)(scale + i * 4);
    float4 sh4 = *(const float4*)(shift + i * 4);
    float y0 = (v.x - mean) * rs * (1.f + sc4.x) + sh4.x;
    float y1 = (v.y - mean) * rs * (1.f + sc4.y) + sh4.y;
    float y2 = (v.z - mean) * rs * (1.f + sc4.z) + sh4.z;
    float y3 = (v.w - mean) * rs * (1.f + sc4.w) + sh4.w;
    ushort4 u;
    u.x = f2h(y0); u.y = f2h(y1); u.z = f2h(y2); u.w = f2h(y3);
    *(ushort4*)&nh2[(size_t)t * DIM + i * 4] = u;
    float4 w0 = *(const float4*)(gw + i * 4);
    float4 w1 = *(const float4*)(gw + DIM + i * 4);
    float4 w2 = *(const float4*)(gw + 2 * DIM + i * 4);
    float4 w3 = *(const float4*)(gw + 3 * DIM + i * 4);
    g0 += y0 * w0.x + y1 * w0.y + y2 * w0.z + y3 * w0.w;
    g1 += y0 * w1.x + y1 * w1.y + y2 * w1.z + y3 * w1.w;
    g2 += y0 * w2.x + y1 * w2.y + y2 * w2.z + y3 * w2.w;
    g3 += y0 * w3.x + y1 * w3.y + y2 * w3.z + y3 * w3.w;
  }
  g0 = wave_sum(g0);
  g1 = wave_sum(g1);
  g2 = wave_sum(g2);
  g3 = wave_sum(g3);
  if (lane == 0) {
    gbuf[wid][0] = g0; gbuf[wid][1] = g1; gbuf[wid][2] = g2; gbuf[wid][3] = g3;
  }
  __syncthreads();
  if (tid == 0) {
    float l[4];
#pragma unroll
    for (int e = 0; e < 4; ++e) l[e] = gbuf[0][e] + gbuf[1][e] + gbuf[2][e] + gbuf[3][e];
    float mx = fmaxf(fmaxf(l[0], l[1]), fmaxf(l[2], l[3]));
    float ex[4], sum = 0.f;
#pragma unroll
    for (int e = 0; e < 4; ++e) { ex[e] = expf(l[e] - mx); sum += ex[e]; }
    float p[4];
#pragma unroll
    for (int e = 0; e < 4; ++e) p[e] = ex[e] / sum;
    int i1 = 0;
    for (int e = 1; e < 4; ++e)
      if (p[e] > p[i1]) i1 = e;
    int i2 = -1;
    for (int e = 0; e < 4; ++e) {
      if (e == i1) continue;
      if (i2 < 0 || p[e] > p[i2]) i2 = e;
    }
    float w[4] = {0.f, 0.f, 0.f, 0.f};
    w[i1] = p[i1];
    w[i2] = p[i2];
    *(float4*)&wd[(size_t)t * 4] = make_float4(w[0], w[1], w[2], w[3]);
  }
}

// deterministic token-ordered top-2 compaction; 1 block, 256 threads, 8 tokens each
__global__ __launch_bounds__(256) void route_compact(const float* __restrict__ wd,
                                                     int* __restrict__ idxbuf,
                                                     int* __restrict__ cnt) {
  __shared__ unsigned short c[256][4];
  __shared__ int offs[256][4];
  const int t = threadIdx.x;
  unsigned char sel[8];
  unsigned short lc[4] = {0, 0, 0, 0};
#pragma unroll
  for (int k = 0; k < 8; ++k) {
    int tok = t * 8 + k;
    float4 w = *(const float4*)&wd[(size_t)tok * 4];
    unsigned m = 0;
    if (w.x != 0.f) { m |= 1; lc[0]++; }
    if (w.y != 0.f) { m |= 2; lc[1]++; }
    if (w.z != 0.f) { m |= 4; lc[2]++; }
    if (w.w != 0.f) { m |= 8; lc[3]++; }
    sel[k] = (unsigned char)m;
  }
#pragma unroll
  for (int e = 0; e < 4; ++e) c[t][e] = lc[e];
  __syncthreads();
  if (t == 0) {
    int run[4] = {0, 0, 0, 0};
    for (int i = 0; i < 256; ++i) {
#pragma unroll
      for (int e = 0; e < 4; ++e) {
        offs[i][e] = run[e];
        run[e] += c[i][e];
      }
    }
#pragma unroll
    for (int e = 0; e < 4; ++e) cnt[e] = run[e];
  }
  __syncthreads();
  int o[4];
#pragma unroll
  for (int e = 0; e < 4; ++e) o[e] = offs[t][e];
#pragma unroll
  for (int k = 0; k < 8; ++k) {
    int tok = t * 8 + k;
    unsigned m = sel[k];
#pragma unroll
    for (int e = 0; e < 4; ++e) {
      if ((m >> e) & 1) idxbuf[e * 2048 + o[e]++] = tok;
    }
  }
}

__global__ __launch_bounds__(256) void swiglu_mul(const unsigned short* __restrict__ h1,
                                                  const unsigned short* __restrict__ h3,
                                                  unsigned short* __restrict__ outp,
                                                  const int* __restrict__ cntp,
                                                  int per_row8, int fixed_n8) {
  const int n8 = cntp ? (*cntp) * per_row8 : fixed_n8;
  const int stride = gridDim.x * 256;
  for (int i = blockIdx.x * 256 + threadIdx.x; i < n8; i += stride) {
    f16x8 a = *(const f16x8*)&h1[(size_t)i * 8];
    f16x8 b = *(const f16x8*)&h3[(size_t)i * 8];
    u16x8 u;
#pragma unroll
    for (int j = 0; j < 8; ++j) {
      float x = (float)a[j];
      float y = x / (1.f + __expf(-x)) * (float)b[j];
      u[j] = f2h(y);
    }
    *(u16x8*)&outp[(size_t)i * 8] = u;
  }
}

// ---------------- GEMM: C[M,N] = A[M,K](fp16) @ B[N,K](fp16)^T ----------------
// 128x128 tile, BK=32, 4 waves, global_load_lds width=16 staging with
// pre-swizzled per-lane global source + linear LDS dest (rule: both-sides).
// MODE: 0 dense | 1 A-gather via idx, rows>=cnt masked, compact C | 2 compact A,
//       scatter C[tok]+= wd*v. EPI: 0 f32(+bias) | 1 f32 aux0[n]*(v+bias)+aux1 |
//       2 scatter += | 3 f32 aux0[n]*(aux2+v)+aux1 | 4 fp16(+bias)
template <int EPI, int MODE>
__global__ __launch_bounds__(256) void gemm128(
    const unsigned short* __restrict__ A, const unsigned short* __restrict__ B,
    const float* __restrict__ bias, void* __restrict__ Cv,
    const float* __restrict__ aux0, const float* __restrict__ aux1,
    const float* __restrict__ aux2, const int* __restrict__ idx,
    const int* __restrict__ cntp, const float* __restrict__ wdp,
    int gx, int M, int N, int K) {
  __shared__ unsigned short sA[4096];
  __shared__ unsigned short sB[4096];
  const int tid = threadIdx.x;
  const int lane = tid & 63;
  const int wv = tid >> 6;
  // XCD-aware bijective swizzle (grid always %8==0)
  const int nwg = gridDim.x;
  const int bid = blockIdx.x;
  const int swzb = (bid & 7) * (nwg >> 3) + (bid >> 3);
  const int m0 = (swzb / gx) * 128, n0 = (swzb % gx) * 128;
  const int cnt = (MODE != 0) ? *cntp : M;
  if (MODE != 0 && m0 >= cnt) return;

  const int wm = (wv >> 1) * 64, wn = (wv & 1) * 64;
  const int fr = lane & 15, fc = lane >> 4;

  // staging geometry: lane -> (row rl, chunk ch); wave wv stages rows
  // [wv*16, wv*16+16) and [64+wv*16, ...). source chunk pre-swizzled.
  const int rl = lane >> 2, ch = lane & 3;
  const int R1 = wv * 16 + rl;
  const int R2 = 64 + R1;
  const int co1 = ((ch ^ ((R1 >> 1) & 3)) << 3);
  const int co2 = ((ch ^ ((R2 >> 1) & 3)) << 3);
  size_t ar1, ar2;
  if constexpr (MODE == 1) {
    int i1 = m0 + R1, i2 = m0 + R2;
    i1 = i1 < cnt ? i1 : cnt - 1;
    i2 = i2 < cnt ? i2 : cnt - 1;
    ar1 = (size_t)idx[i1] * K;
    ar2 = (size_t)idx[i2] * K;
  } else {
    ar1 = (size_t)(m0 + R1) * K;
    ar2 = (size_t)(m0 + R2) * K;
  }
  const unsigned short* gA1 = A + ar1 + co1;
  const unsigned short* gA2 = A + ar2 + co2;
  const unsigned short* gB1 = B + (size_t)(n0 + R1) * K + co1;
  const unsigned short* gB2 = B + (size_t)(n0 + R2) * K + co2;
  unsigned short* lA1 = &sA[(wv * 16) * 32];
  unsigned short* lA2 = &sA[(64 + wv * 16) * 32];
  unsigned short* lB1 = &sB[(wv * 16) * 32];
  unsigned short* lB2 = &sB[(64 + wv * 16) * 32];

  f32x4 acc[4][4];
#pragma unroll
  for (int i = 0; i < 4; ++i) {
#pragma unroll
    for (int j = 0; j < 4; ++j) acc[i][j] = (f32x4)0.f;
  }

  for (int kt = 0; kt < K; kt += 32) {
    if (kt) __syncthreads();
    gld16(gA1 + kt, lA1);
    gld16(gA2 + kt, lA2);
    gld16(gB1 + kt, lB1);
    gld16(gB2 + kt, lB2);
    __syncthreads();  // compiler drains vmcnt before barrier
    f16x8 a[4], b[4];
#pragma unroll
    for (int mi = 0; mi < 4; ++mi) {
      int r = wm + mi * 16 + fr;
      a[mi] = *(const f16x8*)&sA[r * 32 + ((fc ^ ((r >> 1) & 3)) << 3)];
    }
#pragma unroll
    for (int ni = 0; ni < 4; ++ni) {
      int r = wn + ni * 16 + fr;
      b[ni] = *(const f16x8*)&sB[r * 32 + ((fc ^ ((r >> 1) & 3)) << 3)];
    }
#pragma unroll
    for (int mi = 0; mi < 4; ++mi) {
#pragma unroll
      for (int ni = 0; ni < 4; ++ni) acc[mi][ni] = MFMA16(a[mi], b[ni], acc[mi][ni]);
    }
  }
  // epilogue: D[row=(lane>>4)*4+i][col=lane&15] per 16x16 frag
#pragma unroll
  for (int mi = 0; mi < 4; ++mi) {
#pragma unroll
    for (int ni = 0; ni < 4; ++ni) {
      const int n = n0 + wn + ni * 16 + fr;
      const int mb = m0 + wm + mi * 16 + fc * 4;
#pragma unroll
      for (int i = 0; i < 4; ++i) {
        const int m = mb + i;
        if (MODE != 0 && m >= cnt) continue;
        float v = acc[mi][ni][i];
        const size_t cidx = (size_t)m * N + n;
        if constexpr (EPI == 0) {
          if (bias) v += bias[n];
          ((float*)Cv)[cidx] = v;
        } else if constexpr (EPI == 1) {
          ((float*)Cv)[cidx] = aux0[n] * (v + bias[n]) + aux1[cidx];
        } else if constexpr (EPI == 2) {
          const int tk = idx[m];
          ((float*)Cv)[(size_t)tk * N + n] += wdp[(size_t)tk * 4] * v;
        } else if constexpr (EPI == 3) {
          ((float*)Cv)[cidx] = aux0[n] * (aux2[cidx] + v) + aux1[cidx];
        } else {
          if (bias) v += bias[n];
          ((unsigned short*)Cv)[cidx] = f2h(v);
        }
      }
    }
  }
}

// ---------------- host ----------------

extern "C" void kernel_launch(void* const* d_in, const int* in_sizes, int n_in,
                              void* d_out, int out_size, void* d_ws, size_t ws_size,
                              hipStream_t stream) {
  (void)in_sizes; (void)n_in; (void)out_size; (void)ws_size;
  const float* hs = (const float*)d_in[0];
  const float* temb = (const float*)d_in[1];
  const float* rope = (const float*)d_in[2];
  const float* adaw = (const float*)d_in[3];
  const float* adab = (const float*)d_in[4];
  const float* qkvw = (const float*)d_in[5];
  const float* qkvb = (const float*)d_in[6];
  const float* qnw = (const float*)d_in[7];
  const float* knw = (const float*)d_in[8];
  const float* outw = (const float*)d_in[9];
  const float* outb = (const float*)d_in[10];
  const float* gatew = (const float*)d_in[11];
  const float* ew1 = (const float*)d_in[12];
  const float* ew2 = (const float*)d_in[13];
  const float* ew3 = (const float*)d_in[14];
  const float* sw1 = (const float*)d_in[15];
  const float* sw2 = (const float*)d_in[16];
  const float* sw3 = (const float*)d_in[17];
  float* out = (float*)d_out;
  char* ws = (char*)d_ws;

  size_t off = 0;
  auto give = [&](size_t nbytes) {
    size_t r = off;
    off += (nbytes + 255) & ~(size_t)255;
    return r;
  };
  const size_t T = T_TOK, D = DIM;
  size_t o_mod = give(15360 * 4);
  size_t o_ss = give(D * 4);
  size_t o_wd = give(T * 4 * 4);
  size_t o_idx = give(4 * 2048 * 4);
  size_t o_cnt = give(4 * 4);
  size_t o_nh = give(T * D * 2);      // nh fp16; later nh2
  size_t o_qkvh = give(T * 7680 * 2); // qkv fp16; later h1 compact
  size_t o_qh = give(T * D * 2);      // qh..vt later h3 compact (3x10.5MB)
  size_t o_kh = give(T * D * 2);
  size_t o_vt = give(T * D * 2);
  size_t o_obf = give(T * D * 2);
  size_t o_h2 = give(T * D * 4);
  size_t o_y = give(T * D * 4);
  size_t o_hmid = give(T * HID_E * 2);
  // fp16 weights
  size_t o_qkvw = give((size_t)7680 * 2560 * 2);
  size_t o_outw = give((size_t)2560 * 2560 * 2);
  size_t o_ew1 = give((size_t)4 * HID_E * 2560 * 2);
  size_t o_ew2 = give((size_t)4 * 2560 * HID_E * 2);
  size_t o_ew3 = give((size_t)4 * HID_E * 2560 * 2);
  size_t o_sw1 = give((size_t)SHID_E * 2560 * 2);
  size_t o_sw2 = give((size_t)2560 * SHID_E * 2);
  size_t o_sw3 = give((size_t)SHID_E * 2560 * 2);

  float* mod = (float*)(ws + o_mod);
  float* ss = (float*)(ws + o_ss);
  float* wd = (float*)(ws + o_wd);
  int* idxb = (int*)(ws + o_idx);
  int* cnt = (int*)(ws + o_cnt);
  unsigned short* nh_h = (unsigned short*)(ws + o_nh);
  unsigned short* qkvh = (unsigned short*)(ws + o_qkvh);
  unsigned short* qh = (unsigned short*)(ws + o_qh);
  unsigned short* kh = (unsigned short*)(ws + o_kh);
  unsigned short* vt = (unsigned short*)(ws + o_vt);
  unsigned short* obf = (unsigned short*)(ws + o_obf);
  float* h2 = (float*)(ws + o_h2);
  float* ybuf = (float*)(ws + o_y);
  unsigned short* hmid = (unsigned short*)(ws + o_hmid);
  unsigned short* qkvw_h = (unsigned short*)(ws + o_qkvw);
  unsigned short* outw_h = (unsigned short*)(ws + o_outw);
  unsigned short* ew1_h = (unsigned short*)(ws + o_ew1);
  unsigned short* ew2_h = (unsigned short*)(ws + o_ew2);
  unsigned short* ew3_h = (unsigned short*)(ws + o_ew3);
  unsigned short* sw1_h = (unsigned short*)(ws + o_sw1);
  unsigned short* sw2_h = (unsigned short*)(ws + o_sw2);
  unsigned short* sw3_h = (unsigned short*)(ws + o_sw3);
  unsigned short* nh2 = nh_h;
  unsigned short* h1buf = qkvh;
  unsigned short* h3buf = qh;

  // 0) weight conversion f32 -> fp16
  cvt_f16<<<2048, 256, 0, stream>>>(qkvw, qkvw_h, 7680 * 2560 / 8);
  cvt_f16<<<2048, 256, 0, stream>>>(outw, outw_h, 2560 * 2560 / 8);
  cvt_f16<<<2048, 256, 0, stream>>>(ew1, ew1_h, 4 * HID_E * 2560 / 8);
  cvt_f16<<<2048, 256, 0, stream>>>(ew2, ew2_h, 4 * 2560 * HID_E / 8);
  cvt_f16<<<2048, 256, 0, stream>>>(ew3, ew3_h, 4 * HID_E * 2560 / 8);
  cvt_f16<<<2048, 256, 0, stream>>>(sw1, sw1_h, SHID_E * 2560 / 8);
  cvt_f16<<<2048, 256, 0, stream>>>(sw2, sw2_h, 2560 * SHID_E / 8);
  cvt_f16<<<2048, 256, 0, stream>>>(sw3, sw3_h, SHID_E * 2560 / 8);
  // 1) adaLN modulation
  silu_k<<<10, 256, 0, stream>>>(temb, ss);
  adaln_gemv<<<3840, 256, 0, stream>>>(ss, adaw, adab, mod);
  // 2) LN1 + modulate (fp16)
  ln_mod<<<T, 256, 0, stream>>>(hs, mod, mod + D, nh_h);
  // 3) qkv GEMM -> fp16
  gemm128<4, 0><<<60 * 16, 256, 0, stream>>>(nh_h, qkvw_h, qkvb, qkvh,
                                             nullptr, nullptr, nullptr, nullptr, nullptr,
                                             nullptr, 60, 2048, 7680, 2560);
  // 4) RMSNorm + RoPE
  rmsrope<<<T, 256, 0, stream>>>(qkvh, qnw, knw, rope, qh, kh);
  // 5) V transpose
  transpose_v<<<dim3(80, 64), dim3(32, 8), 0, stream>>>(qkvh, vt);
  // 6) MFMA flash attention
  fattn<<<dim3(32, 20), 256, 0, stream>>>(qh, kh, vt, obf);
  // 7) out proj + gate_msa residual -> h2 f32
  gemm128<1, 0><<<20 * 16, 256, 0, stream>>>(obf, outw_h, outb, h2,
                                             mod + 2 * D, hs, nullptr, nullptr, nullptr,
                                             nullptr, 20, 2048, 2560, 2560);
  // 8) LN2 + modulate + routing, then compaction
  ln2_route<<<T, 256, 0, stream>>>(h2, mod + 3 * D, mod + 4 * D, gatew, nh2, wd);
  route_compact<<<1, 256, 0, stream>>>(wd, idxb, cnt);
  // 9) MoE experts (top-2 sparse, gathered)
  hipMemsetAsync(ybuf, 0, T * D * 4, stream);
  for (int e = 0; e < 4; ++e) {
    const unsigned short* w1 = ew1_h + (size_t)e * HID_E * DIM;
    const unsigned short* w3 = ew3_h + (size_t)e * HID_E * DIM;
    const unsigned short* w2 = ew2_h + (size_t)e * DIM * HID_E;
    gemm128<4, 1><<<54 * 16, 256, 0, stream>>>(nh2, w1, nullptr, h1buf,
                                               nullptr, nullptr, nullptr, idxb + e * 2048,
                                               cnt + e, nullptr, 54, 2048, 6912, 2560);
    gemm128<4, 1><<<54 * 16, 256, 0, stream>>>(nh2, w3, nullptr, h3buf,
                                               nullptr, nullptr, nullptr, idxb + e * 2048,
                                               cnt + e, nullptr, 54, 2048, 6912, 2560);
    swiglu_mul<<<2048, 256, 0, stream>>>(h1buf, h3buf, hmid, cnt + e, HID_E / 8, 0);
    gemm128<2, 2><<<20 * 16, 256, 0, stream>>>(hmid, w2, nullptr, ybuf,
                                               nullptr, nullptr, nullptr, idxb + e * 2048,
                                               cnt + e, wd + e, 20, 2048, 2560, 6912);
  }
  // 10) shared expert + final combine
  gemm128<4, 0><<<28 * 16, 256, 0, stream>>>(nh2, sw1_h, nullptr, h1buf,
                                             nullptr, nullptr, nullptr, nullptr, nullptr,
                                             nullptr, 28, 2048, 3584, 2560);
  gemm128<4, 0><<<28 * 16, 256, 0, stream>>>(nh2, sw3_h, nullptr, h3buf,
                                             nullptr, nullptr, nullptr, nullptr, nullptr,
                                             nullptr, 28, 2048, 3584, 2560);
  swiglu_mul<<<2048, 256, 0, stream>>>(h1buf, h3buf, hmid, nullptr, 0, (int)(T * SHID_E / 8));
  gemm128<3, 0><<<20 * 16, 256, 0, stream>>>(hmid, sw2_h, nullptr, out,
                                             mod + 5 * D, h2, ybuf, nullptr, nullptr,
                                             nullptr, 20, 2048, 2560, 3584);
}

// Round 4
// 2495.367 us; speedup vs baseline: 2.1234x; 1.1587x over previous
//
#include <hip/hip_runtime.h>

#define DIM 2560
#define T_TOK 2048
#define NHEADS 20
#define HD 128
#define HID_E 6912
#define SHID_E 3584

typedef _Float16 f16x8 __attribute__((ext_vector_type(8)));
typedef float f32x4 __attribute__((ext_vector_type(4)));
typedef unsigned short u16x8 __attribute__((ext_vector_type(8)));

#define MFMA16(a, b, c) __builtin_amdgcn_mfma_f32_16x16x32_f16((a), (b), (c), 0, 0, 0)

__device__ inline unsigned short f2h(float f) {
  return __builtin_bit_cast(unsigned short, (_Float16)f);
}
__device__ inline float h2f(unsigned short u) {
  return (float)__builtin_bit_cast(_Float16, u);
}
__device__ inline float wave_sum(float v) {
#pragma unroll
  for (int off = 32; off > 0; off >>= 1) v += __shfl_down(v, off, 64);
  return v;
}
// async global->LDS, 16B per lane; LDS dest = wave-uniform base + lane*16
__device__ inline void gld16(const void* g, void* l) {
  __builtin_amdgcn_global_load_lds((const __attribute__((address_space(1))) void*)g,
                                   (__attribute__((address_space(3))) void*)l, 16, 0, 0);
}

// ---------------- tiny kernels ----------------

__global__ __launch_bounds__(256) void silu_k(const float* __restrict__ t,
                                              float* __restrict__ ss) {
  int i = blockIdx.x * 256 + threadIdx.x;
  if (i < DIM) {
    float v = t[i];
    ss[i] = v / (1.f + expf(-v));
  }
}

__global__ __launch_bounds__(256) void cvt_f16(const float* __restrict__ in,
                                               unsigned short* __restrict__ outp, int n8) {
  const int stride = gridDim.x * 256;
  for (int i = blockIdx.x * 256 + threadIdx.x; i < n8; i += stride) {
    float4 a = *(const float4*)(in + (size_t)i * 8);
    float4 b = *(const float4*)(in + (size_t)i * 8 + 4);
    u16x8 u;
    u[0] = f2h(a.x); u[1] = f2h(a.y); u[2] = f2h(a.z); u[3] = f2h(a.w);
    u[4] = f2h(b.x); u[5] = f2h(b.y); u[6] = f2h(b.z); u[7] = f2h(b.w);
    *(u16x8*)&outp[(size_t)i * 8] = u;
  }
}

// interleave w1/w3 rows into B' : row j -> (j&31)<16 ? w1[(j>>5)*16+(j&15)]
//                                          : w3[(j>>5)*16+(j&15)]
__global__ __launch_bounds__(256) void cvt_pair(const float* __restrict__ w1,
                                                const float* __restrict__ w3,
                                                unsigned short* __restrict__ outp) {
  const int j = blockIdx.x;
  const int g = j >> 5, r = j & 31;
  const float* src = (r < 16) ? (w1 + (size_t)(g * 16 + r) * DIM)
                              : (w3 + (size_t)(g * 16 + (r & 15)) * DIM);
  unsigned short* dst = outp + (size_t)j * DIM;
  for (int i = threadIdx.x; i < 320; i += 256) {
    float4 a = *(const float4*)(src + i * 8);
    float4 b = *(const float4*)(src + i * 8 + 4);
    u16x8 u;
    u[0] = f2h(a.x); u[1] = f2h(a.y); u[2] = f2h(a.z); u[3] = f2h(a.w);
    u[4] = f2h(b.x); u[5] = f2h(b.y); u[6] = f2h(b.z); u[7] = f2h(b.w);
    *(u16x8*)&dst[i * 8] = u;
  }
}

// mod[j] = dot(silu(temb), adaln_w[j]) + adaln_b[j]; one wave per output
__global__ __launch_bounds__(256) void adaln_gemv(const float* __restrict__ ss,
                                                  const float* __restrict__ W,
                                                  const float* __restrict__ bias,
                                                  float* __restrict__ mod) {
  const int lane = threadIdx.x & 63;
  const int j = blockIdx.x * 4 + (threadIdx.x >> 6);
  const float* wr = W + (size_t)j * DIM;
  float p = 0.f;
  for (int i = lane; i < 640; i += 64) {
    float4 w = *(const float4*)(wr + i * 4);
    float4 x = *(const float4*)(ss + i * 4);
    p += w.x * x.x + w.y * x.y + w.z * x.z + w.w * x.w;
  }
  p = wave_sum(p);
  if (lane == 0) mod[j] = p + bias[j];
}

// LN (no affine) then *(1+scale)+shift, write fp16. One block per row.
__global__ __launch_bounds__(256) void ln_mod(const float* __restrict__ x,
                                              const float* __restrict__ shift,
                                              const float* __restrict__ scale,
                                              unsigned short* __restrict__ outp) {
  __shared__ float rbuf[8];
  const int t = blockIdx.x, tid = threadIdx.x, lane = tid & 63, wid = tid >> 6;
  const float* xr = x + (size_t)t * DIM;
  float s = 0.f, sq = 0.f;
  for (int i = tid; i < 640; i += 256) {
    float4 v = *(const float4*)(xr + i * 4);
    s += v.x + v.y + v.z + v.w;
    sq += v.x * v.x + v.y * v.y + v.z * v.z + v.w * v.w;
  }
  s = wave_sum(s);
  sq = wave_sum(sq);
  if (lane == 0) {
    rbuf[wid] = s;
    rbuf[4 + wid] = sq;
  }
  __syncthreads();
  float S = rbuf[0] + rbuf[1] + rbuf[2] + rbuf[3];
  float SQ = rbuf[4] + rbuf[5] + rbuf[6] + rbuf[7];
  float mean = S * (1.f / DIM);
  float rs = rsqrtf(SQ * (1.f / DIM) - mean * mean + 1e-6f);
  for (int i = tid; i < 640; i += 256) {
    float4 v = *(const float4*)(xr + i * 4);
    float4 sc4 = *(const float4*)(scale + i * 4);
    float4 sh4 = *(const float4*)(shift + i * 4);
    ushort4 u;
    u.x = f2h((v.x - mean) * rs * (1.f + sc4.x) + sh4.x);
    u.y = f2h((v.y - mean) * rs * (1.f + sc4.y) + sh4.y);
    u.z = f2h((v.z - mean) * rs * (1.f + sc4.z) + sh4.z);
    u.w = f2h((v.w - mean) * rs * (1.f + sc4.w) + sh4.w);
    *(ushort4*)&outp[(size_t)t * DIM + i * 4] = u;
  }
}

// RMSNorm(q),(k) over full 2560 + weight + RoPE -> qh (scaled by 1/sqrt(128)), kh
__global__ __launch_bounds__(256) void rmsrope(const unsigned short* __restrict__ qkv,
                                               const float* __restrict__ qn,
                                               const float* __restrict__ kn,
                                               const float* __restrict__ rope,
                                               unsigned short* __restrict__ qh,
                                               unsigned short* __restrict__ kh) {
  __shared__ float rbuf[8];
  const int t = blockIdx.x, tid = threadIdx.x, lane = tid & 63, wid = tid >> 6;
  const unsigned short* row = qkv + (size_t)t * 7680;
  float sq = 0.f, sk = 0.f;
  for (int i = tid; i < 320; i += 256) {
    f16x8 qv = *(const f16x8*)(row + i * 8);
    f16x8 kv = *(const f16x8*)(row + DIM + i * 8);
#pragma unroll
    for (int j = 0; j < 8; ++j) {
      float q = (float)qv[j], k = (float)kv[j];
      sq += q * q;
      sk += k * k;
    }
  }
  sq = wave_sum(sq);
  sk = wave_sum(sk);
  if (lane == 0) {
    rbuf[wid] = sq;
    rbuf[4 + wid] = sk;
  }
  __syncthreads();
  float SQ = rbuf[0] + rbuf[1] + rbuf[2] + rbuf[3];
  float SK = rbuf[4] + rbuf[5] + rbuf[6] + rbuf[7];
  float rq = rsqrtf(SQ * (1.f / DIM) + 1e-6f) * 0.08838834764831845f;
  float rk = rsqrtf(SK * (1.f / DIM) + 1e-6f);
  for (int pp = tid; pp < 1280; pp += 256) {
    int c = pp * 2;
    float qe = h2f(row[c]) * rq * qn[c], qo = h2f(row[c + 1]) * rq * qn[c + 1];
    float ke = h2f(row[DIM + c]) * rk * kn[c], ko = h2f(row[DIM + c + 1]) * rk * kn[c + 1];
    float4 rr = *(const float4*)(rope + (size_t)t * 256 + (pp & 63) * 4);
    unsigned qp = (unsigned)f2h(rr.x * qe + rr.y * qo) |
                  ((unsigned)f2h(rr.z * qe + rr.w * qo) << 16);
    unsigned kp = (unsigned)f2h(rr.x * ke + rr.y * ko) |
                  ((unsigned)f2h(rr.z * ke + rr.w * ko) << 16);
    *(unsigned*)&qh[(size_t)t * DIM + c] = qp;
    *(unsigned*)&kh[(size_t)t * DIM + c] = kp;
  }
}

// V part of qkv (fp16 [2048][7680] at col 5120) -> vt fp16 [2560][2048]
__global__ void transpose_v(const unsigned short* __restrict__ in,
                            unsigned short* __restrict__ outp) {
  __shared__ unsigned short tile[32][33];
  const int bx = blockIdx.x * 32;  // channel
  const int by = blockIdx.y * 32;  // token
  const int tx = threadIdx.x, ty = threadIdx.y;
  for (int j = ty; j < 32; j += 8)
    tile[j][tx] = in[(size_t)(by + j) * 7680 + 5120 + bx + tx];
  __syncthreads();
  for (int j = ty; j < 32; j += 8)
    outp[(size_t)(bx + j) * T_TOK + by + tx] = tile[tx][j];
}

// ---------------- MFMA flash attention ----------------
__global__ __launch_bounds__(256) void fattn(const unsigned short* __restrict__ qh,
                                             const unsigned short* __restrict__ kh,
                                             const unsigned short* __restrict__ vt,
                                             unsigned short* __restrict__ obuf) {
  __shared__ unsigned short sK[64 * 128];  // [k][d], slot = c ^ (r&15)
  __shared__ unsigned short sV[128 * 64];  // [d][k], slot = c ^ (r&7)
  __shared__ unsigned short sP[64 * 64];   // [q][k], slot = c ^ (r&7)
  __shared__ float sRedM[4][64];
  __shared__ float sRedL[4][64];
  __shared__ float sM[64];
  __shared__ float sL[64];
  const int tid = threadIdx.x, lane = tid & 63, wv = tid >> 6;
  const int g = lane >> 4, fr = lane & 15;
  const int h = blockIdx.y;
  const int q0 = blockIdx.x * 64;

  {
    const int r = tid >> 2, qt = tid & 3;
    const unsigned short* gp = qh + (size_t)(q0 + r) * DIM + h * HD + qt * 32;
    uint4 v0 = ((const uint4*)gp)[0];
    uint4 v1 = ((const uint4*)gp)[1];
    uint4 v2 = ((const uint4*)gp)[2];
    uint4 v3 = ((const uint4*)gp)[3];
    unsigned short* dst = &sK[r * 128];
    const int cb = qt * 4, rs = r & 15;
    *(uint4*)&dst[((cb + 0) ^ rs) * 8] = v0;
    *(uint4*)&dst[((cb + 1) ^ rs) * 8] = v1;
    *(uint4*)&dst[((cb + 2) ^ rs) * 8] = v2;
    *(uint4*)&dst[((cb + 3) ^ rs) * 8] = v3;
  }
  __syncthreads();
  f16x8 qfrag[4][4];
#pragma unroll
  for (int ni = 0; ni < 4; ++ni) {
#pragma unroll
    for (int kt = 0; kt < 4; ++kt) {
      int r = ni * 16 + fr;
      qfrag[ni][kt] = *(const f16x8*)&sK[r * 128 + (((kt * 4 + g) ^ (r & 15)) << 3)];
    }
  }
  __syncthreads();

  f32x4 acco[4][2];
  f32x4 mprev[4];
  float mrun[4], lrun[4];
#pragma unroll
  for (int i = 0; i < 4; ++i) {
    acco[i][0] = (f32x4)0.f;
    acco[i][1] = (f32x4)0.f;
    mprev[i] = (f32x4)(-1e30f);
    mrun[i] = -1e30f;
    lrun[i] = 0.f;
  }

  for (int kt0 = 0; kt0 < T_TOK; kt0 += 64) {
    {
      const int r = tid >> 2, qt = tid & 3;
      const unsigned short* gp = kh + (size_t)(kt0 + r) * DIM + h * HD + qt * 32;
      uint4 v0 = ((const uint4*)gp)[0];
      uint4 v1 = ((const uint4*)gp)[1];
      uint4 v2 = ((const uint4*)gp)[2];
      uint4 v3 = ((const uint4*)gp)[3];
      unsigned short* dst = &sK[r * 128];
      const int cb = qt * 4, rs = r & 15;
      *(uint4*)&dst[((cb + 0) ^ rs) * 8] = v0;
      *(uint4*)&dst[((cb + 1) ^ rs) * 8] = v1;
      *(uint4*)&dst[((cb + 2) ^ rs) * 8] = v2;
      *(uint4*)&dst[((cb + 3) ^ rs) * 8] = v3;
      const int rv = tid >> 1, hf = tid & 1;
      const unsigned short* gv = vt + (size_t)(h * HD + rv) * T_TOK + kt0 + hf * 32;
      uint4 w0 = ((const uint4*)gv)[0];
      uint4 w1 = ((const uint4*)gv)[1];
      uint4 w2 = ((const uint4*)gv)[2];
      uint4 w3 = ((const uint4*)gv)[3];
      unsigned short* dv = &sV[rv * 64];
      const int cv = hf * 4, rvs = rv & 7;
      *(uint4*)&dv[((cv + 0) ^ rvs) * 8] = w0;
      *(uint4*)&dv[((cv + 1) ^ rvs) * 8] = w1;
      *(uint4*)&dv[((cv + 2) ^ rvs) * 8] = w2;
      *(uint4*)&dv[((cv + 3) ^ rvs) * 8] = w3;
    }
    __syncthreads();  // B0

    f32x4 accs[4] = {(f32x4)0.f, (f32x4)0.f, (f32x4)0.f, (f32x4)0.f};
#pragma unroll
    for (int kt = 0; kt < 4; ++kt) {
      int r = wv * 16 + fr;
      f16x8 ak = *(const f16x8*)&sK[r * 128 + (((kt * 4 + g) ^ (r & 15)) << 3)];
#pragma unroll
      for (int ni = 0; ni < 4; ++ni) accs[ni] = MFMA16(ak, qfrag[ni][kt], accs[ni]);
    }

    float pm[4];
#pragma unroll
    for (int ni = 0; ni < 4; ++ni) {
      float m = fmaxf(fmaxf(accs[ni][0], accs[ni][1]), fmaxf(accs[ni][2], accs[ni][3]));
      m = fmaxf(m, __shfl_xor(m, 16));
      m = fmaxf(m, __shfl_xor(m, 32));
      pm[ni] = m;
    }
    if (g == 0) {
#pragma unroll
      for (int ni = 0; ni < 4; ++ni) sRedM[wv][ni * 16 + fr] = pm[ni];
    }
    __syncthreads();  // B1
    float mnew[4];
#pragma unroll
    for (int ni = 0; ni < 4; ++ni) {
      int q = ni * 16 + fr;
      float mt = fmaxf(fmaxf(sRedM[0][q], sRedM[1][q]), fmaxf(sRedM[2][q], sRedM[3][q]));
      mnew[ni] = fmaxf(mrun[ni], mt);
    }
    float lsum[4];
#pragma unroll
    for (int ni = 0; ni < 4; ++ni) {
      float l0 = 0.f;
#pragma unroll
      for (int i = 0; i < 4; ++i) {
        float p = __expf(accs[ni][i] - mnew[ni]);
        accs[ni][i] = p;
        l0 += p;
      }
      l0 += __shfl_xor(l0, 16);
      l0 += __shfl_xor(l0, 32);
      lsum[ni] = l0;
    }
    if (g == 0) {
#pragma unroll
      for (int ni = 0; ni < 4; ++ni) sRedL[wv][ni * 16 + fr] = lsum[ni];
      if (wv == 0) {
#pragma unroll
        for (int ni = 0; ni < 4; ++ni) sM[ni * 16 + fr] = mnew[ni];
      }
    }
#pragma unroll
    for (int ni = 0; ni < 4; ++ni) {
      int q = ni * 16 + fr;
      unsigned p01 = (unsigned)f2h(accs[ni][0]) | ((unsigned)f2h(accs[ni][1]) << 16);
      unsigned p23 = (unsigned)f2h(accs[ni][2]) | ((unsigned)f2h(accs[ni][3]) << 16);
      uint2 pk;
      pk.x = p01;
      pk.y = p23;
      *(uint2*)&sP[q * 64 + ((((wv << 1) | (g >> 1)) ^ (q & 7)) << 3) + ((g & 1) << 2)] = pk;
    }
    __syncthreads();  // B2
#pragma unroll
    for (int ni = 0; ni < 4; ++ni) {
      int q = ni * 16 + fr;
      float lt = sRedL[0][q] + sRedL[1][q] + sRedL[2][q] + sRedL[3][q];
      lrun[ni] = lrun[ni] * __expf(mrun[ni] - mnew[ni]) + lt;
      mrun[ni] = mnew[ni];
    }

#pragma unroll
    for (int mi = 0; mi < 4; ++mi) {
      f32x4 mn = *(const f32x4*)&sM[mi * 16 + g * 4];
      f32x4 sc;
#pragma unroll
      for (int i = 0; i < 4; ++i) sc[i] = __expf(mprev[mi][i] - mn[i]);
      acco[mi][0] *= sc;
      acco[mi][1] *= sc;
      mprev[mi] = mn;
    }
#pragma unroll
    for (int ktp = 0; ktp < 2; ++ktp) {
      f16x8 bv[2];
#pragma unroll
      for (int nd = 0; nd < 2; ++nd) {
        int r = wv * 32 + nd * 16 + fr;
        bv[nd] = *(const f16x8*)&sV[r * 64 + (((ktp * 4 + g) ^ (r & 7)) << 3)];
      }
#pragma unroll
      for (int mi = 0; mi < 4; ++mi) {
        int r = mi * 16 + fr;
        f16x8 ap = *(const f16x8*)&sP[r * 64 + (((ktp * 4 + g) ^ (r & 7)) << 3)];
        acco[mi][0] = MFMA16(ap, bv[0], acco[mi][0]);
        acco[mi][1] = MFMA16(ap, bv[1], acco[mi][1]);
      }
    }
    __syncthreads();  // B3
  }

  if (wv == 0 && g == 0) {
#pragma unroll
    for (int ni = 0; ni < 4; ++ni) sL[ni * 16 + fr] = 1.f / lrun[ni];
  }
  __syncthreads();
#pragma unroll
  for (int mi = 0; mi < 4; ++mi) {
    f32x4 li = *(const f32x4*)&sL[mi * 16 + g * 4];
#pragma unroll
    for (int nd = 0; nd < 2; ++nd) {
#pragma unroll
      for (int i = 0; i < 4; ++i) {
        float o = acco[mi][nd][i] * li[i];
        obuf[(size_t)(q0 + mi * 16 + g * 4 + i) * DIM + h * HD + wv * 32 + nd * 16 + fr] =
            f2h(o);
      }
    }
  }
}

// LN2 + modulate -> nh2 fp16, plus f32 routing (softmax over 4, top-2, unnormalized)
__global__ __launch_bounds__(256) void ln2_route(const float* __restrict__ x,
                                                 const float* __restrict__ shift,
                                                 const float* __restrict__ scale,
                                                 const float* __restrict__ gw,
                                                 unsigned short* __restrict__ nh2,
                                                 float* __restrict__ wd) {
  __shared__ float rbuf[8];
  __shared__ float gbuf[4][4];
  const int t = blockIdx.x, tid = threadIdx.x, lane = tid & 63, wid = tid >> 6;
  const float* xr = x + (size_t)t * DIM;
  float s = 0.f, sq = 0.f;
  for (int i = tid; i < 640; i += 256) {
    float4 v = *(const float4*)(xr + i * 4);
    s += v.x + v.y + v.z + v.w;
    sq += v.x * v.x + v.y * v.y + v.z * v.z + v.w * v.w;
  }
  s = wave_sum(s);
  sq = wave_sum(sq);
  if (lane == 0) {
    rbuf[wid] = s;
    rbuf[4 + wid] = sq;
  }
  __syncthreads();
  float S = rbuf[0] + rbuf[1] + rbuf[2] + rbuf[3];
  float SQ = rbuf[4] + rbuf[5] + rbuf[6] + rbuf[7];
  float mean = S * (1.f / DIM);
  float rs = rsqrtf(SQ * (1.f / DIM) - mean * mean + 1e-6f);
  float g0 = 0.f, g1 = 0.f, g2 = 0.f, g3 = 0.f;
  for (int i = tid; i < 640; i += 256) {
    float4 v = *(const float4*)(xr + i * 4);
    float4 sc4 = *(const float4*)(scale + i * 4);
    float4 sh4 = *(const float4*)(shift + i * 4);
    float y0 = (v.x - mean) * rs * (1.f + sc4.x) + sh4.x;
    float y1 = (v.y - mean) * rs * (1.f + sc4.y) + sh4.y;
    float y2 = (v.z - mean) * rs * (1.f + sc4.z) + sh4.z;
    float y3 = (v.w - mean) * rs * (1.f + sc4.w) + sh4.w;
    ushort4 u;
    u.x = f2h(y0); u.y = f2h(y1); u.z = f2h(y2); u.w = f2h(y3);
    *(ushort4*)&nh2[(size_t)t * DIM + i * 4] = u;
    float4 w0 = *(const float4*)(gw + i * 4);
    float4 w1 = *(const float4*)(gw + DIM + i * 4);
    float4 w2 = *(const float4*)(gw + 2 * DIM + i * 4);
    float4 w3 = *(const float4*)(gw + 3 * DIM + i * 4);
    g0 += y0 * w0.x + y1 * w0.y + y2 * w0.z + y3 * w0.w;
    g1 += y0 * w1.x + y1 * w1.y + y2 * w1.z + y3 * w1.w;
    g2 += y0 * w2.x + y1 * w2.y + y2 * w2.z + y3 * w2.w;
    g3 += y0 * w3.x + y1 * w3.y + y2 * w3.z + y3 * w3.w;
  }
  g0 = wave_sum(g0);
  g1 = wave_sum(g1);
  g2 = wave_sum(g2);
  g3 = wave_sum(g3);
  if (lane == 0) {
    gbuf[wid][0] = g0; gbuf[wid][1] = g1; gbuf[wid][2] = g2; gbuf[wid][3] = g3;
  }
  __syncthreads();
  if (tid == 0) {
    float l[4];
#pragma unroll
    for (int e = 0; e < 4; ++e) l[e] = gbuf[0][e] + gbuf[1][e] + gbuf[2][e] + gbuf[3][e];
    float mx = fmaxf(fmaxf(l[0], l[1]), fmaxf(l[2], l[3]));
    float ex[4], sum = 0.f;
#pragma unroll
    for (int e = 0; e < 4; ++e) { ex[e] = expf(l[e] - mx); sum += ex[e]; }
    float p[4];
#pragma unroll
    for (int e = 0; e < 4; ++e) p[e] = ex[e] / sum;
    int i1 = 0;
    for (int e = 1; e < 4; ++e)
      if (p[e] > p[i1]) i1 = e;
    int i2 = -1;
    for (int e = 0; e < 4; ++e) {
      if (e == i1) continue;
      if (i2 < 0 || p[e] > p[i2]) i2 = e;
    }
    float w[4] = {0.f, 0.f, 0.f, 0.f};
    w[i1] = p[i1];
    w[i2] = p[i2];
    *(float4*)&wd[(size_t)t * 4] = make_float4(w[0], w[1], w[2], w[3]);
  }
}

// deterministic token-ordered top-2 compaction; 1 block, 256 threads, 8 tokens each
__global__ __launch_bounds__(256) void route_compact(const float* __restrict__ wd,
                                                     int* __restrict__ idxbuf,
                                                     int* __restrict__ cnt) {
  __shared__ unsigned short c[256][4];
  __shared__ int offs[256][4];
  const int t = threadIdx.x;
  unsigned char sel[8];
  unsigned short lc[4] = {0, 0, 0, 0};
#pragma unroll
  for (int k = 0; k < 8; ++k) {
    int tok = t * 8 + k;
    float4 w = *(const float4*)&wd[(size_t)tok * 4];
    unsigned m = 0;
    if (w.x != 0.f) { m |= 1; lc[0]++; }
    if (w.y != 0.f) { m |= 2; lc[1]++; }
    if (w.z != 0.f) { m |= 4; lc[2]++; }
    if (w.w != 0.f) { m |= 8; lc[3]++; }
    sel[k] = (unsigned char)m;
  }
#pragma unroll
  for (int e = 0; e < 4; ++e) c[t][e] = lc[e];
  __syncthreads();
  if (t == 0) {
    int run[4] = {0, 0, 0, 0};
    for (int i = 0; i < 256; ++i) {
#pragma unroll
      for (int e = 0; e < 4; ++e) {
        offs[i][e] = run[e];
        run[e] += c[i][e];
      }
    }
#pragma unroll
    for (int e = 0; e < 4; ++e) cnt[e] = run[e];
  }
  __syncthreads();
  int o[4];
#pragma unroll
  for (int e = 0; e < 4; ++e) o[e] = offs[t][e];
#pragma unroll
  for (int k = 0; k < 8; ++k) {
    int tok = t * 8 + k;
    unsigned m = sel[k];
#pragma unroll
    for (int e = 0; e < 4; ++e) {
      if ((m >> e) & 1) idxbuf[e * 2048 + o[e]++] = tok;
    }
  }
}

// ---------------- GEMM: C[M,N] = A[M,K](fp16) @ B[N,K](fp16)^T ----------------
// 128x128 tile, BK=32, 4 waves, 2-phase double-buffered global_load_lds prefetch:
// per K-step: STAGE(next) -> ds_read+MFMA(cur) -> barrier (drains vmcnt).
// MODE: 0 dense | 1 A-gather via idx, compact C | 2 compact A, scatter C.
// EPI: 1 f32 aux0[n]*(v+bias)+aux1 | 2 scatter C[tok*N+n] += wd[tok]*v |
//      3 f32 aux0[n]*(aux2+v)+aux1 | 4 fp16(+bias) | 5 fused swiglu -> fp16, Nh=N/2
template <int EPI, int MODE>
__global__ __launch_bounds__(256) void gemm128(
    const unsigned short* __restrict__ A, const unsigned short* __restrict__ B,
    const float* __restrict__ bias, void* __restrict__ Cv,
    const float* __restrict__ aux0, const float* __restrict__ aux1,
    const float* __restrict__ aux2, const int* __restrict__ idx,
    const int* __restrict__ cntp, const float* __restrict__ wdp,
    int gx, int M, int N, int K) {
  __shared__ unsigned short smem[16384];  // 2 bufs x (A 4096 + B 4096)
  const int tid = threadIdx.x;
  const int lane = tid & 63;
  const int wv = tid >> 6;
  // XCD-aware bijective swizzle (grid always %8==0)
  const int nwg = gridDim.x;
  const int bid = blockIdx.x;
  const int swzb = (bid & 7) * (nwg >> 3) + (bid >> 3);
  const int m0 = (swzb / gx) * 128, n0 = (swzb % gx) * 128;
  const int cnt = (MODE != 0) ? *cntp : M;
  if (MODE != 0 && m0 >= cnt) return;

  const int wm = (wv >> 1) * 64, wn = (wv & 1) * 64;
  const int fr = lane & 15, fc = lane >> 4;

  // staging geometry: wave wv stages rows [wv*16, wv*16+16) and [64+wv*16, ...)
  const int rl = lane >> 2, ch = lane & 3;
  const int R1 = wv * 16 + rl;
  const int R2 = 64 + R1;
  const int co1 = ((ch ^ ((R1 >> 1) & 3)) << 3);
  const int co2 = ((ch ^ ((R2 >> 1) & 3)) << 3);
  size_t ar1, ar2;
  if constexpr (MODE == 1) {
    int i1 = m0 + R1, i2 = m0 + R2;
    i1 = i1 < cnt ? i1 : cnt - 1;
    i2 = i2 < cnt ? i2 : cnt - 1;
    ar1 = (size_t)idx[i1] * K;
    ar2 = (size_t)idx[i2] * K;
  } else {
    ar1 = (size_t)(m0 + R1) * K;
    ar2 = (size_t)(m0 + R2) * K;
  }
  const unsigned short* gA1 = A + ar1 + co1;
  const unsigned short* gA2 = A + ar2 + co2;
  const unsigned short* gB1 = B + (size_t)(n0 + R1) * K + co1;
  const unsigned short* gB2 = B + (size_t)(n0 + R2) * K + co2;
  const int lA1 = (wv * 16) * 32, lA2 = (64 + wv * 16) * 32;

  f32x4 acc[4][4];
#pragma unroll
  for (int i = 0; i < 4; ++i) {
#pragma unroll
    for (int j = 0; j < 4; ++j) acc[i][j] = (f32x4)0.f;
  }

  auto STAGE = [&](int buf, int kt) {
    unsigned short* base = smem + buf * 8192;
    gld16(gA1 + kt, base + lA1);
    gld16(gA2 + kt, base + lA2);
    gld16(gB1 + kt, base + 4096 + lA1);
    gld16(gB2 + kt, base + 4096 + lA2);
  };
  auto COMPUTE = [&](int buf) {
    const unsigned short* sA = smem + buf * 8192;
    const unsigned short* sB = sA + 4096;
    f16x8 a[4], b[4];
#pragma unroll
    for (int mi = 0; mi < 4; ++mi) {
      int r = wm + mi * 16 + fr;
      a[mi] = *(const f16x8*)&sA[r * 32 + ((fc ^ ((r >> 1) & 3)) << 3)];
    }
#pragma unroll
    for (int ni = 0; ni < 4; ++ni) {
      int r = wn + ni * 16 + fr;
      b[ni] = *(const f16x8*)&sB[r * 32 + ((fc ^ ((r >> 1) & 3)) << 3)];
    }
#pragma unroll
    for (int mi = 0; mi < 4; ++mi) {
#pragma unroll
      for (int ni = 0; ni < 4; ++ni) acc[mi][ni] = MFMA16(a[mi], b[ni], acc[mi][ni]);
    }
  };

  const int nk = K >> 5;
  STAGE(0, 0);
  __syncthreads();
  int cur = 0;
  for (int t = 1; t < nk; ++t) {
    STAGE(cur ^ 1, t << 5);
    COMPUTE(cur);
    __syncthreads();
    cur ^= 1;
  }
  COMPUTE(cur);

  // epilogues; frag: D[row=(lane>>4)*4+i][col=lane&15]
  if constexpr (EPI == 5) {
    unsigned short* Ch = (unsigned short*)Cv;
    const int Nh = N >> 1;
#pragma unroll
    for (int mi = 0; mi < 4; ++mi) {
#pragma unroll
      for (int p = 0; p < 2; ++p) {
        const int hcol = (((n0 + wn) >> 5) + p) * 16 + fr;
        const int mb = m0 + wm + mi * 16 + fc * 4;
#pragma unroll
        for (int i = 0; i < 4; ++i) {
          const int m = mb + i;
          if (MODE != 0 && m >= cnt) continue;
          float v1 = acc[mi][2 * p][i];
          float v3 = acc[mi][2 * p + 1][i];
          float y = v1 / (1.f + __expf(-v1)) * v3;
          Ch[(size_t)m * Nh + hcol] = f2h(y);
        }
      }
    }
    return;
  }
#pragma unroll
  for (int mi = 0; mi < 4; ++mi) {
#pragma unroll
    for (int ni = 0; ni < 4; ++ni) {
      const int n = n0 + wn + ni * 16 + fr;
      const int mb = m0 + wm + mi * 16 + fc * 4;
#pragma unroll
      for (int i = 0; i < 4; ++i) {
        const int m = mb + i;
        if (MODE != 0 && m >= cnt) continue;
        float v = acc[mi][ni][i];
        const size_t cidx = (size_t)m * N + n;
        if constexpr (EPI == 1) {
          ((float*)Cv)[cidx] = aux0[n] * (v + bias[n]) + aux1[cidx];
        } else if constexpr (EPI == 2) {
          const int tk = idx[m];
          ((float*)Cv)[(size_t)tk * N + n] += wdp[(size_t)tk * 4] * v;
        } else if constexpr (EPI == 3) {
          ((float*)Cv)[cidx] = aux0[n] * (aux2[cidx] + v) + aux1[cidx];
        } else if constexpr (EPI == 4) {
          if (bias) v += bias[n];
          ((unsigned short*)Cv)[cidx] = f2h(v);
        }
      }
    }
  }
}

// ---------------- host ----------------

extern "C" void kernel_launch(void* const* d_in, const int* in_sizes, int n_in,
                              void* d_out, int out_size, void* d_ws, size_t ws_size,
                              hipStream_t stream) {
  (void)in_sizes; (void)n_in; (void)out_size; (void)ws_size;
  const float* hs = (const float*)d_in[0];
  const float* temb = (const float*)d_in[1];
  const float* rope = (const float*)d_in[2];
  const float* adaw = (const float*)d_in[3];
  const float* adab = (const float*)d_in[4];
  const float* qkvw = (const float*)d_in[5];
  const float* qkvb = (const float*)d_in[6];
  const float* qnw = (const float*)d_in[7];
  const float* knw = (const float*)d_in[8];
  const float* outw = (const float*)d_in[9];
  const float* outb = (const float*)d_in[10];
  const float* gatew = (const float*)d_in[11];
  const float* ew1 = (const float*)d_in[12];
  const float* ew2 = (const float*)d_in[13];
  const float* ew3 = (const float*)d_in[14];
  const float* sw1 = (const float*)d_in[15];
  const float* sw2 = (const float*)d_in[16];
  const float* sw3 = (const float*)d_in[17];
  float* out = (float*)d_out;
  char* ws = (char*)d_ws;

  size_t off = 0;
  auto give = [&](size_t nbytes) {
    size_t r = off;
    off += (nbytes + 255) & ~(size_t)255;
    return r;
  };
  const size_t T = T_TOK, D = DIM;
  size_t o_mod = give(15360 * 4);
  size_t o_ss = give(D * 4);
  size_t o_wd = give(T * 4 * 4);
  size_t o_idx = give(4 * 2048 * 4);
  size_t o_cnt = give(4 * 4);
  size_t o_nh = give(T * D * 2);      // nh fp16; later nh2
  size_t o_qkvh = give(T * 7680 * 2); // qkv fp16
  size_t o_qh = give(T * D * 2);
  size_t o_kh = give(T * D * 2);
  size_t o_vt = give(T * D * 2);
  size_t o_obf = give(T * D * 2);
  size_t o_h2 = give(T * D * 4);
  size_t o_y = give(T * D * 4);
  size_t o_hmid = give(T * HID_E * 2);
  // fp16 weights
  size_t o_qkvw = give((size_t)7680 * 2560 * 2);
  size_t o_outw = give((size_t)2560 * 2560 * 2);
  size_t o_ewA = give((size_t)4 * 2 * HID_E * 2560 * 2);  // interleaved w1/w3
  size_t o_ew2 = give((size_t)4 * 2560 * HID_E * 2);
  size_t o_swA = give((size_t)2 * SHID_E * 2560 * 2);     // interleaved sw1/sw3
  size_t o_sw2 = give((size_t)2560 * SHID_E * 2);

  float* mod = (float*)(ws + o_mod);
  float* ss = (float*)(ws + o_ss);
  float* wd = (float*)(ws + o_wd);
  int* idxb = (int*)(ws + o_idx);
  int* cnt = (int*)(ws + o_cnt);
  unsigned short* nh_h = (unsigned short*)(ws + o_nh);
  unsigned short* qkvh = (unsigned short*)(ws + o_qkvh);
  unsigned short* qh = (unsigned short*)(ws + o_qh);
  unsigned short* kh = (unsigned short*)(ws + o_kh);
  unsigned short* vt = (unsigned short*)(ws + o_vt);
  unsigned short* obf = (unsigned short*)(ws + o_obf);
  float* h2 = (float*)(ws + o_h2);
  float* ybuf = (float*)(ws + o_y);
  unsigned short* hmid = (unsigned short*)(ws + o_hmid);
  unsigned short* qkvw_h = (unsigned short*)(ws + o_qkvw);
  unsigned short* outw_h = (unsigned short*)(ws + o_outw);
  unsigned short* ewA_h = (unsigned short*)(ws + o_ewA);
  unsigned short* ew2_h = (unsigned short*)(ws + o_ew2);
  unsigned short* swA_h = (unsigned short*)(ws + o_swA);
  unsigned short* sw2_h = (unsigned short*)(ws + o_sw2);
  unsigned short* nh2 = nh_h;

  // 0) weight conversion f32 -> fp16 (+ w1/w3 interleave for fused swiglu)
  cvt_f16<<<2048, 256, 0, stream>>>(qkvw, qkvw_h, 7680 * 2560 / 8);
  cvt_f16<<<2048, 256, 0, stream>>>(outw, outw_h, 2560 * 2560 / 8);
  cvt_f16<<<2048, 256, 0, stream>>>(ew2, ew2_h, 4 * 2560 * HID_E / 8);
  cvt_f16<<<2048, 256, 0, stream>>>(sw2, sw2_h, 2560 * SHID_E / 8);
  for (int e = 0; e < 4; ++e) {
    cvt_pair<<<2 * HID_E, 256, 0, stream>>>(ew1 + (size_t)e * HID_E * DIM,
                                            ew3 + (size_t)e * HID_E * DIM,
                                            ewA_h + (size_t)e * 2 * HID_E * DIM);
  }
  cvt_pair<<<2 * SHID_E, 256, 0, stream>>>(sw1, sw3, swA_h);
  // 1) adaLN modulation
  silu_k<<<10, 256, 0, stream>>>(temb, ss);
  adaln_gemv<<<3840, 256, 0, stream>>>(ss, adaw, adab, mod);
  // 2) LN1 + modulate (fp16)
  ln_mod<<<T, 256, 0, stream>>>(hs, mod, mod + D, nh_h);
  // 3) qkv GEMM -> fp16
  gemm128<4, 0><<<60 * 16, 256, 0, stream>>>(nh_h, qkvw_h, qkvb, qkvh,
                                             nullptr, nullptr, nullptr, nullptr, nullptr,
                                             nullptr, 60, 2048, 7680, 2560);
  // 4) RMSNorm + RoPE
  rmsrope<<<T, 256, 0, stream>>>(qkvh, qnw, knw, rope, qh, kh);
  // 5) V transpose
  transpose_v<<<dim3(80, 64), dim3(32, 8), 0, stream>>>(qkvh, vt);
  // 6) MFMA flash attention
  fattn<<<dim3(32, 20), 256, 0, stream>>>(qh, kh, vt, obf);
  // 7) out proj + gate_msa residual -> h2 f32
  gemm128<1, 0><<<20 * 16, 256, 0, stream>>>(obf, outw_h, outb, h2,
                                             mod + 2 * D, hs, nullptr, nullptr, nullptr,
                                             nullptr, 20, 2048, 2560, 2560);
  // 8) LN2 + modulate + routing, then compaction
  ln2_route<<<T, 256, 0, stream>>>(h2, mod + 3 * D, mod + 4 * D, gatew, nh2, wd);
  route_compact<<<1, 256, 0, stream>>>(wd, idxb, cnt);
  // 9) MoE experts (top-2 sparse, gathered, fused w1w3+swiglu)
  hipMemsetAsync(ybuf, 0, T * D * 4, stream);
  for (int e = 0; e < 4; ++e) {
    const unsigned short* wA = ewA_h + (size_t)e * 2 * HID_E * DIM;
    const unsigned short* w2 = ew2_h + (size_t)e * DIM * HID_E;
    gemm128<5, 1><<<108 * 16, 256, 0, stream>>>(nh2, wA, nullptr, hmid,
                                                nullptr, nullptr, nullptr, idxb + e * 2048,
                                                cnt + e, nullptr, 108, 2048, 2 * HID_E, 2560);
    gemm128<2, 2><<<20 * 16, 256, 0, stream>>>(hmid, w2, nullptr, ybuf,
                                               nullptr, nullptr, nullptr, idxb + e * 2048,
                                               cnt + e, wd + e, 20, 2048, 2560, 6912);
  }
  // 10) shared expert (fused w1w3+swiglu) + final combine
  gemm128<5, 0><<<56 * 16, 256, 0, stream>>>(nh2, swA_h, nullptr, hmid,
                                             nullptr, nullptr, nullptr, nullptr, nullptr,
                                             nullptr, 56, 2048, 2 * SHID_E, 2560);
  gemm128<3, 0><<<20 * 16, 256, 0, stream>>>(hmid, sw2_h, nullptr, out,
                                             mod + 5 * D, h2, ybuf, nullptr, nullptr,
                                             nullptr, 20, 2048, 2560, 3584);
}

// Round 5
// 2244.474 us; speedup vs baseline: 2.3607x; 1.1118x over previous
//
#include <hip/hip_runtime.h>

#define DIM 2560
#define T_TOK 2048
#define NHEADS 20
#define HD 128
#define HID_E 6912
#define SHID_E 3584

typedef _Float16 f16x8 __attribute__((ext_vector_type(8)));
typedef float f32x4 __attribute__((ext_vector_type(4)));
typedef unsigned short u16x8 __attribute__((ext_vector_type(8)));

#define MFMA16(a, b, c) __builtin_amdgcn_mfma_f32_16x16x32_f16((a), (b), (c), 0, 0, 0)

__device__ inline unsigned short f2h(float f) {
  return __builtin_bit_cast(unsigned short, (_Float16)f);
}
__device__ inline float h2f(unsigned short u) {
  return (float)__builtin_bit_cast(_Float16, u);
}
__device__ inline float wave_sum(float v) {
#pragma unroll
  for (int off = 32; off > 0; off >>= 1) v += __shfl_down(v, off, 64);
  return v;
}
// async global->LDS, 16B per lane; LDS dest = wave-uniform base + lane*16
__device__ inline void gld16(const void* g, void* l) {
  __builtin_amdgcn_global_load_lds((const __attribute__((address_space(1))) void*)g,
                                   (__attribute__((address_space(3))) void*)l, 16, 0, 0);
}

// ---------------- tiny kernels ----------------

__global__ __launch_bounds__(256) void silu_k(const float* __restrict__ t,
                                              float* __restrict__ ss) {
  int i = blockIdx.x * 256 + threadIdx.x;
  if (i < DIM) {
    float v = t[i];
    ss[i] = v / (1.f + expf(-v));
  }
}

__global__ __launch_bounds__(256) void cvt_f16(const float* __restrict__ in,
                                               unsigned short* __restrict__ outp, int n8) {
  const int stride = gridDim.x * 256;
  for (int i = blockIdx.x * 256 + threadIdx.x; i < n8; i += stride) {
    float4 a = *(const float4*)(in + (size_t)i * 8);
    float4 b = *(const float4*)(in + (size_t)i * 8 + 4);
    u16x8 u;
    u[0] = f2h(a.x); u[1] = f2h(a.y); u[2] = f2h(a.z); u[3] = f2h(a.w);
    u[4] = f2h(b.x); u[5] = f2h(b.y); u[6] = f2h(b.z); u[7] = f2h(b.w);
    *(u16x8*)&outp[(size_t)i * 8] = u;
  }
}

// interleave w1/w3 rows into B' : row j -> (j&31)<16 ? w1[(j>>5)*16+(j&15)]
//                                          : w3[(j>>5)*16+(j&15)]
__global__ __launch_bounds__(256) void cvt_pair(const float* __restrict__ w1,
                                                const float* __restrict__ w3,
                                                unsigned short* __restrict__ outp) {
  const int j = blockIdx.x;
  const int g = j >> 5, r = j & 31;
  const float* src = (r < 16) ? (w1 + (size_t)(g * 16 + r) * DIM)
                              : (w3 + (size_t)(g * 16 + (r & 15)) * DIM);
  unsigned short* dst = outp + (size_t)j * DIM;
  for (int i = threadIdx.x; i < 320; i += 256) {
    float4 a = *(const float4*)(src + i * 8);
    float4 b = *(const float4*)(src + i * 8 + 4);
    u16x8 u;
    u[0] = f2h(a.x); u[1] = f2h(a.y); u[2] = f2h(a.z); u[3] = f2h(a.w);
    u[4] = f2h(b.x); u[5] = f2h(b.y); u[6] = f2h(b.z); u[7] = f2h(b.w);
    *(u16x8*)&dst[i * 8] = u;
  }
}

// mod[j] = dot(silu(temb), adaln_w[j]) + adaln_b[j]; one wave per output
__global__ __launch_bounds__(256) void adaln_gemv(const float* __restrict__ ss,
                                                  const float* __restrict__ W,
                                                  const float* __restrict__ bias,
                                                  float* __restrict__ mod) {
  const int lane = threadIdx.x & 63;
  const int j = blockIdx.x * 4 + (threadIdx.x >> 6);
  const float* wr = W + (size_t)j * DIM;
  float p = 0.f;
  for (int i = lane; i < 640; i += 64) {
    float4 w = *(const float4*)(wr + i * 4);
    float4 x = *(const float4*)(ss + i * 4);
    p += w.x * x.x + w.y * x.y + w.z * x.z + w.w * x.w;
  }
  p = wave_sum(p);
  if (lane == 0) mod[j] = p + bias[j];
}

// LN (no affine) then *(1+scale)+shift, write fp16. One block per row.
__global__ __launch_bounds__(256) void ln_mod(const float* __restrict__ x,
                                              const float* __restrict__ shift,
                                              const float* __restrict__ scale,
                                              unsigned short* __restrict__ outp) {
  __shared__ float rbuf[8];
  const int t = blockIdx.x, tid = threadIdx.x, lane = tid & 63, wid = tid >> 6;
  const float* xr = x + (size_t)t * DIM;
  float s = 0.f, sq = 0.f;
  for (int i = tid; i < 640; i += 256) {
    float4 v = *(const float4*)(xr + i * 4);
    s += v.x + v.y + v.z + v.w;
    sq += v.x * v.x + v.y * v.y + v.z * v.z + v.w * v.w;
  }
  s = wave_sum(s);
  sq = wave_sum(sq);
  if (lane == 0) {
    rbuf[wid] = s;
    rbuf[4 + wid] = sq;
  }
  __syncthreads();
  float S = rbuf[0] + rbuf[1] + rbuf[2] + rbuf[3];
  float SQ = rbuf[4] + rbuf[5] + rbuf[6] + rbuf[7];
  float mean = S * (1.f / DIM);
  float rs = rsqrtf(SQ * (1.f / DIM) - mean * mean + 1e-6f);
  for (int i = tid; i < 640; i += 256) {
    float4 v = *(const float4*)(xr + i * 4);
    float4 sc4 = *(const float4*)(scale + i * 4);
    float4 sh4 = *(const float4*)(shift + i * 4);
    ushort4 u;
    u.x = f2h((v.x - mean) * rs * (1.f + sc4.x) + sh4.x);
    u.y = f2h((v.y - mean) * rs * (1.f + sc4.y) + sh4.y);
    u.z = f2h((v.z - mean) * rs * (1.f + sc4.z) + sh4.z);
    u.w = f2h((v.w - mean) * rs * (1.f + sc4.w) + sh4.w);
    *(ushort4*)&outp[(size_t)t * DIM + i * 4] = u;
  }
}

// RMSNorm(q),(k) over full 2560 + weight + RoPE -> qh (scaled by 1/sqrt(128)), kh
__global__ __launch_bounds__(256) void rmsrope(const unsigned short* __restrict__ qkv,
                                               const float* __restrict__ qn,
                                               const float* __restrict__ kn,
                                               const float* __restrict__ rope,
                                               unsigned short* __restrict__ qh,
                                               unsigned short* __restrict__ kh) {
  __shared__ float rbuf[8];
  const int t = blockIdx.x, tid = threadIdx.x, lane = tid & 63, wid = tid >> 6;
  const unsigned short* row = qkv + (size_t)t * 7680;
  float sq = 0.f, sk = 0.f;
  for (int i = tid; i < 320; i += 256) {
    f16x8 qv = *(const f16x8*)(row + i * 8);
    f16x8 kv = *(const f16x8*)(row + DIM + i * 8);
#pragma unroll
    for (int j = 0; j < 8; ++j) {
      float q = (float)qv[j], k = (float)kv[j];
      sq += q * q;
      sk += k * k;
    }
  }
  sq = wave_sum(sq);
  sk = wave_sum(sk);
  if (lane == 0) {
    rbuf[wid] = sq;
    rbuf[4 + wid] = sk;
  }
  __syncthreads();
  float SQ = rbuf[0] + rbuf[1] + rbuf[2] + rbuf[3];
  float SK = rbuf[4] + rbuf[5] + rbuf[6] + rbuf[7];
  float rq = rsqrtf(SQ * (1.f / DIM) + 1e-6f) * 0.08838834764831845f;
  float rk = rsqrtf(SK * (1.f / DIM) + 1e-6f);
  for (int pp = tid; pp < 1280; pp += 256) {
    int c = pp * 2;
    float qe = h2f(row[c]) * rq * qn[c], qo = h2f(row[c + 1]) * rq * qn[c + 1];
    float ke = h2f(row[DIM + c]) * rk * kn[c], ko = h2f(row[DIM + c + 1]) * rk * kn[c + 1];
    float4 rr = *(const float4*)(rope + (size_t)t * 256 + (pp & 63) * 4);
    unsigned qp = (unsigned)f2h(rr.x * qe + rr.y * qo) |
                  ((unsigned)f2h(rr.z * qe + rr.w * qo) << 16);
    unsigned kp = (unsigned)f2h(rr.x * ke + rr.y * ko) |
                  ((unsigned)f2h(rr.z * ke + rr.w * ko) << 16);
    *(unsigned*)&qh[(size_t)t * DIM + c] = qp;
    *(unsigned*)&kh[(size_t)t * DIM + c] = kp;
  }
}

// V part of qkv (fp16 [2048][7680] at col 5120) -> vt fp16 [2560][2048]
__global__ void transpose_v(const unsigned short* __restrict__ in,
                            unsigned short* __restrict__ outp) {
  __shared__ unsigned short tile[32][33];
  const int bx = blockIdx.x * 32;  // channel
  const int by = blockIdx.y * 32;  // token
  const int tx = threadIdx.x, ty = threadIdx.y;
  for (int j = ty; j < 32; j += 8)
    tile[j][tx] = in[(size_t)(by + j) * 7680 + 5120 + bx + tx];
  __syncthreads();
  for (int j = ty; j < 32; j += 8)
    outp[(size_t)(bx + j) * T_TOK + by + tx] = tile[tx][j];
}

// ---------------- MFMA flash attention ----------------
__global__ __launch_bounds__(256) void fattn(const unsigned short* __restrict__ qh,
                                             const unsigned short* __restrict__ kh,
                                             const unsigned short* __restrict__ vt,
                                             unsigned short* __restrict__ obuf) {
  __shared__ unsigned short sK[64 * 128];  // [k][d], slot = c ^ (r&15)
  __shared__ unsigned short sV[128 * 64];  // [d][k], slot = c ^ (r&7)
  __shared__ unsigned short sP[64 * 64];   // [q][k], slot = c ^ (r&7)
  __shared__ float sRedM[4][64];
  __shared__ float sRedL[4][64];
  __shared__ float sM[64];
  __shared__ float sL[64];
  const int tid = threadIdx.x, lane = tid & 63, wv = tid >> 6;
  const int g = lane >> 4, fr = lane & 15;
  const int h = blockIdx.y;
  const int q0 = blockIdx.x * 64;

  {
    const int r = tid >> 2, qt = tid & 3;
    const unsigned short* gp = qh + (size_t)(q0 + r) * DIM + h * HD + qt * 32;
    uint4 v0 = ((const uint4*)gp)[0];
    uint4 v1 = ((const uint4*)gp)[1];
    uint4 v2 = ((const uint4*)gp)[2];
    uint4 v3 = ((const uint4*)gp)[3];
    unsigned short* dst = &sK[r * 128];
    const int cb = qt * 4, rs = r & 15;
    *(uint4*)&dst[((cb + 0) ^ rs) * 8] = v0;
    *(uint4*)&dst[((cb + 1) ^ rs) * 8] = v1;
    *(uint4*)&dst[((cb + 2) ^ rs) * 8] = v2;
    *(uint4*)&dst[((cb + 3) ^ rs) * 8] = v3;
  }
  __syncthreads();
  f16x8 qfrag[4][4];
#pragma unroll
  for (int ni = 0; ni < 4; ++ni) {
#pragma unroll
    for (int kt = 0; kt < 4; ++kt) {
      int r = ni * 16 + fr;
      qfrag[ni][kt] = *(const f16x8*)&sK[r * 128 + (((kt * 4 + g) ^ (r & 15)) << 3)];
    }
  }
  __syncthreads();

  f32x4 acco[4][2];
  f32x4 mprev[4];
  float mrun[4], lrun[4];
#pragma unroll
  for (int i = 0; i < 4; ++i) {
    acco[i][0] = (f32x4)0.f;
    acco[i][1] = (f32x4)0.f;
    mprev[i] = (f32x4)(-1e30f);
    mrun[i] = -1e30f;
    lrun[i] = 0.f;
  }

  for (int kt0 = 0; kt0 < T_TOK; kt0 += 64) {
    {
      const int r = tid >> 2, qt = tid & 3;
      const unsigned short* gp = kh + (size_t)(kt0 + r) * DIM + h * HD + qt * 32;
      uint4 v0 = ((const uint4*)gp)[0];
      uint4 v1 = ((const uint4*)gp)[1];
      uint4 v2 = ((const uint4*)gp)[2];
      uint4 v3 = ((const uint4*)gp)[3];
      unsigned short* dst = &sK[r * 128];
      const int cb = qt * 4, rs = r & 15;
      *(uint4*)&dst[((cb + 0) ^ rs) * 8] = v0;
      *(uint4*)&dst[((cb + 1) ^ rs) * 8] = v1;
      *(uint4*)&dst[((cb + 2) ^ rs) * 8] = v2;
      *(uint4*)&dst[((cb + 3) ^ rs) * 8] = v3;
      const int rv = tid >> 1, hf = tid & 1;
      const unsigned short* gv = vt + (size_t)(h * HD + rv) * T_TOK + kt0 + hf * 32;
      uint4 w0 = ((const uint4*)gv)[0];
      uint4 w1 = ((const uint4*)gv)[1];
      uint4 w2 = ((const uint4*)gv)[2];
      uint4 w3 = ((const uint4*)gv)[3];
      unsigned short* dv = &sV[rv * 64];
      const int cv = hf * 4, rvs = rv & 7;
      *(uint4*)&dv[((cv + 0) ^ rvs) * 8] = w0;
      *(uint4*)&dv[((cv + 1) ^ rvs) * 8] = w1;
      *(uint4*)&dv[((cv + 2) ^ rvs) * 8] = w2;
      *(uint4*)&dv[((cv + 3) ^ rvs) * 8] = w3;
    }
    __syncthreads();  // B0

    f32x4 accs[4] = {(f32x4)0.f, (f32x4)0.f, (f32x4)0.f, (f32x4)0.f};
#pragma unroll
    for (int kt = 0; kt < 4; ++kt) {
      int r = wv * 16 + fr;
      f16x8 ak = *(const f16x8*)&sK[r * 128 + (((kt * 4 + g) ^ (r & 15)) << 3)];
#pragma unroll
      for (int ni = 0; ni < 4; ++ni) accs[ni] = MFMA16(ak, qfrag[ni][kt], accs[ni]);
    }

    float pm[4];
#pragma unroll
    for (int ni = 0; ni < 4; ++ni) {
      float m = fmaxf(fmaxf(accs[ni][0], accs[ni][1]), fmaxf(accs[ni][2], accs[ni][3]));
      m = fmaxf(m, __shfl_xor(m, 16));
      m = fmaxf(m, __shfl_xor(m, 32));
      pm[ni] = m;
    }
    if (g == 0) {
#pragma unroll
      for (int ni = 0; ni < 4; ++ni) sRedM[wv][ni * 16 + fr] = pm[ni];
    }
    __syncthreads();  // B1
    float mnew[4];
#pragma unroll
    for (int ni = 0; ni < 4; ++ni) {
      int q = ni * 16 + fr;
      float mt = fmaxf(fmaxf(sRedM[0][q], sRedM[1][q]), fmaxf(sRedM[2][q], sRedM[3][q]));
      mnew[ni] = fmaxf(mrun[ni], mt);
    }
    float lsum[4];
#pragma unroll
    for (int ni = 0; ni < 4; ++ni) {
      float l0 = 0.f;
#pragma unroll
      for (int i = 0; i < 4; ++i) {
        float p = __expf(accs[ni][i] - mnew[ni]);
        accs[ni][i] = p;
        l0 += p;
      }
      l0 += __shfl_xor(l0, 16);
      l0 += __shfl_xor(l0, 32);
      lsum[ni] = l0;
    }
    if (g == 0) {
#pragma unroll
      for (int ni = 0; ni < 4; ++ni) sRedL[wv][ni * 16 + fr] = lsum[ni];
      if (wv == 0) {
#pragma unroll
        for (int ni = 0; ni < 4; ++ni) sM[ni * 16 + fr] = mnew[ni];
      }
    }
#pragma unroll
    for (int ni = 0; ni < 4; ++ni) {
      int q = ni * 16 + fr;
      unsigned p01 = (unsigned)f2h(accs[ni][0]) | ((unsigned)f2h(accs[ni][1]) << 16);
      unsigned p23 = (unsigned)f2h(accs[ni][2]) | ((unsigned)f2h(accs[ni][3]) << 16);
      uint2 pk;
      pk.x = p01;
      pk.y = p23;
      *(uint2*)&sP[q * 64 + ((((wv << 1) | (g >> 1)) ^ (q & 7)) << 3) + ((g & 1) << 2)] = pk;
    }
    __syncthreads();  // B2
#pragma unroll
    for (int ni = 0; ni < 4; ++ni) {
      int q = ni * 16 + fr;
      float lt = sRedL[0][q] + sRedL[1][q] + sRedL[2][q] + sRedL[3][q];
      lrun[ni] = lrun[ni] * __expf(mrun[ni] - mnew[ni]) + lt;
      mrun[ni] = mnew[ni];
    }

#pragma unroll
    for (int mi = 0; mi < 4; ++mi) {
      f32x4 mn = *(const f32x4*)&sM[mi * 16 + g * 4];
      f32x4 sc;
#pragma unroll
      for (int i = 0; i < 4; ++i) sc[i] = __expf(mprev[mi][i] - mn[i]);
      acco[mi][0] *= sc;
      acco[mi][1] *= sc;
      mprev[mi] = mn;
    }
#pragma unroll
    for (int ktp = 0; ktp < 2; ++ktp) {
      f16x8 bv[2];
#pragma unroll
      for (int nd = 0; nd < 2; ++nd) {
        int r = wv * 32 + nd * 16 + fr;
        bv[nd] = *(const f16x8*)&sV[r * 64 + (((ktp * 4 + g) ^ (r & 7)) << 3)];
      }
#pragma unroll
      for (int mi = 0; mi < 4; ++mi) {
        int r = mi * 16 + fr;
        f16x8 ap = *(const f16x8*)&sP[r * 64 + (((ktp * 4 + g) ^ (r & 7)) << 3)];
        acco[mi][0] = MFMA16(ap, bv[0], acco[mi][0]);
        acco[mi][1] = MFMA16(ap, bv[1], acco[mi][1]);
      }
    }
    __syncthreads();  // B3
  }

  if (wv == 0 && g == 0) {
#pragma unroll
    for (int ni = 0; ni < 4; ++ni) sL[ni * 16 + fr] = 1.f / lrun[ni];
  }
  __syncthreads();
#pragma unroll
  for (int mi = 0; mi < 4; ++mi) {
    f32x4 li = *(const f32x4*)&sL[mi * 16 + g * 4];
#pragma unroll
    for (int nd = 0; nd < 2; ++nd) {
#pragma unroll
      for (int i = 0; i < 4; ++i) {
        float o = acco[mi][nd][i] * li[i];
        obuf[(size_t)(q0 + mi * 16 + g * 4 + i) * DIM + h * HD + wv * 32 + nd * 16 + fr] =
            f2h(o);
      }
    }
  }
}

// LN2 + modulate -> nh2 fp16, plus f32 routing (softmax over 4, top-2, unnormalized)
__global__ __launch_bounds__(256) void ln2_route(const float* __restrict__ x,
                                                 const float* __restrict__ shift,
                                                 const float* __restrict__ scale,
                                                 const float* __restrict__ gw,
                                                 unsigned short* __restrict__ nh2,
                                                 float* __restrict__ wd) {
  __shared__ float rbuf[8];
  __shared__ float gbuf[4][4];
  const int t = blockIdx.x, tid = threadIdx.x, lane = tid & 63, wid = tid >> 6;
  const float* xr = x + (size_t)t * DIM;
  float s = 0.f, sq = 0.f;
  for (int i = tid; i < 640; i += 256) {
    float4 v = *(const float4*)(xr + i * 4);
    s += v.x + v.y + v.z + v.w;
    sq += v.x * v.x + v.y * v.y + v.z * v.z + v.w * v.w;
  }
  s = wave_sum(s);
  sq = wave_sum(sq);
  if (lane == 0) {
    rbuf[wid] = s;
    rbuf[4 + wid] = sq;
  }
  __syncthreads();
  float S = rbuf[0] + rbuf[1] + rbuf[2] + rbuf[3];
  float SQ = rbuf[4] + rbuf[5] + rbuf[6] + rbuf[7];
  float mean = S * (1.f / DIM);
  float rs = rsqrtf(SQ * (1.f / DIM) - mean * mean + 1e-6f);
  float g0 = 0.f, g1 = 0.f, g2 = 0.f, g3 = 0.f;
  for (int i = tid; i < 640; i += 256) {
    float4 v = *(const float4*)(xr + i * 4);
    float4 sc4 = *(const float4*)(scale + i * 4);
    float4 sh4 = *(const float4*)(shift + i * 4);
    float y0 = (v.x - mean) * rs * (1.f + sc4.x) + sh4.x;
    float y1 = (v.y - mean) * rs * (1.f + sc4.y) + sh4.y;
    float y2 = (v.z - mean) * rs * (1.f + sc4.z) + sh4.z;
    float y3 = (v.w - mean) * rs * (1.f + sc4.w) + sh4.w;
    ushort4 u;
    u.x = f2h(y0); u.y = f2h(y1); u.z = f2h(y2); u.w = f2h(y3);
    *(ushort4*)&nh2[(size_t)t * DIM + i * 4] = u;
    float4 w0 = *(const float4*)(gw + i * 4);
    float4 w1 = *(const float4*)(gw + DIM + i * 4);
    float4 w2 = *(const float4*)(gw + 2 * DIM + i * 4);
    float4 w3 = *(const float4*)(gw + 3 * DIM + i * 4);
    g0 += y0 * w0.x + y1 * w0.y + y2 * w0.z + y3 * w0.w;
    g1 += y0 * w1.x + y1 * w1.y + y2 * w1.z + y3 * w1.w;
    g2 += y0 * w2.x + y1 * w2.y + y2 * w2.z + y3 * w2.w;
    g3 += y0 * w3.x + y1 * w3.y + y2 * w3.z + y3 * w3.w;
  }
  g0 = wave_sum(g0);
  g1 = wave_sum(g1);
  g2 = wave_sum(g2);
  g3 = wave_sum(g3);
  if (lane == 0) {
    gbuf[wid][0] = g0; gbuf[wid][1] = g1; gbuf[wid][2] = g2; gbuf[wid][3] = g3;
  }
  __syncthreads();
  if (tid == 0) {
    float l[4];
#pragma unroll
    for (int e = 0; e < 4; ++e) l[e] = gbuf[0][e] + gbuf[1][e] + gbuf[2][e] + gbuf[3][e];
    float mx = fmaxf(fmaxf(l[0], l[1]), fmaxf(l[2], l[3]));
    float ex[4], sum = 0.f;
#pragma unroll
    for (int e = 0; e < 4; ++e) { ex[e] = expf(l[e] - mx); sum += ex[e]; }
    float p[4];
#pragma unroll
    for (int e = 0; e < 4; ++e) p[e] = ex[e] / sum;
    int i1 = 0;
    for (int e = 1; e < 4; ++e)
      if (p[e] > p[i1]) i1 = e;
    int i2 = -1;
    for (int e = 0; e < 4; ++e) {
      if (e == i1) continue;
      if (i2 < 0 || p[e] > p[i2]) i2 = e;
    }
    float w[4] = {0.f, 0.f, 0.f, 0.f};
    w[i1] = p[i1];
    w[i2] = p[i2];
    *(float4*)&wd[(size_t)t * 4] = make_float4(w[0], w[1], w[2], w[3]);
  }
}

// deterministic token-ordered top-2 compaction; 1 block, 256 threads, 8 tokens each
__global__ __launch_bounds__(256) void route_compact(const float* __restrict__ wd,
                                                     int* __restrict__ idxbuf,
                                                     int* __restrict__ cnt) {
  __shared__ unsigned short c[256][4];
  __shared__ int offs[256][4];
  const int t = threadIdx.x;
  unsigned char sel[8];
  unsigned short lc[4] = {0, 0, 0, 0};
#pragma unroll
  for (int k = 0; k < 8; ++k) {
    int tok = t * 8 + k;
    float4 w = *(const float4*)&wd[(size_t)tok * 4];
    unsigned m = 0;
    if (w.x != 0.f) { m |= 1; lc[0]++; }
    if (w.y != 0.f) { m |= 2; lc[1]++; }
    if (w.z != 0.f) { m |= 4; lc[2]++; }
    if (w.w != 0.f) { m |= 8; lc[3]++; }
    sel[k] = (unsigned char)m;
  }
#pragma unroll
  for (int e = 0; e < 4; ++e) c[t][e] = lc[e];
  __syncthreads();
  if (t == 0) {
    int run[4] = {0, 0, 0, 0};
    for (int i = 0; i < 256; ++i) {
#pragma unroll
      for (int e = 0; e < 4; ++e) {
        offs[i][e] = run[e];
        run[e] += c[i][e];
      }
    }
#pragma unroll
    for (int e = 0; e < 4; ++e) cnt[e] = run[e];
  }
  __syncthreads();
  int o[4];
#pragma unroll
  for (int e = 0; e < 4; ++e) o[e] = offs[t][e];
#pragma unroll
  for (int k = 0; k < 8; ++k) {
    int tok = t * 8 + k;
    unsigned m = sel[k];
#pragma unroll
    for (int e = 0; e < 4; ++e) {
      if ((m >> e) & 1) idxbuf[e * 2048 + o[e]++] = tok;
    }
  }
}

// ---------------- GEMM: C[M,N] = A[M,K](fp16) @ B[N,K](fp16)^T ----------------
// 128x128 tile, BK=32, 4 waves, 2-phase double-buffered global_load_lds prefetch.
// Block mapping: m-FASTEST (column-major) so concurrent blocks share B tiles in
// L2 (B read ~once); XCD swizzle gives each XCD a contiguous column panel.
// MODE: 0 dense | 1 A-gather via idx, compact C | 2 compact A, scatter C.
// EPI: 1 f32 aux0[n]*(v+bias)+aux1 | 2 scatter C[tok*N+n] += wd[tok]*v |
//      3 f32 aux0[n]*(aux2+v)+aux1 | 4 fp16(+bias) | 5 fused swiglu -> fp16, Nh=N/2
template <int EPI, int MODE>
__global__ __launch_bounds__(256) void gemm128(
    const unsigned short* __restrict__ A, const unsigned short* __restrict__ B,
    const float* __restrict__ bias, void* __restrict__ Cv,
    const float* __restrict__ aux0, const float* __restrict__ aux1,
    const float* __restrict__ aux2, const int* __restrict__ idx,
    const int* __restrict__ cntp, const float* __restrict__ wdp,
    int M, int N, int K) {
  __shared__ unsigned short smem[16384];  // 2 bufs x (A 4096 + B 4096)
  const int tid = threadIdx.x;
  const int lane = tid & 63;
  const int wv = tid >> 6;
  // XCD-aware bijective swizzle (grid always %8==0), then m-fastest decompose
  const int nwg = gridDim.x;
  const int bid = blockIdx.x;
  const int swzb = (bid & 7) * (nwg >> 3) + (bid >> 3);
  const int gm = M >> 7;
  const int m0 = (swzb % gm) * 128, n0 = (swzb / gm) * 128;
  const int cnt = (MODE != 0) ? *cntp : M;
  if (MODE != 0 && m0 >= cnt) return;

  const int wm = (wv >> 1) * 64, wn = (wv & 1) * 64;
  const int fr = lane & 15, fc = lane >> 4;

  // staging geometry: wave wv stages rows [wv*16, wv*16+16) and [64+wv*16, ...)
  const int rl = lane >> 2, ch = lane & 3;
  const int R1 = wv * 16 + rl;
  const int R2 = 64 + R1;
  const int co1 = ((ch ^ ((R1 >> 1) & 3)) << 3);
  const int co2 = ((ch ^ ((R2 >> 1) & 3)) << 3);
  size_t ar1, ar2;
  if constexpr (MODE == 1) {
    int i1 = m0 + R1, i2 = m0 + R2;
    i1 = i1 < cnt ? i1 : cnt - 1;
    i2 = i2 < cnt ? i2 : cnt - 1;
    ar1 = (size_t)idx[i1] * K;
    ar2 = (size_t)idx[i2] * K;
  } else {
    ar1 = (size_t)(m0 + R1) * K;
    ar2 = (size_t)(m0 + R2) * K;
  }
  const unsigned short* gA1 = A + ar1 + co1;
  const unsigned short* gA2 = A + ar2 + co2;
  const unsigned short* gB1 = B + (size_t)(n0 + R1) * K + co1;
  const unsigned short* gB2 = B + (size_t)(n0 + R2) * K + co2;
  const int lA1 = (wv * 16) * 32, lA2 = (64 + wv * 16) * 32;

  f32x4 acc[4][4];
#pragma unroll
  for (int i = 0; i < 4; ++i) {
#pragma unroll
    for (int j = 0; j < 4; ++j) acc[i][j] = (f32x4)0.f;
  }

  auto STAGE = [&](int buf, int kt) {
    unsigned short* base = smem + buf * 8192;
    gld16(gA1 + kt, base + lA1);
    gld16(gA2 + kt, base + lA2);
    gld16(gB1 + kt, base + 4096 + lA1);
    gld16(gB2 + kt, base + 4096 + lA2);
  };
  auto COMPUTE = [&](int buf) {
    const unsigned short* sA = smem + buf * 8192;
    const unsigned short* sB = sA + 4096;
    f16x8 a[4], b[4];
#pragma unroll
    for (int mi = 0; mi < 4; ++mi) {
      int r = wm + mi * 16 + fr;
      a[mi] = *(const f16x8*)&sA[r * 32 + ((fc ^ ((r >> 1) & 3)) << 3)];
    }
#pragma unroll
    for (int ni = 0; ni < 4; ++ni) {
      int r = wn + ni * 16 + fr;
      b[ni] = *(const f16x8*)&sB[r * 32 + ((fc ^ ((r >> 1) & 3)) << 3)];
    }
#pragma unroll
    for (int mi = 0; mi < 4; ++mi) {
#pragma unroll
      for (int ni = 0; ni < 4; ++ni) acc[mi][ni] = MFMA16(a[mi], b[ni], acc[mi][ni]);
    }
  };

  const int nk = K >> 5;
  STAGE(0, 0);
  __syncthreads();
  int cur = 0;
  for (int t = 1; t < nk; ++t) {
    STAGE(cur ^ 1, t << 5);
    COMPUTE(cur);
    __syncthreads();
    cur ^= 1;
  }
  COMPUTE(cur);

  // epilogues; frag: D[row=(lane>>4)*4+i][col=lane&15]
  if constexpr (EPI == 5) {
    unsigned short* Ch = (unsigned short*)Cv;
    const int Nh = N >> 1;
#pragma unroll
    for (int mi = 0; mi < 4; ++mi) {
#pragma unroll
      for (int p = 0; p < 2; ++p) {
        const int hcol = (((n0 + wn) >> 5) + p) * 16 + fr;
        const int mb = m0 + wm + mi * 16 + fc * 4;
#pragma unroll
        for (int i = 0; i < 4; ++i) {
          const int m = mb + i;
          if (MODE != 0 && m >= cnt) continue;
          float v1 = acc[mi][2 * p][i];
          float v3 = acc[mi][2 * p + 1][i];
          float y = v1 / (1.f + __expf(-v1)) * v3;
          Ch[(size_t)m * Nh + hcol] = f2h(y);
        }
      }
    }
    return;
  }
#pragma unroll
  for (int mi = 0; mi < 4; ++mi) {
#pragma unroll
    for (int ni = 0; ni < 4; ++ni) {
      const int n = n0 + wn + ni * 16 + fr;
      const int mb = m0 + wm + mi * 16 + fc * 4;
#pragma unroll
      for (int i = 0; i < 4; ++i) {
        const int m = mb + i;
        if (MODE != 0 && m >= cnt) continue;
        float v = acc[mi][ni][i];
        const size_t cidx = (size_t)m * N + n;
        if constexpr (EPI == 1) {
          ((float*)Cv)[cidx] = aux0[n] * (v + bias[n]) + aux1[cidx];
        } else if constexpr (EPI == 2) {
          const int tk = idx[m];
          ((float*)Cv)[(size_t)tk * N + n] += wdp[(size_t)tk * 4] * v;
        } else if constexpr (EPI == 3) {
          ((float*)Cv)[cidx] = aux0[n] * (aux2[cidx] + v) + aux1[cidx];
        } else if constexpr (EPI == 4) {
          if (bias) v += bias[n];
          ((unsigned short*)Cv)[cidx] = f2h(v);
        }
      }
    }
  }
}

// ---------------- host ----------------

extern "C" void kernel_launch(void* const* d_in, const int* in_sizes, int n_in,
                              void* d_out, int out_size, void* d_ws, size_t ws_size,
                              hipStream_t stream) {
  (void)in_sizes; (void)n_in; (void)out_size; (void)ws_size;
  const float* hs = (const float*)d_in[0];
  const float* temb = (const float*)d_in[1];
  const float* rope = (const float*)d_in[2];
  const float* adaw = (const float*)d_in[3];
  const float* adab = (const float*)d_in[4];
  const float* qkvw = (const float*)d_in[5];
  const float* qkvb = (const float*)d_in[6];
  const float* qnw = (const float*)d_in[7];
  const float* knw = (const float*)d_in[8];
  const float* outw = (const float*)d_in[9];
  const float* outb = (const float*)d_in[10];
  const float* gatew = (const float*)d_in[11];
  const float* ew1 = (const float*)d_in[12];
  const float* ew2 = (const float*)d_in[13];
  const float* ew3 = (const float*)d_in[14];
  const float* sw1 = (const float*)d_in[15];
  const float* sw2 = (const float*)d_in[16];
  const float* sw3 = (const float*)d_in[17];
  float* out = (float*)d_out;
  char* ws = (char*)d_ws;

  size_t off = 0;
  auto give = [&](size_t nbytes) {
    size_t r = off;
    off += (nbytes + 255) & ~(size_t)255;
    return r;
  };
  const size_t T = T_TOK, D = DIM;
  size_t o_mod = give(15360 * 4);
  size_t o_ss = give(D * 4);
  size_t o_wd = give(T * 4 * 4);
  size_t o_idx = give(4 * 2048 * 4);
  size_t o_cnt = give(4 * 4);
  size_t o_nh = give(T * D * 2);      // nh fp16; later nh2
  size_t o_qkvh = give(T * 7680 * 2); // qkv fp16
  size_t o_qh = give(T * D * 2);
  size_t o_kh = give(T * D * 2);
  size_t o_vt = give(T * D * 2);
  size_t o_obf = give(T * D * 2);
  size_t o_h2 = give(T * D * 4);
  size_t o_y = give(T * D * 4);
  size_t o_hmid = give(T * HID_E * 2);
  // fp16 weights
  size_t o_qkvw = give((size_t)7680 * 2560 * 2);
  size_t o_outw = give((size_t)2560 * 2560 * 2);
  size_t o_ewA = give((size_t)4 * 2 * HID_E * 2560 * 2);  // interleaved w1/w3
  size_t o_ew2 = give((size_t)4 * 2560 * HID_E * 2);
  size_t o_swA = give((size_t)2 * SHID_E * 2560 * 2);     // interleaved sw1/sw3
  size_t o_sw2 = give((size_t)2560 * SHID_E * 2);

  float* mod = (float*)(ws + o_mod);
  float* ss = (float*)(ws + o_ss);
  float* wd = (float*)(ws + o_wd);
  int* idxb = (int*)(ws + o_idx);
  int* cnt = (int*)(ws + o_cnt);
  unsigned short* nh_h = (unsigned short*)(ws + o_nh);
  unsigned short* qkvh = (unsigned short*)(ws + o_qkvh);
  unsigned short* qh = (unsigned short*)(ws + o_qh);
  unsigned short* kh = (unsigned short*)(ws + o_kh);
  unsigned short* vt = (unsigned short*)(ws + o_vt);
  unsigned short* obf = (unsigned short*)(ws + o_obf);
  float* h2 = (float*)(ws + o_h2);
  float* ybuf = (float*)(ws + o_y);
  unsigned short* hmid = (unsigned short*)(ws + o_hmid);
  unsigned short* qkvw_h = (unsigned short*)(ws + o_qkvw);
  unsigned short* outw_h = (unsigned short*)(ws + o_outw);
  unsigned short* ewA_h = (unsigned short*)(ws + o_ewA);
  unsigned short* ew2_h = (unsigned short*)(ws + o_ew2);
  unsigned short* swA_h = (unsigned short*)(ws + o_swA);
  unsigned short* sw2_h = (unsigned short*)(ws + o_sw2);
  unsigned short* nh2 = nh_h;

  // 0) weight conversion f32 -> fp16 (+ w1/w3 interleave for fused swiglu)
  cvt_f16<<<2048, 256, 0, stream>>>(qkvw, qkvw_h, 7680 * 2560 / 8);
  cvt_f16<<<2048, 256, 0, stream>>>(outw, outw_h, 2560 * 2560 / 8);
  cvt_f16<<<2048, 256, 0, stream>>>(ew2, ew2_h, 4 * 2560 * HID_E / 8);
  cvt_f16<<<2048, 256, 0, stream>>>(sw2, sw2_h, 2560 * SHID_E / 8);
  for (int e = 0; e < 4; ++e) {
    cvt_pair<<<2 * HID_E, 256, 0, stream>>>(ew1 + (size_t)e * HID_E * DIM,
                                            ew3 + (size_t)e * HID_E * DIM,
                                            ewA_h + (size_t)e * 2 * HID_E * DIM);
  }
  cvt_pair<<<2 * SHID_E, 256, 0, stream>>>(sw1, sw3, swA_h);
  // 1) adaLN modulation
  silu_k<<<10, 256, 0, stream>>>(temb, ss);
  adaln_gemv<<<3840, 256, 0, stream>>>(ss, adaw, adab, mod);
  // 2) LN1 + modulate (fp16)
  ln_mod<<<T, 256, 0, stream>>>(hs, mod, mod + D, nh_h);
  // 3) qkv GEMM -> fp16
  gemm128<4, 0><<<60 * 16, 256, 0, stream>>>(nh_h, qkvw_h, qkvb, qkvh,
                                             nullptr, nullptr, nullptr, nullptr, nullptr,
                                             nullptr, 2048, 7680, 2560);
  // 4) RMSNorm + RoPE
  rmsrope<<<T, 256, 0, stream>>>(qkvh, qnw, knw, rope, qh, kh);
  // 5) V transpose
  transpose_v<<<dim3(80, 64), dim3(32, 8), 0, stream>>>(qkvh, vt);
  // 6) MFMA flash attention
  fattn<<<dim3(32, 20), 256, 0, stream>>>(qh, kh, vt, obf);
  // 7) out proj + gate_msa residual -> h2 f32
  gemm128<1, 0><<<20 * 16, 256, 0, stream>>>(obf, outw_h, outb, h2,
                                             mod + 2 * D, hs, nullptr, nullptr, nullptr,
                                             nullptr, 2048, 2560, 2560);
  // 8) LN2 + modulate + routing, then compaction
  ln2_route<<<T, 256, 0, stream>>>(h2, mod + 3 * D, mod + 4 * D, gatew, nh2, wd);
  route_compact<<<1, 256, 0, stream>>>(wd, idxb, cnt);
  // 9) MoE experts (top-2 sparse, gathered, fused w1w3+swiglu)
  hipMemsetAsync(ybuf, 0, T * D * 4, stream);
  for (int e = 0; e < 4; ++e) {
    const unsigned short* wA = ewA_h + (size_t)e * 2 * HID_E * DIM;
    const unsigned short* w2 = ew2_h + (size_t)e * DIM * HID_E;
    gemm128<5, 1><<<108 * 16, 256, 0, stream>>>(nh2, wA, nullptr, hmid,
                                                nullptr, nullptr, nullptr, idxb + e * 2048,
                                                cnt + e, nullptr, 2048, 2 * HID_E, 2560);
    gemm128<2, 2><<<20 * 16, 256, 0, stream>>>(hmid, w2, nullptr, ybuf,
                                               nullptr, nullptr, nullptr, idxb + e * 2048,
                                               cnt + e, wd + e, 2048, 2560, 6912);
  }
  // 10) shared expert (fused w1w3+swiglu) + final combine
  gemm128<5, 0><<<56 * 16, 256, 0, stream>>>(nh2, swA_h, nullptr, hmid,
                                             nullptr, nullptr, nullptr, nullptr, nullptr,
                                             nullptr, 2048, 2 * SHID_E, 2560);
  gemm128<3, 0><<<20 * 16, 256, 0, stream>>>(hmid, sw2_h, nullptr, out,
                                             mod + 5 * D, h2, ybuf, nullptr, nullptr,
                                             nullptr, 2048, 2560, 3584);
}

// Round 6
// 1609.804 us; speedup vs baseline: 3.2915x; 1.3943x over previous
//
#include <hip/hip_runtime.h>

#define DIM 2560
#define T_TOK 2048
#define NHEADS 20
#define HD 128
#define HID_E 6912
#define SHID_E 3584
#define MPAD 5120  // max padded concat rows (4096 + 4*127 -> <=4604, round up)

typedef _Float16 f16x8 __attribute__((ext_vector_type(8)));
typedef float f32x4 __attribute__((ext_vector_type(4)));
typedef unsigned short u16x8 __attribute__((ext_vector_type(8)));

#define MFMA16(a, b, c) __builtin_amdgcn_mfma_f32_16x16x32_f16((a), (b), (c), 0, 0, 0)

__device__ inline unsigned short f2h(float f) {
  return __builtin_bit_cast(unsigned short, (_Float16)f);
}
__device__ inline float h2f(unsigned short u) {
  return (float)__builtin_bit_cast(_Float16, u);
}
__device__ inline float wave_sum(float v) {
#pragma unroll
  for (int off = 32; off > 0; off >>= 1) v += __shfl_down(v, off, 64);
  return v;
}
// async global->LDS, 16B per lane; LDS dest = wave-uniform base + lane*16
__device__ inline void gld16(const void* g, void* l) {
  __builtin_amdgcn_global_load_lds((const __attribute__((address_space(1))) void*)g,
                                   (__attribute__((address_space(3))) void*)l, 16, 0, 0);
}

// ---------------- tiny kernels ----------------

__global__ __launch_bounds__(256) void silu_k(const float* __restrict__ t,
                                              float* __restrict__ ss) {
  int i = blockIdx.x * 256 + threadIdx.x;
  if (i < DIM) {
    float v = t[i];
    ss[i] = v / (1.f + expf(-v));
  }
}

__global__ __launch_bounds__(256) void cvt_f16(const float* __restrict__ in,
                                               unsigned short* __restrict__ outp, int n8) {
  const int stride = gridDim.x * 256;
  for (int i = blockIdx.x * 256 + threadIdx.x; i < n8; i += stride) {
    float4 a = *(const float4*)(in + (size_t)i * 8);
    float4 b = *(const float4*)(in + (size_t)i * 8 + 4);
    u16x8 u;
    u[0] = f2h(a.x); u[1] = f2h(a.y); u[2] = f2h(a.z); u[3] = f2h(a.w);
    u[4] = f2h(b.x); u[5] = f2h(b.y); u[6] = f2h(b.z); u[7] = f2h(b.w);
    *(u16x8*)&outp[(size_t)i * 8] = u;
  }
}

// interleave w1/w3 rows into B' : row j -> (j&31)<16 ? w1[(j>>5)*16+(j&15)]
//                                          : w3[(j>>5)*16+(j&15)]
__global__ __launch_bounds__(256) void cvt_pair(const float* __restrict__ w1,
                                                const float* __restrict__ w3,
                                                unsigned short* __restrict__ outp) {
  const int j = blockIdx.x;
  const int g = j >> 5, r = j & 31;
  const float* src = (r < 16) ? (w1 + (size_t)(g * 16 + r) * DIM)
                              : (w3 + (size_t)(g * 16 + (r & 15)) * DIM);
  unsigned short* dst = outp + (size_t)j * DIM;
  for (int i = threadIdx.x; i < 320; i += 256) {
    float4 a = *(const float4*)(src + i * 8);
    float4 b = *(const float4*)(src + i * 8 + 4);
    u16x8 u;
    u[0] = f2h(a.x); u[1] = f2h(a.y); u[2] = f2h(a.z); u[3] = f2h(a.w);
    u[4] = f2h(b.x); u[5] = f2h(b.y); u[6] = f2h(b.z); u[7] = f2h(b.w);
    *(u16x8*)&dst[i * 8] = u;
  }
}

// mod[j] = dot(silu(temb), adaln_w[j]) + adaln_b[j]; one wave per output
__global__ __launch_bounds__(256) void adaln_gemv(const float* __restrict__ ss,
                                                  const float* __restrict__ W,
                                                  const float* __restrict__ bias,
                                                  float* __restrict__ mod) {
  const int lane = threadIdx.x & 63;
  const int j = blockIdx.x * 4 + (threadIdx.x >> 6);
  const float* wr = W + (size_t)j * DIM;
  float p = 0.f;
  for (int i = lane; i < 640; i += 64) {
    float4 w = *(const float4*)(wr + i * 4);
    float4 x = *(const float4*)(ss + i * 4);
    p += w.x * x.x + w.y * x.y + w.z * x.z + w.w * x.w;
  }
  p = wave_sum(p);
  if (lane == 0) mod[j] = p + bias[j];
}

// LN (no affine) then *(1+scale)+shift, write fp16. One block per row.
__global__ __launch_bounds__(256) void ln_mod(const float* __restrict__ x,
                                              const float* __restrict__ shift,
                                              const float* __restrict__ scale,
                                              unsigned short* __restrict__ outp) {
  __shared__ float rbuf[8];
  const int t = blockIdx.x, tid = threadIdx.x, lane = tid & 63, wid = tid >> 6;
  const float* xr = x + (size_t)t * DIM;
  float s = 0.f, sq = 0.f;
  for (int i = tid; i < 640; i += 256) {
    float4 v = *(const float4*)(xr + i * 4);
    s += v.x + v.y + v.z + v.w;
    sq += v.x * v.x + v.y * v.y + v.z * v.z + v.w * v.w;
  }
  s = wave_sum(s);
  sq = wave_sum(sq);
  if (lane == 0) {
    rbuf[wid] = s;
    rbuf[4 + wid] = sq;
  }
  __syncthreads();
  float S = rbuf[0] + rbuf[1] + rbuf[2] + rbuf[3];
  float SQ = rbuf[4] + rbuf[5] + rbuf[6] + rbuf[7];
  float mean = S * (1.f / DIM);
  float rs = rsqrtf(SQ * (1.f / DIM) - mean * mean + 1e-6f);
  for (int i = tid; i < 640; i += 256) {
    float4 v = *(const float4*)(xr + i * 4);
    float4 sc4 = *(const float4*)(scale + i * 4);
    float4 sh4 = *(const float4*)(shift + i * 4);
    ushort4 u;
    u.x = f2h((v.x - mean) * rs * (1.f + sc4.x) + sh4.x);
    u.y = f2h((v.y - mean) * rs * (1.f + sc4.y) + sh4.y);
    u.z = f2h((v.z - mean) * rs * (1.f + sc4.z) + sh4.z);
    u.w = f2h((v.w - mean) * rs * (1.f + sc4.w) + sh4.w);
    *(ushort4*)&outp[(size_t)t * DIM + i * 4] = u;
  }
}

// RMSNorm(q),(k) over full 2560 + weight + RoPE -> qh (scaled by 1/sqrt(128)), kh
__global__ __launch_bounds__(256) void rmsrope(const unsigned short* __restrict__ qkv,
                                               const float* __restrict__ qn,
                                               const float* __restrict__ kn,
                                               const float* __restrict__ rope,
                                               unsigned short* __restrict__ qh,
                                               unsigned short* __restrict__ kh) {
  __shared__ float rbuf[8];
  const int t = blockIdx.x, tid = threadIdx.x, lane = tid & 63, wid = tid >> 6;
  const unsigned short* row = qkv + (size_t)t * 7680;
  float sq = 0.f, sk = 0.f;
  for (int i = tid; i < 320; i += 256) {
    f16x8 qv = *(const f16x8*)(row + i * 8);
    f16x8 kv = *(const f16x8*)(row + DIM + i * 8);
#pragma unroll
    for (int j = 0; j < 8; ++j) {
      float q = (float)qv[j], k = (float)kv[j];
      sq += q * q;
      sk += k * k;
    }
  }
  sq = wave_sum(sq);
  sk = wave_sum(sk);
  if (lane == 0) {
    rbuf[wid] = sq;
    rbuf[4 + wid] = sk;
  }
  __syncthreads();
  float SQ = rbuf[0] + rbuf[1] + rbuf[2] + rbuf[3];
  float SK = rbuf[4] + rbuf[5] + rbuf[6] + rbuf[7];
  float rq = rsqrtf(SQ * (1.f / DIM) + 1e-6f) * 0.08838834764831845f;
  float rk = rsqrtf(SK * (1.f / DIM) + 1e-6f);
  for (int pp = tid; pp < 1280; pp += 256) {
    int c = pp * 2;
    float qe = h2f(row[c]) * rq * qn[c], qo = h2f(row[c + 1]) * rq * qn[c + 1];
    float ke = h2f(row[DIM + c]) * rk * kn[c], ko = h2f(row[DIM + c + 1]) * rk * kn[c + 1];
    float4 rr = *(const float4*)(rope + (size_t)t * 256 + (pp & 63) * 4);
    unsigned qp = (unsigned)f2h(rr.x * qe + rr.y * qo) |
                  ((unsigned)f2h(rr.z * qe + rr.w * qo) << 16);
    unsigned kp = (unsigned)f2h(rr.x * ke + rr.y * ko) |
                  ((unsigned)f2h(rr.z * ke + rr.w * ko) << 16);
    *(unsigned*)&qh[(size_t)t * DIM + c] = qp;
    *(unsigned*)&kh[(size_t)t * DIM + c] = kp;
  }
}

// V part of qkv (fp16 [2048][7680] at col 5120) -> vt fp16 [2560][2048]
__global__ void transpose_v(const unsigned short* __restrict__ in,
                            unsigned short* __restrict__ outp) {
  __shared__ unsigned short tile[32][33];
  const int bx = blockIdx.x * 32;  // channel
  const int by = blockIdx.y * 32;  // token
  const int tx = threadIdx.x, ty = threadIdx.y;
  for (int j = ty; j < 32; j += 8)
    tile[j][tx] = in[(size_t)(by + j) * 7680 + 5120 + bx + tx];
  __syncthreads();
  for (int j = ty; j < 32; j += 8)
    outp[(size_t)(bx + j) * T_TOK + by + tx] = tile[tx][j];
}

// ---------------- MFMA flash attention ----------------
__global__ __launch_bounds__(256) void fattn(const unsigned short* __restrict__ qh,
                                             const unsigned short* __restrict__ kh,
                                             const unsigned short* __restrict__ vt,
                                             unsigned short* __restrict__ obuf) {
  __shared__ unsigned short sK[64 * 128];  // [k][d], slot = c ^ (r&15)
  __shared__ unsigned short sV[128 * 64];  // [d][k], slot = c ^ (r&7)
  __shared__ unsigned short sP[64 * 64];   // [q][k], slot = c ^ (r&7)
  __shared__ float sRedM[4][64];
  __shared__ float sRedL[4][64];
  __shared__ float sM[64];
  __shared__ float sL[64];
  const int tid = threadIdx.x, lane = tid & 63, wv = tid >> 6;
  const int g = lane >> 4, fr = lane & 15;
  const int h = blockIdx.y;
  const int q0 = blockIdx.x * 64;

  {
    const int r = tid >> 2, qt = tid & 3;
    const unsigned short* gp = qh + (size_t)(q0 + r) * DIM + h * HD + qt * 32;
    uint4 v0 = ((const uint4*)gp)[0];
    uint4 v1 = ((const uint4*)gp)[1];
    uint4 v2 = ((const uint4*)gp)[2];
    uint4 v3 = ((const uint4*)gp)[3];
    unsigned short* dst = &sK[r * 128];
    const int cb = qt * 4, rs = r & 15;
    *(uint4*)&dst[((cb + 0) ^ rs) * 8] = v0;
    *(uint4*)&dst[((cb + 1) ^ rs) * 8] = v1;
    *(uint4*)&dst[((cb + 2) ^ rs) * 8] = v2;
    *(uint4*)&dst[((cb + 3) ^ rs) * 8] = v3;
  }
  __syncthreads();
  f16x8 qfrag[4][4];
#pragma unroll
  for (int ni = 0; ni < 4; ++ni) {
#pragma unroll
    for (int kt = 0; kt < 4; ++kt) {
      int r = ni * 16 + fr;
      qfrag[ni][kt] = *(const f16x8*)&sK[r * 128 + (((kt * 4 + g) ^ (r & 15)) << 3)];
    }
  }
  __syncthreads();

  f32x4 acco[4][2];
  f32x4 mprev[4];
  float mrun[4], lrun[4];
#pragma unroll
  for (int i = 0; i < 4; ++i) {
    acco[i][0] = (f32x4)0.f;
    acco[i][1] = (f32x4)0.f;
    mprev[i] = (f32x4)(-1e30f);
    mrun[i] = -1e30f;
    lrun[i] = 0.f;
  }

  for (int kt0 = 0; kt0 < T_TOK; kt0 += 64) {
    {
      const int r = tid >> 2, qt = tid & 3;
      const unsigned short* gp = kh + (size_t)(kt0 + r) * DIM + h * HD + qt * 32;
      uint4 v0 = ((const uint4*)gp)[0];
      uint4 v1 = ((const uint4*)gp)[1];
      uint4 v2 = ((const uint4*)gp)[2];
      uint4 v3 = ((const uint4*)gp)[3];
      unsigned short* dst = &sK[r * 128];
      const int cb = qt * 4, rs = r & 15;
      *(uint4*)&dst[((cb + 0) ^ rs) * 8] = v0;
      *(uint4*)&dst[((cb + 1) ^ rs) * 8] = v1;
      *(uint4*)&dst[((cb + 2) ^ rs) * 8] = v2;
      *(uint4*)&dst[((cb + 3) ^ rs) * 8] = v3;
      const int rv = tid >> 1, hf = tid & 1;
      const unsigned short* gv = vt + (size_t)(h * HD + rv) * T_TOK + kt0 + hf * 32;
      uint4 w0 = ((const uint4*)gv)[0];
      uint4 w1 = ((const uint4*)gv)[1];
      uint4 w2 = ((const uint4*)gv)[2];
      uint4 w3 = ((const uint4*)gv)[3];
      unsigned short* dv = &sV[rv * 64];
      const int cv = hf * 4, rvs = rv & 7;
      *(uint4*)&dv[((cv + 0) ^ rvs) * 8] = w0;
      *(uint4*)&dv[((cv + 1) ^ rvs) * 8] = w1;
      *(uint4*)&dv[((cv + 2) ^ rvs) * 8] = w2;
      *(uint4*)&dv[((cv + 3) ^ rvs) * 8] = w3;
    }
    __syncthreads();  // B0

    f32x4 accs[4] = {(f32x4)0.f, (f32x4)0.f, (f32x4)0.f, (f32x4)0.f};
#pragma unroll
    for (int kt = 0; kt < 4; ++kt) {
      int r = wv * 16 + fr;
      f16x8 ak = *(const f16x8*)&sK[r * 128 + (((kt * 4 + g) ^ (r & 15)) << 3)];
#pragma unroll
      for (int ni = 0; ni < 4; ++ni) accs[ni] = MFMA16(ak, qfrag[ni][kt], accs[ni]);
    }

    float pm[4];
#pragma unroll
    for (int ni = 0; ni < 4; ++ni) {
      float m = fmaxf(fmaxf(accs[ni][0], accs[ni][1]), fmaxf(accs[ni][2], accs[ni][3]));
      m = fmaxf(m, __shfl_xor(m, 16));
      m = fmaxf(m, __shfl_xor(m, 32));
      pm[ni] = m;
    }
    if (g == 0) {
#pragma unroll
      for (int ni = 0; ni < 4; ++ni) sRedM[wv][ni * 16 + fr] = pm[ni];
    }
    __syncthreads();  // B1
    float mnew[4];
#pragma unroll
    for (int ni = 0; ni < 4; ++ni) {
      int q = ni * 16 + fr;
      float mt = fmaxf(fmaxf(sRedM[0][q], sRedM[1][q]), fmaxf(sRedM[2][q], sRedM[3][q]));
      mnew[ni] = fmaxf(mrun[ni], mt);
    }
    float lsum[4];
#pragma unroll
    for (int ni = 0; ni < 4; ++ni) {
      float l0 = 0.f;
#pragma unroll
      for (int i = 0; i < 4; ++i) {
        float p = __expf(accs[ni][i] - mnew[ni]);
        accs[ni][i] = p;
        l0 += p;
      }
      l0 += __shfl_xor(l0, 16);
      l0 += __shfl_xor(l0, 32);
      lsum[ni] = l0;
    }
    if (g == 0) {
#pragma unroll
      for (int ni = 0; ni < 4; ++ni) sRedL[wv][ni * 16 + fr] = lsum[ni];
      if (wv == 0) {
#pragma unroll
        for (int ni = 0; ni < 4; ++ni) sM[ni * 16 + fr] = mnew[ni];
      }
    }
#pragma unroll
    for (int ni = 0; ni < 4; ++ni) {
      int q = ni * 16 + fr;
      unsigned p01 = (unsigned)f2h(accs[ni][0]) | ((unsigned)f2h(accs[ni][1]) << 16);
      unsigned p23 = (unsigned)f2h(accs[ni][2]) | ((unsigned)f2h(accs[ni][3]) << 16);
      uint2 pk;
      pk.x = p01;
      pk.y = p23;
      *(uint2*)&sP[q * 64 + ((((wv << 1) | (g >> 1)) ^ (q & 7)) << 3) + ((g & 1) << 2)] = pk;
    }
    __syncthreads();  // B2
#pragma unroll
    for (int ni = 0; ni < 4; ++ni) {
      int q = ni * 16 + fr;
      float lt = sRedL[0][q] + sRedL[1][q] + sRedL[2][q] + sRedL[3][q];
      lrun[ni] = lrun[ni] * __expf(mrun[ni] - mnew[ni]) + lt;
      mrun[ni] = mnew[ni];
    }

#pragma unroll
    for (int mi = 0; mi < 4; ++mi) {
      f32x4 mn = *(const f32x4*)&sM[mi * 16 + g * 4];
      f32x4 sc;
#pragma unroll
      for (int i = 0; i < 4; ++i) sc[i] = __expf(mprev[mi][i] - mn[i]);
      acco[mi][0] *= sc;
      acco[mi][1] *= sc;
      mprev[mi] = mn;
    }
#pragma unroll
    for (int ktp = 0; ktp < 2; ++ktp) {
      f16x8 bv[2];
#pragma unroll
      for (int nd = 0; nd < 2; ++nd) {
        int r = wv * 32 + nd * 16 + fr;
        bv[nd] = *(const f16x8*)&sV[r * 64 + (((ktp * 4 + g) ^ (r & 7)) << 3)];
      }
#pragma unroll
      for (int mi = 0; mi < 4; ++mi) {
        int r = mi * 16 + fr;
        f16x8 ap = *(const f16x8*)&sP[r * 64 + (((ktp * 4 + g) ^ (r & 7)) << 3)];
        acco[mi][0] = MFMA16(ap, bv[0], acco[mi][0]);
        acco[mi][1] = MFMA16(ap, bv[1], acco[mi][1]);
      }
    }
    __syncthreads();  // B3
  }

  if (wv == 0 && g == 0) {
#pragma unroll
    for (int ni = 0; ni < 4; ++ni) sL[ni * 16 + fr] = 1.f / lrun[ni];
  }
  __syncthreads();
#pragma unroll
  for (int mi = 0; mi < 4; ++mi) {
    f32x4 li = *(const f32x4*)&sL[mi * 16 + g * 4];
#pragma unroll
    for (int nd = 0; nd < 2; ++nd) {
#pragma unroll
      for (int i = 0; i < 4; ++i) {
        float o = acco[mi][nd][i] * li[i];
        obuf[(size_t)(q0 + mi * 16 + g * 4 + i) * DIM + h * HD + wv * 32 + nd * 16 + fr] =
            f2h(o);
      }
    }
  }
}

// LN2 + modulate -> nh2 fp16, plus f32 routing (softmax over 4, top-2, unnormalized)
__global__ __launch_bounds__(256) void ln2_route(const float* __restrict__ x,
                                                 const float* __restrict__ shift,
                                                 const float* __restrict__ scale,
                                                 const float* __restrict__ gw,
                                                 unsigned short* __restrict__ nh2,
                                                 float* __restrict__ wd) {
  __shared__ float rbuf[8];
  __shared__ float gbuf[4][4];
  const int t = blockIdx.x, tid = threadIdx.x, lane = tid & 63, wid = tid >> 6;
  const float* xr = x + (size_t)t * DIM;
  float s = 0.f, sq = 0.f;
  for (int i = tid; i < 640; i += 256) {
    float4 v = *(const float4*)(xr + i * 4);
    s += v.x + v.y + v.z + v.w;
    sq += v.x * v.x + v.y * v.y + v.z * v.z + v.w * v.w;
  }
  s = wave_sum(s);
  sq = wave_sum(sq);
  if (lane == 0) {
    rbuf[wid] = s;
    rbuf[4 + wid] = sq;
  }
  __syncthreads();
  float S = rbuf[0] + rbuf[1] + rbuf[2] + rbuf[3];
  float SQ = rbuf[4] + rbuf[5] + rbuf[6] + rbuf[7];
  float mean = S * (1.f / DIM);
  float rs = rsqrtf(SQ * (1.f / DIM) - mean * mean + 1e-6f);
  float g0 = 0.f, g1 = 0.f, g2 = 0.f, g3 = 0.f;
  for (int i = tid; i < 640; i += 256) {
    float4 v = *(const float4*)(xr + i * 4);
    float4 sc4 = *(const float4*)(scale + i * 4);
    float4 sh4 = *(const float4*)(shift + i * 4);
    float y0 = (v.x - mean) * rs * (1.f + sc4.x) + sh4.x;
    float y1 = (v.y - mean) * rs * (1.f + sc4.y) + sh4.y;
    float y2 = (v.z - mean) * rs * (1.f + sc4.z) + sh4.z;
    float y3 = (v.w - mean) * rs * (1.f + sc4.w) + sh4.w;
    ushort4 u;
    u.x = f2h(y0); u.y = f2h(y1); u.z = f2h(y2); u.w = f2h(y3);
    *(ushort4*)&nh2[(size_t)t * DIM + i * 4] = u;
    float4 w0 = *(const float4*)(gw + i * 4);
    float4 w1 = *(const float4*)(gw + DIM + i * 4);
    float4 w2 = *(const float4*)(gw + 2 * DIM + i * 4);
    float4 w3 = *(const float4*)(gw + 3 * DIM + i * 4);
    g0 += y0 * w0.x + y1 * w0.y + y2 * w0.z + y3 * w0.w;
    g1 += y0 * w1.x + y1 * w1.y + y2 * w1.z + y3 * w1.w;
    g2 += y0 * w2.x + y1 * w2.y + y2 * w2.z + y3 * w2.w;
    g3 += y0 * w3.x + y1 * w3.y + y2 * w3.z + y3 * w3.w;
  }
  g0 = wave_sum(g0);
  g1 = wave_sum(g1);
  g2 = wave_sum(g2);
  g3 = wave_sum(g3);
  if (lane == 0) {
    gbuf[wid][0] = g0; gbuf[wid][1] = g1; gbuf[wid][2] = g2; gbuf[wid][3] = g3;
  }
  __syncthreads();
  if (tid == 0) {
    float l[4];
#pragma unroll
    for (int e = 0; e < 4; ++e) l[e] = gbuf[0][e] + gbuf[1][e] + gbuf[2][e] + gbuf[3][e];
    float mx = fmaxf(fmaxf(l[0], l[1]), fmaxf(l[2], l[3]));
    float ex[4], sum = 0.f;
#pragma unroll
    for (int e = 0; e < 4; ++e) { ex[e] = expf(l[e] - mx); sum += ex[e]; }
    float p[4];
#pragma unroll
    for (int e = 0; e < 4; ++e) p[e] = ex[e] / sum;
    int i1 = 0;
    for (int e = 1; e < 4; ++e)
      if (p[e] > p[i1]) i1 = e;
    int i2 = -1;
    for (int e = 0; e < 4; ++e) {
      if (e == i1) continue;
      if (i2 < 0 || p[e] > p[i2]) i2 = e;
    }
    float w[4] = {0.f, 0.f, 0.f, 0.f};
    w[i1] = p[i1];
    w[i2] = p[i2];
    *(float4*)&wd[(size_t)t * 4] = make_float4(w[0], w[1], w[2], w[3]);
  }
}

// Concatenated padded top-2 compaction. One block, 256 threads, 8 tokens each.
// Outputs: idx_all[MPAD] token ids (pad=0), seg[5] 128-aligned segment offsets,
// slotAB[2048*2] absolute compact rows, wAB[2048*2] weights.
__global__ __launch_bounds__(256) void route_compact(const float* __restrict__ wd,
                                                     int* __restrict__ idx_all,
                                                     int* __restrict__ seg,
                                                     int* __restrict__ slotAB,
                                                     float* __restrict__ wAB) {
  __shared__ unsigned short c[256][4];
  __shared__ int offs[256][4];
  __shared__ int segs[5];
  const int t = threadIdx.x;
  for (int i = t; i < MPAD; i += 256) idx_all[i] = 0;
  unsigned char sel[8];
  float wv4[8][4];
  unsigned short lc[4] = {0, 0, 0, 0};
#pragma unroll
  for (int k = 0; k < 8; ++k) {
    int tok = t * 8 + k;
    float4 w = *(const float4*)&wd[(size_t)tok * 4];
    wv4[k][0] = w.x; wv4[k][1] = w.y; wv4[k][2] = w.z; wv4[k][3] = w.w;
    unsigned m = 0;
    if (w.x != 0.f) { m |= 1; lc[0]++; }
    if (w.y != 0.f) { m |= 2; lc[1]++; }
    if (w.z != 0.f) { m |= 4; lc[2]++; }
    if (w.w != 0.f) { m |= 8; lc[3]++; }
    sel[k] = (unsigned char)m;
  }
#pragma unroll
  for (int e = 0; e < 4; ++e) c[t][e] = lc[e];
  __syncthreads();
  if (t == 0) {
    int run[4] = {0, 0, 0, 0};
    for (int i = 0; i < 256; ++i) {
#pragma unroll
      for (int e = 0; e < 4; ++e) {
        offs[i][e] = run[e];
        run[e] += c[i][e];
      }
    }
    int s = 0;
    segs[0] = 0;
#pragma unroll
    for (int e = 0; e < 4; ++e) {
      s += (run[e] + 127) & ~127;
      segs[e + 1] = s;
    }
#pragma unroll
    for (int e = 0; e < 5; ++e) seg[e] = segs[e];
  }
  __syncthreads();
  int o[4];
#pragma unroll
  for (int e = 0; e < 4; ++e) o[e] = segs[e] + offs[t][e];
#pragma unroll
  for (int k = 0; k < 8; ++k) {
    int tok = t * 8 + k;
    unsigned m = sel[k];
    int sl[2] = {0, 0};
    float sw[2] = {0.f, 0.f};
    int ns = 0;
#pragma unroll
    for (int e = 0; e < 4; ++e) {
      if ((m >> e) & 1) {
        if (ns < 2) { sl[ns] = o[e]; sw[ns] = wv4[k][e]; }
        idx_all[o[e]++] = tok;
        ns++;
      }
    }
    if (ns == 1) { sl[1] = sl[0]; sw[1] = 0.f; }
    slotAB[tok * 2] = sl[0];
    slotAB[tok * 2 + 1] = sl[1];
    wAB[tok * 2] = sw[0];
    wAB[tok * 2 + 1] = sw[1];
  }
}

// ---------------- GEMM: C[M,N] = A[M,K](fp16) @ B[N,K](fp16)^T ----------------
// 128x128 tile, BK=32, 4 waves, 2-phase double-buffered global_load_lds prefetch.
// m-FASTEST block order + bijective XCD swizzle (grid always %8==0).
// MODE: 0 dense | 1 concat-gather: A rows = idx[m], B selected by seg segment,
//       bound total=seg[4] | 2 concat-direct: A compact rows, B by seg, bound.
// EPI: 1 f32 aux0[n]*(v+bias)+aux1 | 3(unused) | 4 fp16(+bias) |
//      5 fused swiglu -> fp16 Nh=N/2 | 6 final: aux0[n]*(v + wA*yc[slA]+wB*yc[slB]) + aux1
template <int EPI, int MODE>
__global__ __launch_bounds__(256) void gemm128(
    const unsigned short* __restrict__ A, const unsigned short* __restrict__ B,
    const float* __restrict__ bias, void* __restrict__ Cv,
    const float* __restrict__ aux0, const float* __restrict__ aux1,
    const int* __restrict__ idx, const int* __restrict__ seg,
    const int* __restrict__ slotAB, const float* __restrict__ wAB,
    const unsigned short* __restrict__ yc, int M, int N, int K) {
  __shared__ unsigned short smem[16384];  // 2 bufs x (A 4096 + B 4096)
  const int tid = threadIdx.x;
  const int lane = tid & 63;
  const int wv = tid >> 6;
  const int nwg = gridDim.x;
  const int bid = blockIdx.x;
  const int swzb = (bid & 7) * (nwg >> 3) + (bid >> 3);
  const int gm = M >> 7;
  const int m0 = (swzb % gm) * 128, n0 = (swzb / gm) * 128;
  if (MODE != 0 && m0 >= seg[4]) return;

  const unsigned short* Bp = B;
  if constexpr (MODE != 0) {
    int e = 0;
#pragma unroll
    for (int i = 1; i < 4; ++i)
      if (m0 >= seg[i]) e = i;
    Bp = B + (size_t)e * N * K;
  }

  const int wm = (wv >> 1) * 64, wn = (wv & 1) * 64;
  const int fr = lane & 15, fc = lane >> 4;

  // staging geometry: wave wv stages rows [wv*16, wv*16+16) and [64+wv*16, ...)
  const int rl = lane >> 2, ch = lane & 3;
  const int R1 = wv * 16 + rl;
  const int R2 = 64 + R1;
  const int co1 = ((ch ^ ((R1 >> 1) & 3)) << 3);
  const int co2 = ((ch ^ ((R2 >> 1) & 3)) << 3);
  size_t ar1, ar2;
  if constexpr (MODE == 1) {
    ar1 = (size_t)idx[m0 + R1] * K;
    ar2 = (size_t)idx[m0 + R2] * K;
  } else {
    ar1 = (size_t)(m0 + R1) * K;
    ar2 = (size_t)(m0 + R2) * K;
  }
  const unsigned short* gA1 = A + ar1 + co1;
  const unsigned short* gA2 = A + ar2 + co2;
  const unsigned short* gB1 = Bp + (size_t)(n0 + R1) * K + co1;
  const unsigned short* gB2 = Bp + (size_t)(n0 + R2) * K + co2;
  const int lA1 = (wv * 16) * 32, lA2 = (64 + wv * 16) * 32;

  f32x4 acc[4][4];
#pragma unroll
  for (int i = 0; i < 4; ++i) {
#pragma unroll
    for (int j = 0; j < 4; ++j) acc[i][j] = (f32x4)0.f;
  }

  auto STAGE = [&](int buf, int kt) {
    unsigned short* base = smem + buf * 8192;
    gld16(gA1 + kt, base + lA1);
    gld16(gA2 + kt, base + lA2);
    gld16(gB1 + kt, base + 4096 + lA1);
    gld16(gB2 + kt, base + 4096 + lA2);
  };
  auto COMPUTE = [&](int buf) {
    const unsigned short* sA = smem + buf * 8192;
    const unsigned short* sB = sA + 4096;
    f16x8 a[4], b[4];
#pragma unroll
    for (int mi = 0; mi < 4; ++mi) {
      int r = wm + mi * 16 + fr;
      a[mi] = *(const f16x8*)&sA[r * 32 + ((fc ^ ((r >> 1) & 3)) << 3)];
    }
#pragma unroll
    for (int ni = 0; ni < 4; ++ni) {
      int r = wn + ni * 16 + fr;
      b[ni] = *(const f16x8*)&sB[r * 32 + ((fc ^ ((r >> 1) & 3)) << 3)];
    }
#pragma unroll
    for (int mi = 0; mi < 4; ++mi) {
#pragma unroll
      for (int ni = 0; ni < 4; ++ni) acc[mi][ni] = MFMA16(a[mi], b[ni], acc[mi][ni]);
    }
  };

  const int nk = K >> 5;
  STAGE(0, 0);
  __syncthreads();
  int cur = 0;
  for (int t = 1; t < nk; ++t) {
    STAGE(cur ^ 1, t << 5);
    COMPUTE(cur);
    __syncthreads();
    cur ^= 1;
  }
  COMPUTE(cur);

  // epilogues; frag: D[row=(lane>>4)*4+i][col=lane&15]
  if constexpr (EPI == 5) {
    unsigned short* Ch = (unsigned short*)Cv;
    const int Nh = N >> 1;
#pragma unroll
    for (int mi = 0; mi < 4; ++mi) {
#pragma unroll
      for (int p = 0; p < 2; ++p) {
        const int hcol = (((n0 + wn) >> 5) + p) * 16 + fr;
        const int mb = m0 + wm + mi * 16 + fc * 4;
#pragma unroll
        for (int i = 0; i < 4; ++i) {
          const int m = mb + i;
          float v1 = acc[mi][2 * p][i];
          float v3 = acc[mi][2 * p + 1][i];
          float y = v1 / (1.f + __expf(-v1)) * v3;
          Ch[(size_t)m * Nh + hcol] = f2h(y);
        }
      }
    }
    return;
  }
#pragma unroll
  for (int mi = 0; mi < 4; ++mi) {
#pragma unroll
    for (int ni = 0; ni < 4; ++ni) {
      const int n = n0 + wn + ni * 16 + fr;
      const int mb = m0 + wm + mi * 16 + fc * 4;
#pragma unroll
      for (int i = 0; i < 4; ++i) {
        const int m = mb + i;
        float v = acc[mi][ni][i];
        const size_t cidx = (size_t)m * N + n;
        if constexpr (EPI == 1) {
          ((float*)Cv)[cidx] = aux0[n] * (v + bias[n]) + aux1[cidx];
        } else if constexpr (EPI == 4) {
          if (bias) v += bias[n];
          ((unsigned short*)Cv)[cidx] = f2h(v);
        } else if constexpr (EPI == 6) {
          const int sA_ = slotAB[m * 2], sB_ = slotAB[m * 2 + 1];
          const float wA_ = wAB[m * 2], wB_ = wAB[m * 2 + 1];
          float vm = wA_ * h2f(yc[(size_t)sA_ * N + n]) + wB_ * h2f(yc[(size_t)sB_ * N + n]);
          ((float*)Cv)[cidx] = aux0[n] * (v + vm) + aux1[cidx];
        }
      }
    }
  }
}

// ---------------- host ----------------

extern "C" void kernel_launch(void* const* d_in, const int* in_sizes, int n_in,
                              void* d_out, int out_size, void* d_ws, size_t ws_size,
                              hipStream_t stream) {
  (void)in_sizes; (void)n_in; (void)out_size; (void)ws_size;
  const float* hs = (const float*)d_in[0];
  const float* temb = (const float*)d_in[1];
  const float* rope = (const float*)d_in[2];
  const float* adaw = (const float*)d_in[3];
  const float* adab = (const float*)d_in[4];
  const float* qkvw = (const float*)d_in[5];
  const float* qkvb = (const float*)d_in[6];
  const float* qnw = (const float*)d_in[7];
  const float* knw = (const float*)d_in[8];
  const float* outw = (const float*)d_in[9];
  const float* outb = (const float*)d_in[10];
  const float* gatew = (const float*)d_in[11];
  const float* ew1 = (const float*)d_in[12];
  const float* ew2 = (const float*)d_in[13];
  const float* ew3 = (const float*)d_in[14];
  const float* sw1 = (const float*)d_in[15];
  const float* sw2 = (const float*)d_in[16];
  const float* sw3 = (const float*)d_in[17];
  float* out = (float*)d_out;
  char* ws = (char*)d_ws;

  size_t off = 0;
  auto give = [&](size_t nbytes) {
    size_t r = off;
    off += (nbytes + 255) & ~(size_t)255;
    return r;
  };
  const size_t T = T_TOK, D = DIM;
  size_t o_mod = give(15360 * 4);
  size_t o_ss = give(D * 4);
  size_t o_wd = give(T * 4 * 4);
  size_t o_idx = give(MPAD * 4);
  size_t o_seg = give(8 * 4);
  size_t o_slot = give(T * 2 * 4);
  size_t o_wab = give(T * 2 * 4);
  size_t o_nh = give(T * D * 2);      // nh fp16; later nh2
  size_t o_qkvh = give(T * 7680 * 2); // qkv fp16; region later reused as hmid
  size_t o_qh = give(T * D * 2);
  size_t o_kh = give(T * D * 2);
  size_t o_vt = give(T * D * 2);
  size_t o_obf = give(T * D * 2);
  size_t o_h2 = give(T * D * 4);
  size_t o_yc = give((size_t)MPAD * D * 2);       // compact expert outputs fp16
  size_t o_hmid2 = give(T * SHID_E * 2);          // shared-expert mid
  // fp16 weights
  size_t o_qkvw = give((size_t)7680 * 2560 * 2);
  size_t o_outw = give((size_t)2560 * 2560 * 2);
  size_t o_ewA = give((size_t)4 * 2 * HID_E * 2560 * 2);  // interleaved w1/w3
  size_t o_ew2 = give((size_t)4 * 2560 * HID_E * 2);
  size_t o_swA = give((size_t)2 * SHID_E * 2560 * 2);     // interleaved sw1/sw3
  size_t o_sw2 = give((size_t)2560 * SHID_E * 2);

  float* mod = (float*)(ws + o_mod);
  float* ss = (float*)(ws + o_ss);
  float* wd = (float*)(ws + o_wd);
  int* idxb = (int*)(ws + o_idx);
  int* segp = (int*)(ws + o_seg);
  int* slotAB = (int*)(ws + o_slot);
  float* wAB = (float*)(ws + o_wab);
  unsigned short* nh_h = (unsigned short*)(ws + o_nh);
  unsigned short* qkvh = (unsigned short*)(ws + o_qkvh);
  unsigned short* qh = (unsigned short*)(ws + o_qh);
  unsigned short* kh = (unsigned short*)(ws + o_kh);
  unsigned short* vt = (unsigned short*)(ws + o_vt);
  unsigned short* obf = (unsigned short*)(ws + o_obf);
  float* h2 = (float*)(ws + o_h2);
  unsigned short* yc = (unsigned short*)(ws + o_yc);
  unsigned short* hmid2 = (unsigned short*)(ws + o_hmid2);
  unsigned short* qkvw_h = (unsigned short*)(ws + o_qkvw);
  unsigned short* outw_h = (unsigned short*)(ws + o_outw);
  unsigned short* ewA_h = (unsigned short*)(ws + o_ewA);
  unsigned short* ew2_h = (unsigned short*)(ws + o_ew2);
  unsigned short* swA_h = (unsigned short*)(ws + o_swA);
  unsigned short* sw2_h = (unsigned short*)(ws + o_sw2);
  unsigned short* nh2 = nh_h;
  // hmid (MPAD x 6912 fp16 = 70.8 MB) aliases qkvh..obf (73.4 MB), dead after out-proj
  unsigned short* hmid = qkvh;

  // 0) weight conversion f32 -> fp16 (+ w1/w3 interleave for fused swiglu)
  cvt_f16<<<2048, 256, 0, stream>>>(qkvw, qkvw_h, 7680 * 2560 / 8);
  cvt_f16<<<2048, 256, 0, stream>>>(outw, outw_h, 2560 * 2560 / 8);
  cvt_f16<<<2048, 256, 0, stream>>>(ew2, ew2_h, 4 * 2560 * HID_E / 8);
  cvt_f16<<<2048, 256, 0, stream>>>(sw2, sw2_h, 2560 * SHID_E / 8);
  for (int e = 0; e < 4; ++e) {
    cvt_pair<<<2 * HID_E, 256, 0, stream>>>(ew1 + (size_t)e * HID_E * DIM,
                                            ew3 + (size_t)e * HID_E * DIM,
                                            ewA_h + (size_t)e * 2 * HID_E * DIM);
  }
  cvt_pair<<<2 * SHID_E, 256, 0, stream>>>(sw1, sw3, swA_h);
  // 1) adaLN modulation
  silu_k<<<10, 256, 0, stream>>>(temb, ss);
  adaln_gemv<<<3840, 256, 0, stream>>>(ss, adaw, adab, mod);
  // 2) LN1 + modulate (fp16)
  ln_mod<<<T, 256, 0, stream>>>(hs, mod, mod + D, nh_h);
  // 3) qkv GEMM -> fp16
  gemm128<4, 0><<<16 * 60, 256, 0, stream>>>(nh_h, qkvw_h, qkvb, qkvh,
                                             nullptr, nullptr, nullptr, nullptr,
                                             nullptr, nullptr, nullptr, 2048, 7680, 2560);
  // 4) RMSNorm + RoPE
  rmsrope<<<T, 256, 0, stream>>>(qkvh, qnw, knw, rope, qh, kh);
  // 5) V transpose
  transpose_v<<<dim3(80, 64), dim3(32, 8), 0, stream>>>(qkvh, vt);
  // 6) MFMA flash attention
  fattn<<<dim3(32, 20), 256, 0, stream>>>(qh, kh, vt, obf);
  // 7) out proj + gate_msa residual -> h2 f32
  gemm128<1, 0><<<16 * 20, 256, 0, stream>>>(obf, outw_h, outb, h2,
                                             mod + 2 * D, hs, nullptr, nullptr,
                                             nullptr, nullptr, nullptr, 2048, 2560, 2560);
  // 8) LN2 + modulate + routing, then concatenated padded compaction
  ln2_route<<<T, 256, 0, stream>>>(h2, mod + 3 * D, mod + 4 * D, gatew, nh2, wd);
  route_compact<<<1, 256, 0, stream>>>(wd, idxb, segp, slotAB, wAB);
  // 9) MoE experts: ONE fused w1w3+swiglu GEMM + ONE w2 GEMM over all experts
  gemm128<5, 1><<<40 * 108, 256, 0, stream>>>(nh2, ewA_h, nullptr, hmid,
                                              nullptr, nullptr, idxb, segp,
                                              nullptr, nullptr, nullptr,
                                              MPAD, 2 * HID_E, 2560);
  gemm128<4, 2><<<40 * 20, 256, 0, stream>>>(hmid, ew2_h, nullptr, yc,
                                             nullptr, nullptr, nullptr, segp,
                                             nullptr, nullptr, nullptr,
                                             MPAD, 2560, 6912);
  // 10) shared expert (fused w1w3+swiglu) + final combine w/ yc gather
  gemm128<5, 0><<<16 * 56, 256, 0, stream>>>(nh2, swA_h, nullptr, hmid2,
                                             nullptr, nullptr, nullptr, nullptr,
                                             nullptr, nullptr, nullptr, 2048, 2 * SHID_E, 2560);
  gemm128<6, 0><<<16 * 20, 256, 0, stream>>>(hmid2, sw2_h, nullptr, out,
                                             mod + 5 * D, h2, nullptr, nullptr,
                                             slotAB, wAB, yc, 2048, 2560, 3584);
}

// Round 7
// 1487.245 us; speedup vs baseline: 3.5627x; 1.0824x over previous
//
#include <hip/hip_runtime.h>

#define DIM 2560
#define T_TOK 2048
#define NHEADS 20
#define HD 128
#define HID_E 6912
#define SHID_E 3584
#define MPAD 5120  // concat rows, segments padded to 256 (max 4096+4*255 <= 5120)

typedef _Float16 f16x8 __attribute__((ext_vector_type(8)));
typedef float f32x4 __attribute__((ext_vector_type(4)));
typedef unsigned short u16x8 __attribute__((ext_vector_type(8)));

#define MFMA16(a, b, c) __builtin_amdgcn_mfma_f32_16x16x32_f16((a), (b), (c), 0, 0, 0)

__device__ inline unsigned short f2h(float f) {
  return __builtin_bit_cast(unsigned short, (_Float16)f);
}
__device__ inline float h2f(unsigned short u) {
  return (float)__builtin_bit_cast(_Float16, u);
}
__device__ inline float wave_sum(float v) {
#pragma unroll
  for (int off = 32; off > 0; off >>= 1) v += __shfl_down(v, off, 64);
  return v;
}
// async global->LDS, 16B per lane; LDS dest = wave-uniform base + lane*16
__device__ inline void gld16(const void* g, void* l) {
  __builtin_amdgcn_global_load_lds((const __attribute__((address_space(1))) void*)g,
                                   (__attribute__((address_space(3))) void*)l, 16, 0, 0);
}

// ---------------- tiny kernels ----------------

__global__ __launch_bounds__(256) void silu_k(const float* __restrict__ t,
                                              float* __restrict__ ss) {
  int i = blockIdx.x * 256 + threadIdx.x;
  if (i < DIM) {
    float v = t[i];
    ss[i] = v / (1.f + expf(-v));
  }
}

__global__ __launch_bounds__(256) void cvt_f16(const float* __restrict__ in,
                                               unsigned short* __restrict__ outp, int n8) {
  const int stride = gridDim.x * 256;
  for (int i = blockIdx.x * 256 + threadIdx.x; i < n8; i += stride) {
    float4 a = *(const float4*)(in + (size_t)i * 8);
    float4 b = *(const float4*)(in + (size_t)i * 8 + 4);
    u16x8 u;
    u[0] = f2h(a.x); u[1] = f2h(a.y); u[2] = f2h(a.z); u[3] = f2h(a.w);
    u[4] = f2h(b.x); u[5] = f2h(b.y); u[6] = f2h(b.z); u[7] = f2h(b.w);
    *(u16x8*)&outp[(size_t)i * 8] = u;
  }
}

// interleave w1/w3 rows into B' : row j -> (j&31)<16 ? w1[(j>>5)*16+(j&15)]
//                                          : w3[(j>>5)*16+(j&15)]
__global__ __launch_bounds__(256) void cvt_pair(const float* __restrict__ w1,
                                                const float* __restrict__ w3,
                                                unsigned short* __restrict__ outp) {
  const int j = blockIdx.x;
  const int g = j >> 5, r = j & 31;
  const float* src = (r < 16) ? (w1 + (size_t)(g * 16 + r) * DIM)
                              : (w3 + (size_t)(g * 16 + (r & 15)) * DIM);
  unsigned short* dst = outp + (size_t)j * DIM;
  for (int i = threadIdx.x; i < 320; i += 256) {
    float4 a = *(const float4*)(src + i * 8);
    float4 b = *(const float4*)(src + i * 8 + 4);
    u16x8 u;
    u[0] = f2h(a.x); u[1] = f2h(a.y); u[2] = f2h(a.z); u[3] = f2h(a.w);
    u[4] = f2h(b.x); u[5] = f2h(b.y); u[6] = f2h(b.z); u[7] = f2h(b.w);
    *(u16x8*)&dst[i * 8] = u;
  }
}

// mod[j] = dot(silu(temb), adaln_w[j]) + adaln_b[j]; one wave per output
__global__ __launch_bounds__(256) void adaln_gemv(const float* __restrict__ ss,
                                                  const float* __restrict__ W,
                                                  const float* __restrict__ bias,
                                                  float* __restrict__ mod) {
  const int lane = threadIdx.x & 63;
  const int j = blockIdx.x * 4 + (threadIdx.x >> 6);
  const float* wr = W + (size_t)j * DIM;
  float p = 0.f;
  for (int i = lane; i < 640; i += 64) {
    float4 w = *(const float4*)(wr + i * 4);
    float4 x = *(const float4*)(ss + i * 4);
    p += w.x * x.x + w.y * x.y + w.z * x.z + w.w * x.w;
  }
  p = wave_sum(p);
  if (lane == 0) mod[j] = p + bias[j];
}

// LN (no affine) then *(1+scale)+shift, write fp16. One block per row.
__global__ __launch_bounds__(256) void ln_mod(const float* __restrict__ x,
                                              const float* __restrict__ shift,
                                              const float* __restrict__ scale,
                                              unsigned short* __restrict__ outp) {
  __shared__ float rbuf[8];
  const int t = blockIdx.x, tid = threadIdx.x, lane = tid & 63, wid = tid >> 6;
  const float* xr = x + (size_t)t * DIM;
  float s = 0.f, sq = 0.f;
  for (int i = tid; i < 640; i += 256) {
    float4 v = *(const float4*)(xr + i * 4);
    s += v.x + v.y + v.z + v.w;
    sq += v.x * v.x + v.y * v.y + v.z * v.z + v.w * v.w;
  }
  s = wave_sum(s);
  sq = wave_sum(sq);
  if (lane == 0) {
    rbuf[wid] = s;
    rbuf[4 + wid] = sq;
  }
  __syncthreads();
  float S = rbuf[0] + rbuf[1] + rbuf[2] + rbuf[3];
  float SQ = rbuf[4] + rbuf[5] + rbuf[6] + rbuf[7];
  float mean = S * (1.f / DIM);
  float rs = rsqrtf(SQ * (1.f / DIM) - mean * mean + 1e-6f);
  for (int i = tid; i < 640; i += 256) {
    float4 v = *(const float4*)(xr + i * 4);
    float4 sc4 = *(const float4*)(scale + i * 4);
    float4 sh4 = *(const float4*)(shift + i * 4);
    ushort4 u;
    u.x = f2h((v.x - mean) * rs * (1.f + sc4.x) + sh4.x);
    u.y = f2h((v.y - mean) * rs * (1.f + sc4.y) + sh4.y);
    u.z = f2h((v.z - mean) * rs * (1.f + sc4.z) + sh4.z);
    u.w = f2h((v.w - mean) * rs * (1.f + sc4.w) + sh4.w);
    *(ushort4*)&outp[(size_t)t * DIM + i * 4] = u;
  }
}

// RMSNorm(q),(k) over full 2560 + weight + RoPE -> qh (scaled by 1/sqrt(128)), kh
__global__ __launch_bounds__(256) void rmsrope(const unsigned short* __restrict__ qkv,
                                               const float* __restrict__ qn,
                                               const float* __restrict__ kn,
                                               const float* __restrict__ rope,
                                               unsigned short* __restrict__ qh,
                                               unsigned short* __restrict__ kh) {
  __shared__ float rbuf[8];
  const int t = blockIdx.x, tid = threadIdx.x, lane = tid & 63, wid = tid >> 6;
  const unsigned short* row = qkv + (size_t)t * 7680;
  float sq = 0.f, sk = 0.f;
  for (int i = tid; i < 320; i += 256) {
    f16x8 qv = *(const f16x8*)(row + i * 8);
    f16x8 kv = *(const f16x8*)(row + DIM + i * 8);
#pragma unroll
    for (int j = 0; j < 8; ++j) {
      float q = (float)qv[j], k = (float)kv[j];
      sq += q * q;
      sk += k * k;
    }
  }
  sq = wave_sum(sq);
  sk = wave_sum(sk);
  if (lane == 0) {
    rbuf[wid] = sq;
    rbuf[4 + wid] = sk;
  }
  __syncthreads();
  float SQ = rbuf[0] + rbuf[1] + rbuf[2] + rbuf[3];
  float SK = rbuf[4] + rbuf[5] + rbuf[6] + rbuf[7];
  float rq = rsqrtf(SQ * (1.f / DIM) + 1e-6f) * 0.08838834764831845f;
  float rk = rsqrtf(SK * (1.f / DIM) + 1e-6f);
  for (int pp = tid; pp < 1280; pp += 256) {
    int c = pp * 2;
    float qe = h2f(row[c]) * rq * qn[c], qo = h2f(row[c + 1]) * rq * qn[c + 1];
    float ke = h2f(row[DIM + c]) * rk * kn[c], ko = h2f(row[DIM + c + 1]) * rk * kn[c + 1];
    float4 rr = *(const float4*)(rope + (size_t)t * 256 + (pp & 63) * 4);
    unsigned qp = (unsigned)f2h(rr.x * qe + rr.y * qo) |
                  ((unsigned)f2h(rr.z * qe + rr.w * qo) << 16);
    unsigned kp = (unsigned)f2h(rr.x * ke + rr.y * ko) |
                  ((unsigned)f2h(rr.z * ke + rr.w * ko) << 16);
    *(unsigned*)&qh[(size_t)t * DIM + c] = qp;
    *(unsigned*)&kh[(size_t)t * DIM + c] = kp;
  }
}

// V part of qkv (fp16 [2048][7680] at col 5120) -> vt fp16 [2560][2048]
__global__ void transpose_v(const unsigned short* __restrict__ in,
                            unsigned short* __restrict__ outp) {
  __shared__ unsigned short tile[32][33];
  const int bx = blockIdx.x * 32;  // channel
  const int by = blockIdx.y * 32;  // token
  const int tx = threadIdx.x, ty = threadIdx.y;
  for (int j = ty; j < 32; j += 8)
    tile[j][tx] = in[(size_t)(by + j) * 7680 + 5120 + bx + tx];
  __syncthreads();
  for (int j = ty; j < 32; j += 8)
    outp[(size_t)(bx + j) * T_TOK + by + tx] = tile[tx][j];
}

// ---------------- MFMA flash attention ----------------
__global__ __launch_bounds__(256) void fattn(const unsigned short* __restrict__ qh,
                                             const unsigned short* __restrict__ kh,
                                             const unsigned short* __restrict__ vt,
                                             unsigned short* __restrict__ obuf) {
  __shared__ unsigned short sK[64 * 128];  // [k][d], slot = c ^ (r&15)
  __shared__ unsigned short sV[128 * 64];  // [d][k], slot = c ^ (r&7)
  __shared__ unsigned short sP[64 * 64];   // [q][k], slot = c ^ (r&7)
  __shared__ float sRedM[4][64];
  __shared__ float sRedL[4][64];
  __shared__ float sM[64];
  __shared__ float sL[64];
  const int tid = threadIdx.x, lane = tid & 63, wv = tid >> 6;
  const int g = lane >> 4, fr = lane & 15;
  const int h = blockIdx.y;
  const int q0 = blockIdx.x * 64;

  {
    const int r = tid >> 2, qt = tid & 3;
    const unsigned short* gp = qh + (size_t)(q0 + r) * DIM + h * HD + qt * 32;
    uint4 v0 = ((const uint4*)gp)[0];
    uint4 v1 = ((const uint4*)gp)[1];
    uint4 v2 = ((const uint4*)gp)[2];
    uint4 v3 = ((const uint4*)gp)[3];
    unsigned short* dst = &sK[r * 128];
    const int cb = qt * 4, rs = r & 15;
    *(uint4*)&dst[((cb + 0) ^ rs) * 8] = v0;
    *(uint4*)&dst[((cb + 1) ^ rs) * 8] = v1;
    *(uint4*)&dst[((cb + 2) ^ rs) * 8] = v2;
    *(uint4*)&dst[((cb + 3) ^ rs) * 8] = v3;
  }
  __syncthreads();
  f16x8 qfrag[4][4];
#pragma unroll
  for (int ni = 0; ni < 4; ++ni) {
#pragma unroll
    for (int kt = 0; kt < 4; ++kt) {
      int r = ni * 16 + fr;
      qfrag[ni][kt] = *(const f16x8*)&sK[r * 128 + (((kt * 4 + g) ^ (r & 15)) << 3)];
    }
  }
  __syncthreads();

  f32x4 acco[4][2];
  f32x4 mprev[4];
  float mrun[4], lrun[4];
#pragma unroll
  for (int i = 0; i < 4; ++i) {
    acco[i][0] = (f32x4)0.f;
    acco[i][1] = (f32x4)0.f;
    mprev[i] = (f32x4)(-1e30f);
    mrun[i] = -1e30f;
    lrun[i] = 0.f;
  }

  for (int kt0 = 0; kt0 < T_TOK; kt0 += 64) {
    {
      const int r = tid >> 2, qt = tid & 3;
      const unsigned short* gp = kh + (size_t)(kt0 + r) * DIM + h * HD + qt * 32;
      uint4 v0 = ((const uint4*)gp)[0];
      uint4 v1 = ((const uint4*)gp)[1];
      uint4 v2 = ((const uint4*)gp)[2];
      uint4 v3 = ((const uint4*)gp)[3];
      unsigned short* dst = &sK[r * 128];
      const int cb = qt * 4, rs = r & 15;
      *(uint4*)&dst[((cb + 0) ^ rs) * 8] = v0;
      *(uint4*)&dst[((cb + 1) ^ rs) * 8] = v1;
      *(uint4*)&dst[((cb + 2) ^ rs) * 8] = v2;
      *(uint4*)&dst[((cb + 3) ^ rs) * 8] = v3;
      const int rv = tid >> 1, hf = tid & 1;
      const unsigned short* gv = vt + (size_t)(h * HD + rv) * T_TOK + kt0 + hf * 32;
      uint4 w0 = ((const uint4*)gv)[0];
      uint4 w1 = ((const uint4*)gv)[1];
      uint4 w2 = ((const uint4*)gv)[2];
      uint4 w3 = ((const uint4*)gv)[3];
      unsigned short* dv = &sV[rv * 64];
      const int cv = hf * 4, rvs = rv & 7;
      *(uint4*)&dv[((cv + 0) ^ rvs) * 8] = w0;
      *(uint4*)&dv[((cv + 1) ^ rvs) * 8] = w1;
      *(uint4*)&dv[((cv + 2) ^ rvs) * 8] = w2;
      *(uint4*)&dv[((cv + 3) ^ rvs) * 8] = w3;
    }
    __syncthreads();  // B0

    f32x4 accs[4] = {(f32x4)0.f, (f32x4)0.f, (f32x4)0.f, (f32x4)0.f};
#pragma unroll
    for (int kt = 0; kt < 4; ++kt) {
      int r = wv * 16 + fr;
      f16x8 ak = *(const f16x8*)&sK[r * 128 + (((kt * 4 + g) ^ (r & 15)) << 3)];
#pragma unroll
      for (int ni = 0; ni < 4; ++ni) accs[ni] = MFMA16(ak, qfrag[ni][kt], accs[ni]);
    }

    float pm[4];
#pragma unroll
    for (int ni = 0; ni < 4; ++ni) {
      float m = fmaxf(fmaxf(accs[ni][0], accs[ni][1]), fmaxf(accs[ni][2], accs[ni][3]));
      m = fmaxf(m, __shfl_xor(m, 16));
      m = fmaxf(m, __shfl_xor(m, 32));
      pm[ni] = m;
    }
    if (g == 0) {
#pragma unroll
      for (int ni = 0; ni < 4; ++ni) sRedM[wv][ni * 16 + fr] = pm[ni];
    }
    __syncthreads();  // B1
    float mnew[4];
#pragma unroll
    for (int ni = 0; ni < 4; ++ni) {
      int q = ni * 16 + fr;
      float mt = fmaxf(fmaxf(sRedM[0][q], sRedM[1][q]), fmaxf(sRedM[2][q], sRedM[3][q]));
      mnew[ni] = fmaxf(mrun[ni], mt);
    }
    float lsum[4];
#pragma unroll
    for (int ni = 0; ni < 4; ++ni) {
      float l0 = 0.f;
#pragma unroll
      for (int i = 0; i < 4; ++i) {
        float p = __expf(accs[ni][i] - mnew[ni]);
        accs[ni][i] = p;
        l0 += p;
      }
      l0 += __shfl_xor(l0, 16);
      l0 += __shfl_xor(l0, 32);
      lsum[ni] = l0;
    }
    if (g == 0) {
#pragma unroll
      for (int ni = 0; ni < 4; ++ni) sRedL[wv][ni * 16 + fr] = lsum[ni];
      if (wv == 0) {
#pragma unroll
        for (int ni = 0; ni < 4; ++ni) sM[ni * 16 + fr] = mnew[ni];
      }
    }
#pragma unroll
    for (int ni = 0; ni < 4; ++ni) {
      int q = ni * 16 + fr;
      unsigned p01 = (unsigned)f2h(accs[ni][0]) | ((unsigned)f2h(accs[ni][1]) << 16);
      unsigned p23 = (unsigned)f2h(accs[ni][2]) | ((unsigned)f2h(accs[ni][3]) << 16);
      uint2 pk;
      pk.x = p01;
      pk.y = p23;
      *(uint2*)&sP[q * 64 + ((((wv << 1) | (g >> 1)) ^ (q & 7)) << 3) + ((g & 1) << 2)] = pk;
    }
    __syncthreads();  // B2
#pragma unroll
    for (int ni = 0; ni < 4; ++ni) {
      int q = ni * 16 + fr;
      float lt = sRedL[0][q] + sRedL[1][q] + sRedL[2][q] + sRedL[3][q];
      lrun[ni] = lrun[ni] * __expf(mrun[ni] - mnew[ni]) + lt;
      mrun[ni] = mnew[ni];
    }

#pragma unroll
    for (int mi = 0; mi < 4; ++mi) {
      f32x4 mn = *(const f32x4*)&sM[mi * 16 + g * 4];
      f32x4 sc;
#pragma unroll
      for (int i = 0; i < 4; ++i) sc[i] = __expf(mprev[mi][i] - mn[i]);
      acco[mi][0] *= sc;
      acco[mi][1] *= sc;
      mprev[mi] = mn;
    }
#pragma unroll
    for (int ktp = 0; ktp < 2; ++ktp) {
      f16x8 bv[2];
#pragma unroll
      for (int nd = 0; nd < 2; ++nd) {
        int r = wv * 32 + nd * 16 + fr;
        bv[nd] = *(const f16x8*)&sV[r * 64 + (((ktp * 4 + g) ^ (r & 7)) << 3)];
      }
#pragma unroll
      for (int mi = 0; mi < 4; ++mi) {
        int r = mi * 16 + fr;
        f16x8 ap = *(const f16x8*)&sP[r * 64 + (((ktp * 4 + g) ^ (r & 7)) << 3)];
        acco[mi][0] = MFMA16(ap, bv[0], acco[mi][0]);
        acco[mi][1] = MFMA16(ap, bv[1], acco[mi][1]);
      }
    }
    __syncthreads();  // B3
  }

  if (wv == 0 && g == 0) {
#pragma unroll
    for (int ni = 0; ni < 4; ++ni) sL[ni * 16 + fr] = 1.f / lrun[ni];
  }
  __syncthreads();
#pragma unroll
  for (int mi = 0; mi < 4; ++mi) {
    f32x4 li = *(const f32x4*)&sL[mi * 16 + g * 4];
#pragma unroll
    for (int nd = 0; nd < 2; ++nd) {
#pragma unroll
      for (int i = 0; i < 4; ++i) {
        float o = acco[mi][nd][i] * li[i];
        obuf[(size_t)(q0 + mi * 16 + g * 4 + i) * DIM + h * HD + wv * 32 + nd * 16 + fr] =
            f2h(o);
      }
    }
  }
}

// LN2 + modulate -> nh2 fp16, plus f32 routing (softmax over 4, top-2, unnormalized)
__global__ __launch_bounds__(256) void ln2_route(const float* __restrict__ x,
                                                 const float* __restrict__ shift,
                                                 const float* __restrict__ scale,
                                                 const float* __restrict__ gw,
                                                 unsigned short* __restrict__ nh2,
                                                 float* __restrict__ wd) {
  __shared__ float rbuf[8];
  __shared__ float gbuf[4][4];
  const int t = blockIdx.x, tid = threadIdx.x, lane = tid & 63, wid = tid >> 6;
  const float* xr = x + (size_t)t * DIM;
  float s = 0.f, sq = 0.f;
  for (int i = tid; i < 640; i += 256) {
    float4 v = *(const float4*)(xr + i * 4);
    s += v.x + v.y + v.z + v.w;
    sq += v.x * v.x + v.y * v.y + v.z * v.z + v.w * v.w;
  }
  s = wave_sum(s);
  sq = wave_sum(sq);
  if (lane == 0) {
    rbuf[wid] = s;
    rbuf[4 + wid] = sq;
  }
  __syncthreads();
  float S = rbuf[0] + rbuf[1] + rbuf[2] + rbuf[3];
  float SQ = rbuf[4] + rbuf[5] + rbuf[6] + rbuf[7];
  float mean = S * (1.f / DIM);
  float rs = rsqrtf(SQ * (1.f / DIM) - mean * mean + 1e-6f);
  float g0 = 0.f, g1 = 0.f, g2 = 0.f, g3 = 0.f;
  for (int i = tid; i < 640; i += 256) {
    float4 v = *(const float4*)(xr + i * 4);
    float4 sc4 = *(const float4*)(scale + i * 4);
    float4 sh4 = *(const float4*)(shift + i * 4);
    float y0 = (v.x - mean) * rs * (1.f + sc4.x) + sh4.x;
    float y1 = (v.y - mean) * rs * (1.f + sc4.y) + sh4.y;
    float y2 = (v.z - mean) * rs * (1.f + sc4.z) + sh4.z;
    float y3 = (v.w - mean) * rs * (1.f + sc4.w) + sh4.w;
    ushort4 u;
    u.x = f2h(y0); u.y = f2h(y1); u.z = f2h(y2); u.w = f2h(y3);
    *(ushort4*)&nh2[(size_t)t * DIM + i * 4] = u;
    float4 w0 = *(const float4*)(gw + i * 4);
    float4 w1 = *(const float4*)(gw + DIM + i * 4);
    float4 w2 = *(const float4*)(gw + 2 * DIM + i * 4);
    float4 w3 = *(const float4*)(gw + 3 * DIM + i * 4);
    g0 += y0 * w0.x + y1 * w0.y + y2 * w0.z + y3 * w0.w;
    g1 += y0 * w1.x + y1 * w1.y + y2 * w1.z + y3 * w1.w;
    g2 += y0 * w2.x + y1 * w2.y + y2 * w2.z + y3 * w2.w;
    g3 += y0 * w3.x + y1 * w3.y + y2 * w3.z + y3 * w3.w;
  }
  g0 = wave_sum(g0);
  g1 = wave_sum(g1);
  g2 = wave_sum(g2);
  g3 = wave_sum(g3);
  if (lane == 0) {
    gbuf[wid][0] = g0; gbuf[wid][1] = g1; gbuf[wid][2] = g2; gbuf[wid][3] = g3;
  }
  __syncthreads();
  if (tid == 0) {
    float l[4];
#pragma unroll
    for (int e = 0; e < 4; ++e) l[e] = gbuf[0][e] + gbuf[1][e] + gbuf[2][e] + gbuf[3][e];
    float mx = fmaxf(fmaxf(l[0], l[1]), fmaxf(l[2], l[3]));
    float ex[4], sum = 0.f;
#pragma unroll
    for (int e = 0; e < 4; ++e) { ex[e] = expf(l[e] - mx); sum += ex[e]; }
    float p[4];
#pragma unroll
    for (int e = 0; e < 4; ++e) p[e] = ex[e] / sum;
    int i1 = 0;
    for (int e = 1; e < 4; ++e)
      if (p[e] > p[i1]) i1 = e;
    int i2 = -1;
    for (int e = 0; e < 4; ++e) {
      if (e == i1) continue;
      if (i2 < 0 || p[e] > p[i2]) i2 = e;
    }
    float w[4] = {0.f, 0.f, 0.f, 0.f};
    w[i1] = p[i1];
    w[i2] = p[i2];
    *(float4*)&wd[(size_t)t * 4] = make_float4(w[0], w[1], w[2], w[3]);
  }
}

// Concatenated padded top-2 compaction. One block, 256 threads, 8 tokens each.
// Segments padded to 256 (for the 256-tile GEMM). idx pad rows point at token 0.
__global__ __launch_bounds__(256) void route_compact(const float* __restrict__ wd,
                                                     int* __restrict__ idx_all,
                                                     int* __restrict__ seg,
                                                     int* __restrict__ slotAB,
                                                     float* __restrict__ wAB) {
  __shared__ unsigned short c[256][4];
  __shared__ int offs[256][4];
  __shared__ int segs[5];
  const int t = threadIdx.x;
  for (int i = t; i < MPAD; i += 256) idx_all[i] = 0;
  unsigned char sel[8];
  float wv4[8][4];
  unsigned short lc[4] = {0, 0, 0, 0};
#pragma unroll
  for (int k = 0; k < 8; ++k) {
    int tok = t * 8 + k;
    float4 w = *(const float4*)&wd[(size_t)tok * 4];
    wv4[k][0] = w.x; wv4[k][1] = w.y; wv4[k][2] = w.z; wv4[k][3] = w.w;
    unsigned m = 0;
    if (w.x != 0.f) { m |= 1; lc[0]++; }
    if (w.y != 0.f) { m |= 2; lc[1]++; }
    if (w.z != 0.f) { m |= 4; lc[2]++; }
    if (w.w != 0.f) { m |= 8; lc[3]++; }
    sel[k] = (unsigned char)m;
  }
#pragma unroll
  for (int e = 0; e < 4; ++e) c[t][e] = lc[e];
  __syncthreads();
  if (t == 0) {
    int run[4] = {0, 0, 0, 0};
    for (int i = 0; i < 256; ++i) {
#pragma unroll
      for (int e = 0; e < 4; ++e) {
        offs[i][e] = run[e];
        run[e] += c[i][e];
      }
    }
    int s = 0;
    segs[0] = 0;
#pragma unroll
    for (int e = 0; e < 4; ++e) {
      s += (run[e] + 255) & ~255;
      segs[e + 1] = s;
    }
#pragma unroll
    for (int e = 0; e < 5; ++e) seg[e] = segs[e];
  }
  __syncthreads();
  int o[4];
#pragma unroll
  for (int e = 0; e < 4; ++e) o[e] = segs[e] + offs[t][e];
#pragma unroll
  for (int k = 0; k < 8; ++k) {
    int tok = t * 8 + k;
    unsigned m = sel[k];
    int sl[2] = {0, 0};
    float sw[2] = {0.f, 0.f};
    int ns = 0;
#pragma unroll
    for (int e = 0; e < 4; ++e) {
      if ((m >> e) & 1) {
        if (ns < 2) { sl[ns] = o[e]; sw[ns] = wv4[k][e]; }
        idx_all[o[e]++] = tok;
        ns++;
      }
    }
    if (ns == 1) { sl[1] = sl[0]; sw[1] = 0.f; }
    slotAB[tok * 2] = sl[0];
    slotAB[tok * 2 + 1] = sl[1];
    wAB[tok * 2] = sw[0];
    wAB[tok * 2 + 1] = sw[1];
  }
}

// ---------------- gemm128: kept for w2 / out-proj / final (epilogue-heavy) ----------------
// EPI: 1 f32 aux0[n]*(v+bias)+aux1 | 4 fp16(+bias) |
//      6 final: aux0[n]*(v + wA*yc[slA]+wB*yc[slB]) + aux1
// MODE: 0 dense | 2 concat-direct: A compact rows, B by seg, bound seg[4]
template <int EPI, int MODE>
__global__ __launch_bounds__(256) void gemm128(
    const unsigned short* __restrict__ A, const unsigned short* __restrict__ B,
    const float* __restrict__ bias, void* __restrict__ Cv,
    const float* __restrict__ aux0, const float* __restrict__ aux1,
    const int* __restrict__ idx, const int* __restrict__ seg,
    const int* __restrict__ slotAB, const float* __restrict__ wAB,
    const unsigned short* __restrict__ yc, int M, int N, int K) {
  __shared__ unsigned short smem[16384];  // 2 bufs x (A 4096 + B 4096)
  const int tid = threadIdx.x;
  const int lane = tid & 63;
  const int wv = tid >> 6;
  const int nwg = gridDim.x;
  const int bid = blockIdx.x;
  const int swzb = (bid & 7) * (nwg >> 3) + (bid >> 3);
  const int gm = M >> 7;
  const int m0 = (swzb % gm) * 128, n0 = (swzb / gm) * 128;
  if (MODE != 0 && m0 >= seg[4]) return;

  const unsigned short* Bp = B;
  if constexpr (MODE != 0) {
    int e = 0;
#pragma unroll
    for (int i = 1; i < 4; ++i)
      if (m0 >= seg[i]) e = i;
    Bp = B + (size_t)e * N * K;
  }

  const int wm = (wv >> 1) * 64, wn = (wv & 1) * 64;
  const int fr = lane & 15, fc = lane >> 4;

  const int rl = lane >> 2, ch = lane & 3;
  const int R1 = wv * 16 + rl;
  const int R2 = 64 + R1;
  const int co1 = ((ch ^ ((R1 >> 1) & 3)) << 3);
  const int co2 = ((ch ^ ((R2 >> 1) & 3)) << 3);
  const size_t ar1 = (size_t)(m0 + R1) * K;
  const size_t ar2 = (size_t)(m0 + R2) * K;
  const unsigned short* gA1 = A + ar1 + co1;
  const unsigned short* gA2 = A + ar2 + co2;
  const unsigned short* gB1 = Bp + (size_t)(n0 + R1) * K + co1;
  const unsigned short* gB2 = Bp + (size_t)(n0 + R2) * K + co2;
  const int lA1 = (wv * 16) * 32, lA2 = (64 + wv * 16) * 32;

  f32x4 acc[4][4];
#pragma unroll
  for (int i = 0; i < 4; ++i) {
#pragma unroll
    for (int j = 0; j < 4; ++j) acc[i][j] = (f32x4)0.f;
  }

  auto STAGE = [&](int buf, int kt) {
    unsigned short* base = smem + buf * 8192;
    gld16(gA1 + kt, base + lA1);
    gld16(gA2 + kt, base + lA2);
    gld16(gB1 + kt, base + 4096 + lA1);
    gld16(gB2 + kt, base + 4096 + lA2);
  };
  auto COMPUTE = [&](int buf) {
    const unsigned short* sA = smem + buf * 8192;
    const unsigned short* sB = sA + 4096;
    f16x8 a[4], b[4];
#pragma unroll
    for (int mi = 0; mi < 4; ++mi) {
      int r = wm + mi * 16 + fr;
      a[mi] = *(const f16x8*)&sA[r * 32 + ((fc ^ ((r >> 1) & 3)) << 3)];
    }
#pragma unroll
    for (int ni = 0; ni < 4; ++ni) {
      int r = wn + ni * 16 + fr;
      b[ni] = *(const f16x8*)&sB[r * 32 + ((fc ^ ((r >> 1) & 3)) << 3)];
    }
#pragma unroll
    for (int mi = 0; mi < 4; ++mi) {
#pragma unroll
      for (int ni = 0; ni < 4; ++ni) acc[mi][ni] = MFMA16(a[mi], b[ni], acc[mi][ni]);
    }
  };

  const int nk = K >> 5;
  STAGE(0, 0);
  __syncthreads();
  int cur = 0;
  for (int t = 1; t < nk; ++t) {
    STAGE(cur ^ 1, t << 5);
    COMPUTE(cur);
    __syncthreads();
    cur ^= 1;
  }
  COMPUTE(cur);

#pragma unroll
  for (int mi = 0; mi < 4; ++mi) {
#pragma unroll
    for (int ni = 0; ni < 4; ++ni) {
      const int n = n0 + wn + ni * 16 + fr;
      const int mb = m0 + wm + mi * 16 + fc * 4;
#pragma unroll
      for (int i = 0; i < 4; ++i) {
        const int m = mb + i;
        float v = acc[mi][ni][i];
        const size_t cidx = (size_t)m * N + n;
        if constexpr (EPI == 1) {
          ((float*)Cv)[cidx] = aux0[n] * (v + bias[n]) + aux1[cidx];
        } else if constexpr (EPI == 4) {
          if (bias) v += bias[n];
          ((unsigned short*)Cv)[cidx] = f2h(v);
        } else if constexpr (EPI == 6) {
          const int sA_ = slotAB[m * 2], sB_ = slotAB[m * 2 + 1];
          const float wA_ = wAB[m * 2], wB_ = wAB[m * 2 + 1];
          float vm = wA_ * h2f(yc[(size_t)sA_ * N + n]) + wB_ * h2f(yc[(size_t)sB_ * N + n]);
          ((float*)Cv)[cidx] = aux0[n] * (v + vm) + aux1[cidx];
        }
      }
    }
  }
}

// ---------------- gemm256: 256x256 tile, 8 waves, BK=32, phase-interleaved ----------------
// LDS 64KB: 2 bufs x (A 256x32 + B 256x32) fp16. Chunk slot = c ^ ((r>>1)&3).
// 4 phases per K-tile: {ds_read A-frag pair (+B frags ph0), issue gld16 (ph0/ph1),
//  sched_barrier, setprio(1), 8 MFMA, setprio(0), sched_barrier}; ONE barrier/K-tile.
// MODE: 0 dense | 1 gather: A rows = idx[m], B selected by 256-aligned seg segment.
// EPI: 4 fp16(+bias) | 5 fused swiglu -> fp16, Nh=N/2
template <int EPI, int MODE>
__global__ __launch_bounds__(512) void gemm256(
    const unsigned short* __restrict__ A, const unsigned short* __restrict__ B,
    const float* __restrict__ bias, void* __restrict__ Cv,
    const int* __restrict__ idx, const int* __restrict__ seg,
    int M, int N, int K) {
  __shared__ unsigned short smem[32768];  // [buf:2][A 8192 | B 8192]
  const int tid = threadIdx.x;
  const int lane = tid & 63;
  const int wv = tid >> 6;           // 0..7
  const int wr = wv >> 2;            // 0..1 (m half)
  const int wc = wv & 3;             // 0..3 (n quarter)
  const int fr = lane & 15, fc = lane >> 4;

  const int nwg = gridDim.x;
  const int bid = blockIdx.x;
  const int swzb = (bid & 7) * (nwg >> 3) + (bid >> 3);
  const int gm = M >> 8;
  const int m0 = (swzb % gm) * 256, n0 = (swzb / gm) * 256;
  if (MODE != 0 && m0 >= seg[4]) return;

  const unsigned short* Bp = B;
  if constexpr (MODE != 0) {
    int e = 0;
#pragma unroll
    for (int i = 1; i < 4; ++i)
      if (m0 >= seg[i]) e = i;
    Bp = B + (size_t)e * N * K;
  }

  // staging: per K-tile 4 gld16/wave: A rows [i*128+wv*16, +16), same for B.
  const int srow = (lane >> 2);            // 0..15 within 16-row group
  const int srcc = ((lane & 3) ^ ((lane >> 3) & 3)) << 3;  // pre-swizzled chunk (shorts)
  int mr0, mr1;
  if constexpr (MODE == 1) {
    mr0 = idx[m0 + wv * 16 + srow];
    mr1 = idx[m0 + 128 + wv * 16 + srow];
  } else {
    mr0 = m0 + wv * 16 + srow;
    mr1 = m0 + 128 + wv * 16 + srow;
  }
  const unsigned short* gA0 = A + (size_t)mr0 * K + srcc;
  const unsigned short* gA1 = A + (size_t)mr1 * K + srcc;
  const unsigned short* gB0 = Bp + (size_t)(n0 + wv * 16 + srow) * K + srcc;
  const unsigned short* gB1 = Bp + (size_t)(n0 + 128 + wv * 16 + srow) * K + srcc;
  const int lw = wv << 9;  // wv*16 rows * 32 shorts

  // fragment read offsets (shorts); frag stride = 16 rows * 32 = 512
  const int sw = (fr >> 1) & 3;
  const int fo = ((fc ^ sw) << 3);
  const int aoff = (wr * 128 + fr) * 32 + fo;
  const int boff = (wc * 64 + fr) * 32 + fo;

  f32x4 acc[8][4];
#pragma unroll
  for (int i = 0; i < 8; ++i) {
#pragma unroll
    for (int j = 0; j < 4; ++j) acc[i][j] = (f32x4)0.f;
  }

  const int nk = K >> 5;
  // prologue: stage K-tile 0 into buf 0
  gld16(gA0, &smem[lw]);
  gld16(gA1, &smem[4096 + lw]);
  gld16(gB0, &smem[8192 + lw]);
  gld16(gB1, &smem[12288 + lw]);
  __syncthreads();

  for (int t = 0; t < nk; ++t) {
    const int cb = (t & 1) * 16384;        // current buffer base
    const int nb = cb ^ 16384;             // next buffer base
    const int kn = (t + 1) << 5;
    const bool more = (t + 1) < nk;
    const unsigned short* sA = smem + cb;
    const unsigned short* sB = smem + cb + 8192;

    // ---- phase 0: B frags + A frags 0,1; stage next A ----
    f16x8 b0 = *(const f16x8*)&sB[boff];
    f16x8 b1 = *(const f16x8*)&sB[boff + 512];
    f16x8 b2 = *(const f16x8*)&sB[boff + 1024];
    f16x8 b3 = *(const f16x8*)&sB[boff + 1536];
    {
      f16x8 a0 = *(const f16x8*)&sA[aoff];
      f16x8 a1 = *(const f16x8*)&sA[aoff + 512];
      if (more) {
        gld16(gA0 + kn, &smem[nb + lw]);
        gld16(gA1 + kn, &smem[nb + 4096 + lw]);
      }
      __builtin_amdgcn_sched_barrier(0);
      __builtin_amdgcn_s_setprio(1);
      acc[0][0] = MFMA16(a0, b0, acc[0][0]);
      acc[0][1] = MFMA16(a0, b1, acc[0][1]);
      acc[0][2] = MFMA16(a0, b2, acc[0][2]);
      acc[0][3] = MFMA16(a0, b3, acc[0][3]);
      acc[1][0] = MFMA16(a1, b0, acc[1][0]);
      acc[1][1] = MFMA16(a1, b1, acc[1][1]);
      acc[1][2] = MFMA16(a1, b2, acc[1][2]);
      acc[1][3] = MFMA16(a1, b3, acc[1][3]);
      __builtin_amdgcn_s_setprio(0);
      __builtin_amdgcn_sched_barrier(0);
    }
    // ---- phase 1: A frags 2,3; stage next B ----
    {
      f16x8 a0 = *(const f16x8*)&sA[aoff + 1024];
      f16x8 a1 = *(const f16x8*)&sA[aoff + 1536];
      if (more) {
        gld16(gB0 + kn, &smem[nb + 8192 + lw]);
        gld16(gB1 + kn, &smem[nb + 12288 + lw]);
      }
      __builtin_amdgcn_sched_barrier(0);
      __builtin_amdgcn_s_setprio(1);
      acc[2][0] = MFMA16(a0, b0, acc[2][0]);
      acc[2][1] = MFMA16(a0, b1, acc[2][1]);
      acc[2][2] = MFMA16(a0, b2, acc[2][2]);
      acc[2][3] = MFMA16(a0, b3, acc[2][3]);
      acc[3][0] = MFMA16(a1, b0, acc[3][0]);
      acc[3][1] = MFMA16(a1, b1, acc[3][1]);
      acc[3][2] = MFMA16(a1, b2, acc[3][2]);
      acc[3][3] = MFMA16(a1, b3, acc[3][3]);
      __builtin_amdgcn_s_setprio(0);
      __builtin_amdgcn_sched_barrier(0);
    }
    // ---- phase 2: A frags 4,5 ----
    {
      f16x8 a0 = *(const f16x8*)&sA[aoff + 2048];
      f16x8 a1 = *(const f16x8*)&sA[aoff + 2560];
      __builtin_amdgcn_sched_barrier(0);
      __builtin_amdgcn_s_setprio(1);
      acc[4][0] = MFMA16(a0, b0, acc[4][0]);
      acc[4][1] = MFMA16(a0, b1, acc[4][1]);
      acc[4][2] = MFMA16(a0, b2, acc[4][2]);
      acc[4][3] = MFMA16(a0, b3, acc[4][3]);
      acc[5][0] = MFMA16(a1, b0, acc[5][0]);
      acc[5][1] = MFMA16(a1, b1, acc[5][1]);
      acc[5][2] = MFMA16(a1, b2, acc[5][2]);
      acc[5][3] = MFMA16(a1, b3, acc[5][3]);
      __builtin_amdgcn_s_setprio(0);
      __builtin_amdgcn_sched_barrier(0);
    }
    // ---- phase 3: A frags 6,7 ----
    {
      f16x8 a0 = *(const f16x8*)&sA[aoff + 3072];
      f16x8 a1 = *(const f16x8*)&sA[aoff + 3584];
      __builtin_amdgcn_sched_barrier(0);
      __builtin_amdgcn_s_setprio(1);
      acc[6][0] = MFMA16(a0, b0, acc[6][0]);
      acc[6][1] = MFMA16(a0, b1, acc[6][1]);
      acc[6][2] = MFMA16(a0, b2, acc[6][2]);
      acc[6][3] = MFMA16(a0, b3, acc[6][3]);
      acc[7][0] = MFMA16(a1, b0, acc[7][0]);
      acc[7][1] = MFMA16(a1, b1, acc[7][1]);
      acc[7][2] = MFMA16(a1, b2, acc[7][2]);
      acc[7][3] = MFMA16(a1, b3, acc[7][3]);
      __builtin_amdgcn_s_setprio(0);
      __builtin_amdgcn_sched_barrier(0);
    }
    __syncthreads();  // drains vmcnt (next tile loaded) + guards buffer reuse
  }

  // epilogue; frag: D[row=fc*4+i][col=fr]
  if constexpr (EPI == 5) {
    unsigned short* Ch = (unsigned short*)Cv;
    const int Nh = N >> 1;
#pragma unroll
    for (int mi = 0; mi < 8; ++mi) {
#pragma unroll
      for (int p = 0; p < 2; ++p) {
        const int hcol = (((n0 + wc * 64) >> 5) + p) * 16 + fr;
        const int mb = m0 + wr * 128 + mi * 16 + fc * 4;
#pragma unroll
        for (int i = 0; i < 4; ++i) {
          const int m = mb + i;
          float v1 = acc[mi][2 * p][i];
          float v3 = acc[mi][2 * p + 1][i];
          float y = v1 / (1.f + __expf(-v1)) * v3;
          Ch[(size_t)m * Nh + hcol] = f2h(y);
        }
      }
    }
  } else {
    unsigned short* Ch = (unsigned short*)Cv;
#pragma unroll
    for (int mi = 0; mi < 8; ++mi) {
#pragma unroll
      for (int ni = 0; ni < 4; ++ni) {
        const int n = n0 + wc * 64 + ni * 16 + fr;
        const int mb = m0 + wr * 128 + mi * 16 + fc * 4;
#pragma unroll
        for (int i = 0; i < 4; ++i) {
          const int m = mb + i;
          float v = acc[mi][ni][i];
          if (bias) v += bias[n];
          Ch[(size_t)m * N + n] = f2h(v);
        }
      }
    }
  }
}

// ---------------- host ----------------

extern "C" void kernel_launch(void* const* d_in, const int* in_sizes, int n_in,
                              void* d_out, int out_size, void* d_ws, size_t ws_size,
                              hipStream_t stream) {
  (void)in_sizes; (void)n_in; (void)out_size; (void)ws_size;
  const float* hs = (const float*)d_in[0];
  const float* temb = (const float*)d_in[1];
  const float* rope = (const float*)d_in[2];
  const float* adaw = (const float*)d_in[3];
  const float* adab = (const float*)d_in[4];
  const float* qkvw = (const float*)d_in[5];
  const float* qkvb = (const float*)d_in[6];
  const float* qnw = (const float*)d_in[7];
  const float* knw = (const float*)d_in[8];
  const float* outw = (const float*)d_in[9];
  const float* outb = (const float*)d_in[10];
  const float* gatew = (const float*)d_in[11];
  const float* ew1 = (const float*)d_in[12];
  const float* ew2 = (const float*)d_in[13];
  const float* ew3 = (const float*)d_in[14];
  const float* sw1 = (const float*)d_in[15];
  const float* sw2 = (const float*)d_in[16];
  const float* sw3 = (const float*)d_in[17];
  float* out = (float*)d_out;
  char* ws = (char*)d_ws;

  size_t off = 0;
  auto give = [&](size_t nbytes) {
    size_t r = off;
    off += (nbytes + 255) & ~(size_t)255;
    return r;
  };
  const size_t T = T_TOK, D = DIM;
  size_t o_mod = give(15360 * 4);
  size_t o_ss = give(D * 4);
  size_t o_wd = give(T * 4 * 4);
  size_t o_idx = give(MPAD * 4);
  size_t o_seg = give(8 * 4);
  size_t o_slot = give(T * 2 * 4);
  size_t o_wab = give(T * 2 * 4);
  size_t o_nh = give(T * D * 2);      // nh fp16; later nh2
  size_t o_qkvh = give(T * 7680 * 2); // qkv fp16; region later reused as hmid
  size_t o_qh = give(T * D * 2);
  size_t o_kh = give(T * D * 2);
  size_t o_vt = give(T * D * 2);
  size_t o_obf = give(T * D * 2);
  size_t o_h2 = give(T * D * 4);
  size_t o_yc = give((size_t)MPAD * D * 2);       // compact expert outputs fp16
  size_t o_hmid2 = give(T * SHID_E * 2);          // shared-expert mid
  // fp16 weights
  size_t o_qkvw = give((size_t)7680 * 2560 * 2);
  size_t o_outw = give((size_t)2560 * 2560 * 2);
  size_t o_ewA = give((size_t)4 * 2 * HID_E * 2560 * 2);  // interleaved w1/w3
  size_t o_ew2 = give((size_t)4 * 2560 * HID_E * 2);
  size_t o_swA = give((size_t)2 * SHID_E * 2560 * 2);     // interleaved sw1/sw3
  size_t o_sw2 = give((size_t)2560 * SHID_E * 2);

  float* mod = (float*)(ws + o_mod);
  float* ss = (float*)(ws + o_ss);
  float* wd = (float*)(ws + o_wd);
  int* idxb = (int*)(ws + o_idx);
  int* segp = (int*)(ws + o_seg);
  int* slotAB = (int*)(ws + o_slot);
  float* wAB = (float*)(ws + o_wab);
  unsigned short* nh_h = (unsigned short*)(ws + o_nh);
  unsigned short* qkvh = (unsigned short*)(ws + o_qkvh);
  unsigned short* qh = (unsigned short*)(ws + o_qh);
  unsigned short* kh = (unsigned short*)(ws + o_kh);
  unsigned short* vt = (unsigned short*)(ws + o_vt);
  unsigned short* obf = (unsigned short*)(ws + o_obf);
  float* h2 = (float*)(ws + o_h2);
  unsigned short* yc = (unsigned short*)(ws + o_yc);
  unsigned short* hmid2 = (unsigned short*)(ws + o_hmid2);
  unsigned short* qkvw_h = (unsigned short*)(ws + o_qkvw);
  unsigned short* outw_h = (unsigned short*)(ws + o_outw);
  unsigned short* ewA_h = (unsigned short*)(ws + o_ewA);
  unsigned short* ew2_h = (unsigned short*)(ws + o_ew2);
  unsigned short* swA_h = (unsigned short*)(ws + o_swA);
  unsigned short* sw2_h = (unsigned short*)(ws + o_sw2);
  unsigned short* nh2 = nh_h;
  // hmid (MPAD x 6912 fp16 = 70.8 MB) aliases qkvh..obf (73.4 MB), dead after out-proj
  unsigned short* hmid = qkvh;

  // 0) weight conversion f32 -> fp16 (+ w1/w3 interleave for fused swiglu)
  cvt_f16<<<2048, 256, 0, stream>>>(qkvw, qkvw_h, 7680 * 2560 / 8);
  cvt_f16<<<2048, 256, 0, stream>>>(outw, outw_h, 2560 * 2560 / 8);
  cvt_f16<<<2048, 256, 0, stream>>>(ew2, ew2_h, 4 * 2560 * HID_E / 8);
  cvt_f16<<<2048, 256, 0, stream>>>(sw2, sw2_h, 2560 * SHID_E / 8);
  for (int e = 0; e < 4; ++e) {
    cvt_pair<<<2 * HID_E, 256, 0, stream>>>(ew1 + (size_t)e * HID_E * DIM,
                                            ew3 + (size_t)e * HID_E * DIM,
                                            ewA_h + (size_t)e * 2 * HID_E * DIM);
  }
  cvt_pair<<<2 * SHID_E, 256, 0, stream>>>(sw1, sw3, swA_h);
  // 1) adaLN modulation
  silu_k<<<10, 256, 0, stream>>>(temb, ss);
  adaln_gemv<<<3840, 256, 0, stream>>>(ss, adaw, adab, mod);
  // 2) LN1 + modulate (fp16)
  ln_mod<<<T, 256, 0, stream>>>(hs, mod, mod + D, nh_h);
  // 3) qkv GEMM -> fp16 (256-tile)
  gemm256<4, 0><<<240, 512, 0, stream>>>(nh_h, qkvw_h, qkvb, qkvh,
                                         nullptr, nullptr, 2048, 7680, 2560);
  // 4) RMSNorm + RoPE
  rmsrope<<<T, 256, 0, stream>>>(qkvh, qnw, knw, rope, qh, kh);
  // 5) V transpose
  transpose_v<<<dim3(80, 64), dim3(32, 8), 0, stream>>>(qkvh, vt);
  // 6) MFMA flash attention
  fattn<<<dim3(32, 20), 256, 0, stream>>>(qh, kh, vt, obf);
  // 7) out proj + gate_msa residual -> h2 f32
  gemm128<1, 0><<<16 * 20, 256, 0, stream>>>(obf, outw_h, outb, h2,
                                             mod + 2 * D, hs, nullptr, nullptr,
                                             nullptr, nullptr, nullptr, 2048, 2560, 2560);
  // 8) LN2 + modulate + routing, then concatenated 256-padded compaction
  ln2_route<<<T, 256, 0, stream>>>(h2, mod + 3 * D, mod + 4 * D, gatew, nh2, wd);
  route_compact<<<1, 256, 0, stream>>>(wd, idxb, segp, slotAB, wAB);
  // 9) MoE experts: ONE fused w1w3+swiglu 256-tile GEMM + ONE w2 GEMM
  gemm256<5, 1><<<20 * 54, 512, 0, stream>>>(nh2, ewA_h, nullptr, hmid,
                                             idxb, segp, MPAD, 2 * HID_E, 2560);
  gemm128<4, 2><<<40 * 20, 256, 0, stream>>>(hmid, ew2_h, nullptr, yc,
                                             nullptr, nullptr, nullptr, segp,
                                             nullptr, nullptr, nullptr,
                                             MPAD, 2560, 6912);
  // 10) shared expert (256-tile fused w1w3+swiglu) + final combine w/ yc gather
  gemm256<5, 0><<<8 * 28, 512, 0, stream>>>(nh2, swA_h, nullptr, hmid2,
                                            nullptr, nullptr, 2048, 2 * SHID_E, 2560);
  gemm128<6, 0><<<16 * 20, 256, 0, stream>>>(hmid2, sw2_h, nullptr, out,
                                             mod + 5 * D, h2, nullptr, nullptr,
                                             slotAB, wAB, yc, 2048, 2560, 3584);
}

// Round 8
// 1423.233 us; speedup vs baseline: 3.7229x; 1.0450x over previous
//
#include <hip/hip_runtime.h>

#define DIM 2560
#define T_TOK 2048
#define NHEADS 20
#define HD 128
#define HID_E 6912
#define SHID_E 3584
#define MPAD 5120  // concat rows, segments padded to 256 (max 4096+4*255 <= 5120)

typedef _Float16 f16x8 __attribute__((ext_vector_type(8)));
typedef float f32x4 __attribute__((ext_vector_type(4)));
typedef unsigned short u16x8 __attribute__((ext_vector_type(8)));

#define MFMA16(a, b, c) __builtin_amdgcn_mfma_f32_16x16x32_f16((a), (b), (c), 0, 0, 0)

__device__ inline unsigned short f2h(float f) {
  return __builtin_bit_cast(unsigned short, (_Float16)f);
}
__device__ inline float h2f(unsigned short u) {
  return (float)__builtin_bit_cast(_Float16, u);
}
__device__ inline float wave_sum(float v) {
#pragma unroll
  for (int off = 32; off > 0; off >>= 1) v += __shfl_down(v, off, 64);
  return v;
}
// async global->LDS, 16B per lane; LDS dest = wave-uniform base + lane*16
__device__ inline void gld16(const void* g, void* l) {
  __builtin_amdgcn_global_load_lds((const __attribute__((address_space(1))) void*)g,
                                   (__attribute__((address_space(3))) void*)l, 16, 0, 0);
}

// ---------------- tiny kernels ----------------

__global__ __launch_bounds__(256) void silu_k(const float* __restrict__ t,
                                              float* __restrict__ ss) {
  int i = blockIdx.x * 256 + threadIdx.x;
  if (i < DIM) {
    float v = t[i];
    ss[i] = v / (1.f + expf(-v));
  }
}

__global__ __launch_bounds__(256) void cvt_f16(const float* __restrict__ in,
                                               unsigned short* __restrict__ outp, int n8) {
  const int stride = gridDim.x * 256;
  for (int i = blockIdx.x * 256 + threadIdx.x; i < n8; i += stride) {
    float4 a = *(const float4*)(in + (size_t)i * 8);
    float4 b = *(const float4*)(in + (size_t)i * 8 + 4);
    u16x8 u;
    u[0] = f2h(a.x); u[1] = f2h(a.y); u[2] = f2h(a.z); u[3] = f2h(a.w);
    u[4] = f2h(b.x); u[5] = f2h(b.y); u[6] = f2h(b.z); u[7] = f2h(b.w);
    *(u16x8*)&outp[(size_t)i * 8] = u;
  }
}

// interleave w1/w3 rows into B' : row j -> (j&31)<16 ? w1[(j>>5)*16+(j&15)]
//                                          : w3[(j>>5)*16+(j&15)]
__global__ __launch_bounds__(256) void cvt_pair(const float* __restrict__ w1,
                                                const float* __restrict__ w3,
                                                unsigned short* __restrict__ outp) {
  const int j = blockIdx.x;
  const int g = j >> 5, r = j & 31;
  const float* src = (r < 16) ? (w1 + (size_t)(g * 16 + r) * DIM)
                              : (w3 + (size_t)(g * 16 + (r & 15)) * DIM);
  unsigned short* dst = outp + (size_t)j * DIM;
  for (int i = threadIdx.x; i < 320; i += 256) {
    float4 a = *(const float4*)(src + i * 8);
    float4 b = *(const float4*)(src + i * 8 + 4);
    u16x8 u;
    u[0] = f2h(a.x); u[1] = f2h(a.y); u[2] = f2h(a.z); u[3] = f2h(a.w);
    u[4] = f2h(b.x); u[5] = f2h(b.y); u[6] = f2h(b.z); u[7] = f2h(b.w);
    *(u16x8*)&dst[i * 8] = u;
  }
}

// mod[j] = dot(silu(temb), adaln_w[j]) + adaln_b[j]; one wave per output
__global__ __launch_bounds__(256) void adaln_gemv(const float* __restrict__ ss,
                                                  const float* __restrict__ W,
                                                  const float* __restrict__ bias,
                                                  float* __restrict__ mod) {
  const int lane = threadIdx.x & 63;
  const int j = blockIdx.x * 4 + (threadIdx.x >> 6);
  const float* wr = W + (size_t)j * DIM;
  float p = 0.f;
  for (int i = lane; i < 640; i += 64) {
    float4 w = *(const float4*)(wr + i * 4);
    float4 x = *(const float4*)(ss + i * 4);
    p += w.x * x.x + w.y * x.y + w.z * x.z + w.w * x.w;
  }
  p = wave_sum(p);
  if (lane == 0) mod[j] = p + bias[j];
}

// LN (no affine) then *(1+scale)+shift, write fp16. One block per row.
__global__ __launch_bounds__(256) void ln_mod(const float* __restrict__ x,
                                              const float* __restrict__ shift,
                                              const float* __restrict__ scale,
                                              unsigned short* __restrict__ outp) {
  __shared__ float rbuf[8];
  const int t = blockIdx.x, tid = threadIdx.x, lane = tid & 63, wid = tid >> 6;
  const float* xr = x + (size_t)t * DIM;
  float s = 0.f, sq = 0.f;
  for (int i = tid; i < 640; i += 256) {
    float4 v = *(const float4*)(xr + i * 4);
    s += v.x + v.y + v.z + v.w;
    sq += v.x * v.x + v.y * v.y + v.z * v.z + v.w * v.w;
  }
  s = wave_sum(s);
  sq = wave_sum(sq);
  if (lane == 0) {
    rbuf[wid] = s;
    rbuf[4 + wid] = sq;
  }
  __syncthreads();
  float S = rbuf[0] + rbuf[1] + rbuf[2] + rbuf[3];
  float SQ = rbuf[4] + rbuf[5] + rbuf[6] + rbuf[7];
  float mean = S * (1.f / DIM);
  float rs = rsqrtf(SQ * (1.f / DIM) - mean * mean + 1e-6f);
  for (int i = tid; i < 640; i += 256) {
    float4 v = *(const float4*)(xr + i * 4);
    float4 sc4 = *(const float4*)(scale + i * 4);
    float4 sh4 = *(const float4*)(shift + i * 4);
    ushort4 u;
    u.x = f2h((v.x - mean) * rs * (1.f + sc4.x) + sh4.x);
    u.y = f2h((v.y - mean) * rs * (1.f + sc4.y) + sh4.y);
    u.z = f2h((v.z - mean) * rs * (1.f + sc4.z) + sh4.z);
    u.w = f2h((v.w - mean) * rs * (1.f + sc4.w) + sh4.w);
    *(ushort4*)&outp[(size_t)t * DIM + i * 4] = u;
  }
}

// RMSNorm(q),(k) over full 2560 + weight + RoPE -> qh (scaled by 1/sqrt(128)), kh
__global__ __launch_bounds__(256) void rmsrope(const unsigned short* __restrict__ qkv,
                                               const float* __restrict__ qn,
                                               const float* __restrict__ kn,
                                               const float* __restrict__ rope,
                                               unsigned short* __restrict__ qh,
                                               unsigned short* __restrict__ kh) {
  __shared__ float rbuf[8];
  const int t = blockIdx.x, tid = threadIdx.x, lane = tid & 63, wid = tid >> 6;
  const unsigned short* row = qkv + (size_t)t * 7680;
  float sq = 0.f, sk = 0.f;
  for (int i = tid; i < 320; i += 256) {
    f16x8 qv = *(const f16x8*)(row + i * 8);
    f16x8 kv = *(const f16x8*)(row + DIM + i * 8);
#pragma unroll
    for (int j = 0; j < 8; ++j) {
      float q = (float)qv[j], k = (float)kv[j];
      sq += q * q;
      sk += k * k;
    }
  }
  sq = wave_sum(sq);
  sk = wave_sum(sk);
  if (lane == 0) {
    rbuf[wid] = sq;
    rbuf[4 + wid] = sk;
  }
  __syncthreads();
  float SQ = rbuf[0] + rbuf[1] + rbuf[2] + rbuf[3];
  float SK = rbuf[4] + rbuf[5] + rbuf[6] + rbuf[7];
  float rq = rsqrtf(SQ * (1.f / DIM) + 1e-6f) * 0.08838834764831845f;
  float rk = rsqrtf(SK * (1.f / DIM) + 1e-6f);
  for (int pp = tid; pp < 1280; pp += 256) {
    int c = pp * 2;
    float qe = h2f(row[c]) * rq * qn[c], qo = h2f(row[c + 1]) * rq * qn[c + 1];
    float ke = h2f(row[DIM + c]) * rk * kn[c], ko = h2f(row[DIM + c + 1]) * rk * kn[c + 1];
    float4 rr = *(const float4*)(rope + (size_t)t * 256 + (pp & 63) * 4);
    unsigned qp = (unsigned)f2h(rr.x * qe + rr.y * qo) |
                  ((unsigned)f2h(rr.z * qe + rr.w * qo) << 16);
    unsigned kp = (unsigned)f2h(rr.x * ke + rr.y * ko) |
                  ((unsigned)f2h(rr.z * ke + rr.w * ko) << 16);
    *(unsigned*)&qh[(size_t)t * DIM + c] = qp;
    *(unsigned*)&kh[(size_t)t * DIM + c] = kp;
  }
}

// V part of qkv (fp16 [2048][7680] at col 5120) -> vt fp16 [2560][2048]
__global__ void transpose_v(const unsigned short* __restrict__ in,
                            unsigned short* __restrict__ outp) {
  __shared__ unsigned short tile[32][33];
  const int bx = blockIdx.x * 32;  // channel
  const int by = blockIdx.y * 32;  // token
  const int tx = threadIdx.x, ty = threadIdx.y;
  for (int j = ty; j < 32; j += 8)
    tile[j][tx] = in[(size_t)(by + j) * 7680 + 5120 + bx + tx];
  __syncthreads();
  for (int j = ty; j < 32; j += 8)
    outp[(size_t)(bx + j) * T_TOK + by + tx] = tile[tx][j];
}

// ---------------- MFMA flash attention ----------------
__global__ __launch_bounds__(256) void fattn(const unsigned short* __restrict__ qh,
                                             const unsigned short* __restrict__ kh,
                                             const unsigned short* __restrict__ vt,
                                             unsigned short* __restrict__ obuf) {
  __shared__ unsigned short sK[64 * 128];  // [k][d], slot = c ^ (r&15)
  __shared__ unsigned short sV[128 * 64];  // [d][k], slot = c ^ (r&7)
  __shared__ unsigned short sP[64 * 64];   // [q][k], slot = c ^ (r&7)
  __shared__ float sRedM[4][64];
  __shared__ float sRedL[4][64];
  __shared__ float sM[64];
  __shared__ float sL[64];
  const int tid = threadIdx.x, lane = tid & 63, wv = tid >> 6;
  const int g = lane >> 4, fr = lane & 15;
  const int h = blockIdx.y;
  const int q0 = blockIdx.x * 64;

  {
    const int r = tid >> 2, qt = tid & 3;
    const unsigned short* gp = qh + (size_t)(q0 + r) * DIM + h * HD + qt * 32;
    uint4 v0 = ((const uint4*)gp)[0];
    uint4 v1 = ((const uint4*)gp)[1];
    uint4 v2 = ((const uint4*)gp)[2];
    uint4 v3 = ((const uint4*)gp)[3];
    unsigned short* dst = &sK[r * 128];
    const int cb = qt * 4, rs = r & 15;
    *(uint4*)&dst[((cb + 0) ^ rs) * 8] = v0;
    *(uint4*)&dst[((cb + 1) ^ rs) * 8] = v1;
    *(uint4*)&dst[((cb + 2) ^ rs) * 8] = v2;
    *(uint4*)&dst[((cb + 3) ^ rs) * 8] = v3;
  }
  __syncthreads();
  f16x8 qfrag[4][4];
#pragma unroll
  for (int ni = 0; ni < 4; ++ni) {
#pragma unroll
    for (int kt = 0; kt < 4; ++kt) {
      int r = ni * 16 + fr;
      qfrag[ni][kt] = *(const f16x8*)&sK[r * 128 + (((kt * 4 + g) ^ (r & 15)) << 3)];
    }
  }
  __syncthreads();

  f32x4 acco[4][2];
  f32x4 mprev[4];
  float mrun[4], lrun[4];
#pragma unroll
  for (int i = 0; i < 4; ++i) {
    acco[i][0] = (f32x4)0.f;
    acco[i][1] = (f32x4)0.f;
    mprev[i] = (f32x4)(-1e30f);
    mrun[i] = -1e30f;
    lrun[i] = 0.f;
  }

  for (int kt0 = 0; kt0 < T_TOK; kt0 += 64) {
    {
      const int r = tid >> 2, qt = tid & 3;
      const unsigned short* gp = kh + (size_t)(kt0 + r) * DIM + h * HD + qt * 32;
      uint4 v0 = ((const uint4*)gp)[0];
      uint4 v1 = ((const uint4*)gp)[1];
      uint4 v2 = ((const uint4*)gp)[2];
      uint4 v3 = ((const uint4*)gp)[3];
      unsigned short* dst = &sK[r * 128];
      const int cb = qt * 4, rs = r & 15;
      *(uint4*)&dst[((cb + 0) ^ rs) * 8] = v0;
      *(uint4*)&dst[((cb + 1) ^ rs) * 8] = v1;
      *(uint4*)&dst[((cb + 2) ^ rs) * 8] = v2;
      *(uint4*)&dst[((cb + 3) ^ rs) * 8] = v3;
      const int rv = tid >> 1, hf = tid & 1;
      const unsigned short* gv = vt + (size_t)(h * HD + rv) * T_TOK + kt0 + hf * 32;
      uint4 w0 = ((const uint4*)gv)[0];
      uint4 w1 = ((const uint4*)gv)[1];
      uint4 w2 = ((const uint4*)gv)[2];
      uint4 w3 = ((const uint4*)gv)[3];
      unsigned short* dv = &sV[rv * 64];
      const int cv = hf * 4, rvs = rv & 7;
      *(uint4*)&dv[((cv + 0) ^ rvs) * 8] = w0;
      *(uint4*)&dv[((cv + 1) ^ rvs) * 8] = w1;
      *(uint4*)&dv[((cv + 2) ^ rvs) * 8] = w2;
      *(uint4*)&dv[((cv + 3) ^ rvs) * 8] = w3;
    }
    __syncthreads();  // B0

    f32x4 accs[4] = {(f32x4)0.f, (f32x4)0.f, (f32x4)0.f, (f32x4)0.f};
#pragma unroll
    for (int kt = 0; kt < 4; ++kt) {
      int r = wv * 16 + fr;
      f16x8 ak = *(const f16x8*)&sK[r * 128 + (((kt * 4 + g) ^ (r & 15)) << 3)];
#pragma unroll
      for (int ni = 0; ni < 4; ++ni) accs[ni] = MFMA16(ak, qfrag[ni][kt], accs[ni]);
    }

    float pm[4];
#pragma unroll
    for (int ni = 0; ni < 4; ++ni) {
      float m = fmaxf(fmaxf(accs[ni][0], accs[ni][1]), fmaxf(accs[ni][2], accs[ni][3]));
      m = fmaxf(m, __shfl_xor(m, 16));
      m = fmaxf(m, __shfl_xor(m, 32));
      pm[ni] = m;
    }
    if (g == 0) {
#pragma unroll
      for (int ni = 0; ni < 4; ++ni) sRedM[wv][ni * 16 + fr] = pm[ni];
    }
    __syncthreads();  // B1
    float mnew[4];
#pragma unroll
    for (int ni = 0; ni < 4; ++ni) {
      int q = ni * 16 + fr;
      float mt = fmaxf(fmaxf(sRedM[0][q], sRedM[1][q]), fmaxf(sRedM[2][q], sRedM[3][q]));
      mnew[ni] = fmaxf(mrun[ni], mt);
    }
    float lsum[4];
#pragma unroll
    for (int ni = 0; ni < 4; ++ni) {
      float l0 = 0.f;
#pragma unroll
      for (int i = 0; i < 4; ++i) {
        float p = __expf(accs[ni][i] - mnew[ni]);
        accs[ni][i] = p;
        l0 += p;
      }
      l0 += __shfl_xor(l0, 16);
      l0 += __shfl_xor(l0, 32);
      lsum[ni] = l0;
    }
    if (g == 0) {
#pragma unroll
      for (int ni = 0; ni < 4; ++ni) sRedL[wv][ni * 16 + fr] = lsum[ni];
      if (wv == 0) {
#pragma unroll
        for (int ni = 0; ni < 4; ++ni) sM[ni * 16 + fr] = mnew[ni];
      }
    }
#pragma unroll
    for (int ni = 0; ni < 4; ++ni) {
      int q = ni * 16 + fr;
      unsigned p01 = (unsigned)f2h(accs[ni][0]) | ((unsigned)f2h(accs[ni][1]) << 16);
      unsigned p23 = (unsigned)f2h(accs[ni][2]) | ((unsigned)f2h(accs[ni][3]) << 16);
      uint2 pk;
      pk.x = p01;
      pk.y = p23;
      *(uint2*)&sP[q * 64 + ((((wv << 1) | (g >> 1)) ^ (q & 7)) << 3) + ((g & 1) << 2)] = pk;
    }
    __syncthreads();  // B2
#pragma unroll
    for (int ni = 0; ni < 4; ++ni) {
      int q = ni * 16 + fr;
      float lt = sRedL[0][q] + sRedL[1][q] + sRedL[2][q] + sRedL[3][q];
      lrun[ni] = lrun[ni] * __expf(mrun[ni] - mnew[ni]) + lt;
      mrun[ni] = mnew[ni];
    }

#pragma unroll
    for (int mi = 0; mi < 4; ++mi) {
      f32x4 mn = *(const f32x4*)&sM[mi * 16 + g * 4];
      f32x4 sc;
#pragma unroll
      for (int i = 0; i < 4; ++i) sc[i] = __expf(mprev[mi][i] - mn[i]);
      acco[mi][0] *= sc;
      acco[mi][1] *= sc;
      mprev[mi] = mn;
    }
#pragma unroll
    for (int ktp = 0; ktp < 2; ++ktp) {
      f16x8 bv[2];
#pragma unroll
      for (int nd = 0; nd < 2; ++nd) {
        int r = wv * 32 + nd * 16 + fr;
        bv[nd] = *(const f16x8*)&sV[r * 64 + (((ktp * 4 + g) ^ (r & 7)) << 3)];
      }
#pragma unroll
      for (int mi = 0; mi < 4; ++mi) {
        int r = mi * 16 + fr;
        f16x8 ap = *(const f16x8*)&sP[r * 64 + (((ktp * 4 + g) ^ (r & 7)) << 3)];
        acco[mi][0] = MFMA16(ap, bv[0], acco[mi][0]);
        acco[mi][1] = MFMA16(ap, bv[1], acco[mi][1]);
      }
    }
    __syncthreads();  // B3
  }

  if (wv == 0 && g == 0) {
#pragma unroll
    for (int ni = 0; ni < 4; ++ni) sL[ni * 16 + fr] = 1.f / lrun[ni];
  }
  __syncthreads();
#pragma unroll
  for (int mi = 0; mi < 4; ++mi) {
    f32x4 li = *(const f32x4*)&sL[mi * 16 + g * 4];
#pragma unroll
    for (int nd = 0; nd < 2; ++nd) {
#pragma unroll
      for (int i = 0; i < 4; ++i) {
        float o = acco[mi][nd][i] * li[i];
        obuf[(size_t)(q0 + mi * 16 + g * 4 + i) * DIM + h * HD + wv * 32 + nd * 16 + fr] =
            f2h(o);
      }
    }
  }
}

// LN2 + modulate -> nh2 fp16, plus f32 routing (softmax over 4, top-2, unnormalized)
__global__ __launch_bounds__(256) void ln2_route(const float* __restrict__ x,
                                                 const float* __restrict__ shift,
                                                 const float* __restrict__ scale,
                                                 const float* __restrict__ gw,
                                                 unsigned short* __restrict__ nh2,
                                                 float* __restrict__ wd) {
  __shared__ float rbuf[8];
  __shared__ float gbuf[4][4];
  const int t = blockIdx.x, tid = threadIdx.x, lane = tid & 63, wid = tid >> 6;
  const float* xr = x + (size_t)t * DIM;
  float s = 0.f, sq = 0.f;
  for (int i = tid; i < 640; i += 256) {
    float4 v = *(const float4*)(xr + i * 4);
    s += v.x + v.y + v.z + v.w;
    sq += v.x * v.x + v.y * v.y + v.z * v.z + v.w * v.w;
  }
  s = wave_sum(s);
  sq = wave_sum(sq);
  if (lane == 0) {
    rbuf[wid] = s;
    rbuf[4 + wid] = sq;
  }
  __syncthreads();
  float S = rbuf[0] + rbuf[1] + rbuf[2] + rbuf[3];
  float SQ = rbuf[4] + rbuf[5] + rbuf[6] + rbuf[7];
  float mean = S * (1.f / DIM);
  float rs = rsqrtf(SQ * (1.f / DIM) - mean * mean + 1e-6f);
  float g0 = 0.f, g1 = 0.f, g2 = 0.f, g3 = 0.f;
  for (int i = tid; i < 640; i += 256) {
    float4 v = *(const float4*)(xr + i * 4);
    float4 sc4 = *(const float4*)(scale + i * 4);
    float4 sh4 = *(const float4*)(shift + i * 4);
    float y0 = (v.x - mean) * rs * (1.f + sc4.x) + sh4.x;
    float y1 = (v.y - mean) * rs * (1.f + sc4.y) + sh4.y;
    float y2 = (v.z - mean) * rs * (1.f + sc4.z) + sh4.z;
    float y3 = (v.w - mean) * rs * (1.f + sc4.w) + sh4.w;
    ushort4 u;
    u.x = f2h(y0); u.y = f2h(y1); u.z = f2h(y2); u.w = f2h(y3);
    *(ushort4*)&nh2[(size_t)t * DIM + i * 4] = u;
    float4 w0 = *(const float4*)(gw + i * 4);
    float4 w1 = *(const float4*)(gw + DIM + i * 4);
    float4 w2 = *(const float4*)(gw + 2 * DIM + i * 4);
    float4 w3 = *(const float4*)(gw + 3 * DIM + i * 4);
    g0 += y0 * w0.x + y1 * w0.y + y2 * w0.z + y3 * w0.w;
    g1 += y0 * w1.x + y1 * w1.y + y2 * w1.z + y3 * w1.w;
    g2 += y0 * w2.x + y1 * w2.y + y2 * w2.z + y3 * w2.w;
    g3 += y0 * w3.x + y1 * w3.y + y2 * w3.z + y3 * w3.w;
  }
  g0 = wave_sum(g0);
  g1 = wave_sum(g1);
  g2 = wave_sum(g2);
  g3 = wave_sum(g3);
  if (lane == 0) {
    gbuf[wid][0] = g0; gbuf[wid][1] = g1; gbuf[wid][2] = g2; gbuf[wid][3] = g3;
  }
  __syncthreads();
  if (tid == 0) {
    float l[4];
#pragma unroll
    for (int e = 0; e < 4; ++e) l[e] = gbuf[0][e] + gbuf[1][e] + gbuf[2][e] + gbuf[3][e];
    float mx = fmaxf(fmaxf(l[0], l[1]), fmaxf(l[2], l[3]));
    float ex[4], sum = 0.f;
#pragma unroll
    for (int e = 0; e < 4; ++e) { ex[e] = expf(l[e] - mx); sum += ex[e]; }
    float p[4];
#pragma unroll
    for (int e = 0; e < 4; ++e) p[e] = ex[e] / sum;
    int i1 = 0;
    for (int e = 1; e < 4; ++e)
      if (p[e] > p[i1]) i1 = e;
    int i2 = -1;
    for (int e = 0; e < 4; ++e) {
      if (e == i1) continue;
      if (i2 < 0 || p[e] > p[i2]) i2 = e;
    }
    float w[4] = {0.f, 0.f, 0.f, 0.f};
    w[i1] = p[i1];
    w[i2] = p[i2];
    *(float4*)&wd[(size_t)t * 4] = make_float4(w[0], w[1], w[2], w[3]);
  }
}

// Concatenated padded top-2 compaction. One block, 256 threads, 8 tokens each.
// Segments padded to 256 (for the 256-tile GEMM). idx pad rows point at token 0.
__global__ __launch_bounds__(256) void route_compact(const float* __restrict__ wd,
                                                     int* __restrict__ idx_all,
                                                     int* __restrict__ seg,
                                                     int* __restrict__ slotAB,
                                                     float* __restrict__ wAB) {
  __shared__ unsigned short c[256][4];
  __shared__ int offs[256][4];
  __shared__ int segs[5];
  const int t = threadIdx.x;
  for (int i = t; i < MPAD; i += 256) idx_all[i] = 0;
  unsigned char sel[8];
  float wv4[8][4];
  unsigned short lc[4] = {0, 0, 0, 0};
#pragma unroll
  for (int k = 0; k < 8; ++k) {
    int tok = t * 8 + k;
    float4 w = *(const float4*)&wd[(size_t)tok * 4];
    wv4[k][0] = w.x; wv4[k][1] = w.y; wv4[k][2] = w.z; wv4[k][3] = w.w;
    unsigned m = 0;
    if (w.x != 0.f) { m |= 1; lc[0]++; }
    if (w.y != 0.f) { m |= 2; lc[1]++; }
    if (w.z != 0.f) { m |= 4; lc[2]++; }
    if (w.w != 0.f) { m |= 8; lc[3]++; }
    sel[k] = (unsigned char)m;
  }
#pragma unroll
  for (int e = 0; e < 4; ++e) c[t][e] = lc[e];
  __syncthreads();
  if (t == 0) {
    int run[4] = {0, 0, 0, 0};
    for (int i = 0; i < 256; ++i) {
#pragma unroll
      for (int e = 0; e < 4; ++e) {
        offs[i][e] = run[e];
        run[e] += c[i][e];
      }
    }
    int s = 0;
    segs[0] = 0;
#pragma unroll
    for (int e = 0; e < 4; ++e) {
      s += (run[e] + 255) & ~255;
      segs[e + 1] = s;
    }
#pragma unroll
    for (int e = 0; e < 5; ++e) seg[e] = segs[e];
  }
  __syncthreads();
  int o[4];
#pragma unroll
  for (int e = 0; e < 4; ++e) o[e] = segs[e] + offs[t][e];
#pragma unroll
  for (int k = 0; k < 8; ++k) {
    int tok = t * 8 + k;
    unsigned m = sel[k];
    int sl[2] = {0, 0};
    float sw[2] = {0.f, 0.f};
    int ns = 0;
#pragma unroll
    for (int e = 0; e < 4; ++e) {
      if ((m >> e) & 1) {
        if (ns < 2) { sl[ns] = o[e]; sw[ns] = wv4[k][e]; }
        idx_all[o[e]++] = tok;
        ns++;
      }
    }
    if (ns == 1) { sl[1] = sl[0]; sw[1] = 0.f; }
    slotAB[tok * 2] = sl[0];
    slotAB[tok * 2 + 1] = sl[1];
    wAB[tok * 2] = sw[0];
    wAB[tok * 2 + 1] = sw[1];
  }
}

// ---------------- gemm128: kept for w2 / out-proj / final (epilogue-heavy) ----------------
// EPI: 1 f32 aux0[n]*(v+bias)+aux1 | 4 fp16(+bias) |
//      6 final: aux0[n]*(v + wA*yc[slA]+wB*yc[slB]) + aux1
// MODE: 0 dense | 2 concat-direct: A compact rows, B by seg, bound seg[4]
template <int EPI, int MODE>
__global__ __launch_bounds__(256) void gemm128(
    const unsigned short* __restrict__ A, const unsigned short* __restrict__ B,
    const float* __restrict__ bias, void* __restrict__ Cv,
    const float* __restrict__ aux0, const float* __restrict__ aux1,
    const int* __restrict__ idx, const int* __restrict__ seg,
    const int* __restrict__ slotAB, const float* __restrict__ wAB,
    const unsigned short* __restrict__ yc, int M, int N, int K) {
  __shared__ unsigned short smem[16384];  // 2 bufs x (A 4096 + B 4096)
  const int tid = threadIdx.x;
  const int lane = tid & 63;
  const int wv = tid >> 6;
  const int nwg = gridDim.x;
  const int bid = blockIdx.x;
  const int swzb = (bid & 7) * (nwg >> 3) + (bid >> 3);
  const int gm = M >> 7;
  const int m0 = (swzb % gm) * 128, n0 = (swzb / gm) * 128;
  if (MODE != 0 && m0 >= seg[4]) return;

  const unsigned short* Bp = B;
  if constexpr (MODE != 0) {
    int e = 0;
#pragma unroll
    for (int i = 1; i < 4; ++i)
      if (m0 >= seg[i]) e = i;
    Bp = B + (size_t)e * N * K;
  }

  const int wm = (wv >> 1) * 64, wn = (wv & 1) * 64;
  const int fr = lane & 15, fc = lane >> 4;

  const int rl = lane >> 2, ch = lane & 3;
  const int R1 = wv * 16 + rl;
  const int R2 = 64 + R1;
  const int co1 = ((ch ^ ((R1 >> 1) & 3)) << 3);
  const int co2 = ((ch ^ ((R2 >> 1) & 3)) << 3);
  const size_t ar1 = (size_t)(m0 + R1) * K;
  const size_t ar2 = (size_t)(m0 + R2) * K;
  const unsigned short* gA1 = A + ar1 + co1;
  const unsigned short* gA2 = A + ar2 + co2;
  const unsigned short* gB1 = Bp + (size_t)(n0 + R1) * K + co1;
  const unsigned short* gB2 = Bp + (size_t)(n0 + R2) * K + co2;
  const int lA1 = (wv * 16) * 32, lA2 = (64 + wv * 16) * 32;

  f32x4 acc[4][4];
#pragma unroll
  for (int i = 0; i < 4; ++i) {
#pragma unroll
    for (int j = 0; j < 4; ++j) acc[i][j] = (f32x4)0.f;
  }

  auto STAGE = [&](int buf, int kt) {
    unsigned short* base = smem + buf * 8192;
    gld16(gA1 + kt, base + lA1);
    gld16(gA2 + kt, base + lA2);
    gld16(gB1 + kt, base + 4096 + lA1);
    gld16(gB2 + kt, base + 4096 + lA2);
  };
  auto COMPUTE = [&](int buf) {
    const unsigned short* sA = smem + buf * 8192;
    const unsigned short* sB = sA + 4096;
    f16x8 a[4], b[4];
#pragma unroll
    for (int mi = 0; mi < 4; ++mi) {
      int r = wm + mi * 16 + fr;
      a[mi] = *(const f16x8*)&sA[r * 32 + ((fc ^ ((r >> 1) & 3)) << 3)];
    }
#pragma unroll
    for (int ni = 0; ni < 4; ++ni) {
      int r = wn + ni * 16 + fr;
      b[ni] = *(const f16x8*)&sB[r * 32 + ((fc ^ ((r >> 1) & 3)) << 3)];
    }
#pragma unroll
    for (int mi = 0; mi < 4; ++mi) {
#pragma unroll
      for (int ni = 0; ni < 4; ++ni) acc[mi][ni] = MFMA16(a[mi], b[ni], acc[mi][ni]);
    }
  };

  const int nk = K >> 5;
  STAGE(0, 0);
  __syncthreads();
  int cur = 0;
  for (int t = 1; t < nk; ++t) {
    STAGE(cur ^ 1, t << 5);
    COMPUTE(cur);
    __syncthreads();
    cur ^= 1;
  }
  COMPUTE(cur);

#pragma unroll
  for (int mi = 0; mi < 4; ++mi) {
#pragma unroll
    for (int ni = 0; ni < 4; ++ni) {
      const int n = n0 + wn + ni * 16 + fr;
      const int mb = m0 + wm + mi * 16 + fc * 4;
#pragma unroll
      for (int i = 0; i < 4; ++i) {
        const int m = mb + i;
        float v = acc[mi][ni][i];
        const size_t cidx = (size_t)m * N + n;
        if constexpr (EPI == 1) {
          ((float*)Cv)[cidx] = aux0[n] * (v + bias[n]) + aux1[cidx];
        } else if constexpr (EPI == 4) {
          if (bias) v += bias[n];
          ((unsigned short*)Cv)[cidx] = f2h(v);
        } else if constexpr (EPI == 6) {
          const int sA_ = slotAB[m * 2], sB_ = slotAB[m * 2 + 1];
          const float wA_ = wAB[m * 2], wB_ = wAB[m * 2 + 1];
          float vm = wA_ * h2f(yc[(size_t)sA_ * N + n]) + wB_ * h2f(yc[(size_t)sB_ * N + n]);
          ((float*)Cv)[cidx] = aux0[n] * (v + vm) + aux1[cidx];
        }
      }
    }
  }
}

// ---------------- gemm256: 256x256 tile, 8 waves, BK=32, depth-2 counted pipeline ----------
// LDS 96KB: 3 bufs x (A 16KB | B 16KB). Per iteration: s_waitcnt vmcnt(4) (tile t done,
// t+1 in flight) + raw s_barrier; 4 MFMA phases read buf[t%3] while issuing tile t+2
// into buf[(t+2)%3] (A in ph0, B in ph1). vmcnt never drains to 0 in the loop (T4).
// MODE: 0 dense | 1 gather: A rows = idx[m], B selected by 256-aligned seg segment.
// EPI: 4 fp16(+bias) | 5 fused swiglu -> fp16, Nh=N/2
template <int EPI, int MODE>
__global__ __launch_bounds__(512) void gemm256(
    const unsigned short* __restrict__ A, const unsigned short* __restrict__ B,
    const float* __restrict__ bias, void* __restrict__ Cv,
    const int* __restrict__ idx, const int* __restrict__ seg,
    int M, int N, int K) {
  __shared__ unsigned short smem[49152];  // 3 bufs x 16384 shorts (32KB each)
  const int tid = threadIdx.x;
  const int lane = tid & 63;
  const int wv = tid >> 6;           // 0..7
  const int wr = wv >> 2;            // 0..1 (m half)
  const int wc = wv & 3;             // 0..3 (n quarter)
  const int fr = lane & 15, fc = lane >> 4;

  const int nwg = gridDim.x;
  const int bid = blockIdx.x;
  const int swzb = (bid & 7) * (nwg >> 3) + (bid >> 3);
  const int gm = M >> 8;
  const int m0 = (swzb % gm) * 256, n0 = (swzb / gm) * 256;
  if (MODE != 0 && m0 >= seg[4]) return;

  const unsigned short* Bp = B;
  if constexpr (MODE != 0) {
    int e = 0;
#pragma unroll
    for (int i = 1; i < 4; ++i)
      if (m0 >= seg[i]) e = i;
    Bp = B + (size_t)e * N * K;
  }

  // staging: per K-tile 4 gld16/wave: A rows [wv*16,+16) of each 128-half, same for B.
  const int srow = (lane >> 2);            // 0..15 within 16-row group
  const int srcc = ((lane & 3) ^ ((lane >> 3) & 3)) << 3;  // pre-swizzled chunk (shorts)
  int mr0, mr1;
  if constexpr (MODE == 1) {
    mr0 = idx[m0 + wv * 16 + srow];
    mr1 = idx[m0 + 128 + wv * 16 + srow];
  } else {
    mr0 = m0 + wv * 16 + srow;
    mr1 = m0 + 128 + wv * 16 + srow;
  }
  const unsigned short* gA0 = A + (size_t)mr0 * K + srcc;
  const unsigned short* gA1 = A + (size_t)mr1 * K + srcc;
  const unsigned short* gB0 = Bp + (size_t)(n0 + wv * 16 + srow) * K + srcc;
  const unsigned short* gB1 = Bp + (size_t)(n0 + 128 + wv * 16 + srow) * K + srcc;
  const int lw = wv << 9;  // wv*16 rows * 32 shorts

  // fragment read offsets (shorts); frag stride = 16 rows * 32 = 512
  const int sw = (fr >> 1) & 3;
  const int fo = ((fc ^ sw) << 3);
  const int aoff = (wr * 128 + fr) * 32 + fo;
  const int boff = (wc * 64 + fr) * 32 + fo;

  f32x4 acc[8][4];
#pragma unroll
  for (int i = 0; i < 8; ++i) {
#pragma unroll
    for (int j = 0; j < 4; ++j) acc[i][j] = (f32x4)0.f;
  }

  const int nk = K >> 5;
  // prologue: stage K-tiles 0 (buf0) and 1 (buf1)
  gld16(gA0, &smem[lw]);
  gld16(gA1, &smem[4096 + lw]);
  gld16(gB0, &smem[8192 + lw]);
  gld16(gB1, &smem[12288 + lw]);
  gld16(gA0 + 32, &smem[16384 + lw]);
  gld16(gA1 + 32, &smem[16384 + 4096 + lw]);
  gld16(gB0 + 32, &smem[16384 + 8192 + lw]);
  gld16(gB1 + 32, &smem[16384 + 12288 + lw]);

  int cur = 0;
  for (int t = 0; t < nk; ++t) {
    // tile t's 4 loads complete; tile t+1's 4 may remain in flight
    if (t < nk - 1)
      asm volatile("s_waitcnt vmcnt(4)" ::: "memory");
    else
      asm volatile("s_waitcnt vmcnt(0)" ::: "memory");
    __builtin_amdgcn_s_barrier();
    __builtin_amdgcn_sched_barrier(0);

    const unsigned short* sA = smem + cur * 16384;
    const unsigned short* sB = sA + 8192;
    int nxt = cur + 2;
    if (nxt >= 3) nxt -= 3;
    unsigned short* nbase = smem + nxt * 16384;
    const bool more = (t + 2) < nk;
    const int kn = (t + 2) << 5;

    // ---- phase 0: B frags + A frags 0,1; issue next-next A ----
    f16x8 b0 = *(const f16x8*)&sB[boff];
    f16x8 b1 = *(const f16x8*)&sB[boff + 512];
    f16x8 b2 = *(const f16x8*)&sB[boff + 1024];
    f16x8 b3 = *(const f16x8*)&sB[boff + 1536];
    {
      f16x8 a0 = *(const f16x8*)&sA[aoff];
      f16x8 a1 = *(const f16x8*)&sA[aoff + 512];
      if (more) {
        gld16(gA0 + kn, nbase + lw);
        gld16(gA1 + kn, nbase + 4096 + lw);
      }
      __builtin_amdgcn_sched_barrier(0);
      __builtin_amdgcn_s_setprio(1);
      acc[0][0] = MFMA16(a0, b0, acc[0][0]);
      acc[0][1] = MFMA16(a0, b1, acc[0][1]);
      acc[0][2] = MFMA16(a0, b2, acc[0][2]);
      acc[0][3] = MFMA16(a0, b3, acc[0][3]);
      acc[1][0] = MFMA16(a1, b0, acc[1][0]);
      acc[1][1] = MFMA16(a1, b1, acc[1][1]);
      acc[1][2] = MFMA16(a1, b2, acc[1][2]);
      acc[1][3] = MFMA16(a1, b3, acc[1][3]);
      __builtin_amdgcn_s_setprio(0);
      __builtin_amdgcn_sched_barrier(0);
    }
    // ---- phase 1: A frags 2,3; issue next-next B ----
    {
      f16x8 a0 = *(const f16x8*)&sA[aoff + 1024];
      f16x8 a1 = *(const f16x8*)&sA[aoff + 1536];
      if (more) {
        gld16(gB0 + kn, nbase + 8192 + lw);
        gld16(gB1 + kn, nbase + 12288 + lw);
      }
      __builtin_amdgcn_sched_barrier(0);
      __builtin_amdgcn_s_setprio(1);
      acc[2][0] = MFMA16(a0, b0, acc[2][0]);
      acc[2][1] = MFMA16(a0, b1, acc[2][1]);
      acc[2][2] = MFMA16(a0, b2, acc[2][2]);
      acc[2][3] = MFMA16(a0, b3, acc[2][3]);
      acc[3][0] = MFMA16(a1, b0, acc[3][0]);
      acc[3][1] = MFMA16(a1, b1, acc[3][1]);
      acc[3][2] = MFMA16(a1, b2, acc[3][2]);
      acc[3][3] = MFMA16(a1, b3, acc[3][3]);
      __builtin_amdgcn_s_setprio(0);
      __builtin_amdgcn_sched_barrier(0);
    }
    // ---- phase 2: A frags 4,5 ----
    {
      f16x8 a0 = *(const f16x8*)&sA[aoff + 2048];
      f16x8 a1 = *(const f16x8*)&sA[aoff + 2560];
      __builtin_amdgcn_sched_barrier(0);
      __builtin_amdgcn_s_setprio(1);
      acc[4][0] = MFMA16(a0, b0, acc[4][0]);
      acc[4][1] = MFMA16(a0, b1, acc[4][1]);
      acc[4][2] = MFMA16(a0, b2, acc[4][2]);
      acc[4][3] = MFMA16(a0, b3, acc[4][3]);
      acc[5][0] = MFMA16(a1, b0, acc[5][0]);
      acc[5][1] = MFMA16(a1, b1, acc[5][1]);
      acc[5][2] = MFMA16(a1, b2, acc[5][2]);
      acc[5][3] = MFMA16(a1, b3, acc[5][3]);
      __builtin_amdgcn_s_setprio(0);
      __builtin_amdgcn_sched_barrier(0);
    }
    // ---- phase 3: A frags 6,7 ----
    {
      f16x8 a0 = *(const f16x8*)&sA[aoff + 3072];
      f16x8 a1 = *(const f16x8*)&sA[aoff + 3584];
      __builtin_amdgcn_sched_barrier(0);
      __builtin_amdgcn_s_setprio(1);
      acc[6][0] = MFMA16(a0, b0, acc[6][0]);
      acc[6][1] = MFMA16(a0, b1, acc[6][1]);
      acc[6][2] = MFMA16(a0, b2, acc[6][2]);
      acc[6][3] = MFMA16(a0, b3, acc[6][3]);
      acc[7][0] = MFMA16(a1, b0, acc[7][0]);
      acc[7][1] = MFMA16(a1, b1, acc[7][1]);
      acc[7][2] = MFMA16(a1, b2, acc[7][2]);
      acc[7][3] = MFMA16(a1, b3, acc[7][3]);
      __builtin_amdgcn_s_setprio(0);
      __builtin_amdgcn_sched_barrier(0);
    }
    cur += 1;
    if (cur >= 3) cur -= 3;
  }

  // epilogue; frag: D[row=fc*4+i][col=fr]
  if constexpr (EPI == 5) {
    unsigned short* Ch = (unsigned short*)Cv;
    const int Nh = N >> 1;
#pragma unroll
    for (int mi = 0; mi < 8; ++mi) {
#pragma unroll
      for (int p = 0; p < 2; ++p) {
        const int hcol = (((n0 + wc * 64) >> 5) + p) * 16 + fr;
        const int mb = m0 + wr * 128 + mi * 16 + fc * 4;
#pragma unroll
        for (int i = 0; i < 4; ++i) {
          const int m = mb + i;
          float v1 = acc[mi][2 * p][i];
          float v3 = acc[mi][2 * p + 1][i];
          float y = v1 / (1.f + __expf(-v1)) * v3;
          Ch[(size_t)m * Nh + hcol] = f2h(y);
        }
      }
    }
  } else {
    unsigned short* Ch = (unsigned short*)Cv;
#pragma unroll
    for (int mi = 0; mi < 8; ++mi) {
#pragma unroll
      for (int ni = 0; ni < 4; ++ni) {
        const int n = n0 + wc * 64 + ni * 16 + fr;
        const int mb = m0 + wr * 128 + mi * 16 + fc * 4;
#pragma unroll
        for (int i = 0; i < 4; ++i) {
          const int m = mb + i;
          float v = acc[mi][ni][i];
          if (bias) v += bias[n];
          Ch[(size_t)m * N + n] = f2h(v);
        }
      }
    }
  }
}

// ---------------- host ----------------

extern "C" void kernel_launch(void* const* d_in, const int* in_sizes, int n_in,
                              void* d_out, int out_size, void* d_ws, size_t ws_size,
                              hipStream_t stream) {
  (void)in_sizes; (void)n_in; (void)out_size; (void)ws_size;
  const float* hs = (const float*)d_in[0];
  const float* temb = (const float*)d_in[1];
  const float* rope = (const float*)d_in[2];
  const float* adaw = (const float*)d_in[3];
  const float* adab = (const float*)d_in[4];
  const float* qkvw = (const float*)d_in[5];
  const float* qkvb = (const float*)d_in[6];
  const float* qnw = (const float*)d_in[7];
  const float* knw = (const float*)d_in[8];
  const float* outw = (const float*)d_in[9];
  const float* outb = (const float*)d_in[10];
  const float* gatew = (const float*)d_in[11];
  const float* ew1 = (const float*)d_in[12];
  const float* ew2 = (const float*)d_in[13];
  const float* ew3 = (const float*)d_in[14];
  const float* sw1 = (const float*)d_in[15];
  const float* sw2 = (const float*)d_in[16];
  const float* sw3 = (const float*)d_in[17];
  float* out = (float*)d_out;
  char* ws = (char*)d_ws;

  size_t off = 0;
  auto give = [&](size_t nbytes) {
    size_t r = off;
    off += (nbytes + 255) & ~(size_t)255;
    return r;
  };
  const size_t T = T_TOK, D = DIM;
  size_t o_mod = give(15360 * 4);
  size_t o_ss = give(D * 4);
  size_t o_wd = give(T * 4 * 4);
  size_t o_idx = give(MPAD * 4);
  size_t o_seg = give(8 * 4);
  size_t o_slot = give(T * 2 * 4);
  size_t o_wab = give(T * 2 * 4);
  size_t o_nh = give(T * D * 2);      // nh fp16; later nh2
  size_t o_qkvh = give(T * 7680 * 2); // qkv fp16; region later reused as hmid
  size_t o_qh = give(T * D * 2);
  size_t o_kh = give(T * D * 2);
  size_t o_vt = give(T * D * 2);
  size_t o_obf = give(T * D * 2);
  size_t o_h2 = give(T * D * 4);
  size_t o_yc = give((size_t)MPAD * D * 2);       // compact expert outputs fp16
  size_t o_hmid2 = give(T * SHID_E * 2);          // shared-expert mid
  // fp16 weights
  size_t o_qkvw = give((size_t)7680 * 2560 * 2);
  size_t o_outw = give((size_t)2560 * 2560 * 2);
  size_t o_ewA = give((size_t)4 * 2 * HID_E * 2560 * 2);  // interleaved w1/w3
  size_t o_ew2 = give((size_t)4 * 2560 * HID_E * 2);
  size_t o_swA = give((size_t)2 * SHID_E * 2560 * 2);     // interleaved sw1/sw3
  size_t o_sw2 = give((size_t)2560 * SHID_E * 2);

  float* mod = (float*)(ws + o_mod);
  float* ss = (float*)(ws + o_ss);
  float* wd = (float*)(ws + o_wd);
  int* idxb = (int*)(ws + o_idx);
  int* segp = (int*)(ws + o_seg);
  int* slotAB = (int*)(ws + o_slot);
  float* wAB = (float*)(ws + o_wab);
  unsigned short* nh_h = (unsigned short*)(ws + o_nh);
  unsigned short* qkvh = (unsigned short*)(ws + o_qkvh);
  unsigned short* qh = (unsigned short*)(ws + o_qh);
  unsigned short* kh = (unsigned short*)(ws + o_kh);
  unsigned short* vt = (unsigned short*)(ws + o_vt);
  unsigned short* obf = (unsigned short*)(ws + o_obf);
  float* h2 = (float*)(ws + o_h2);
  unsigned short* yc = (unsigned short*)(ws + o_yc);
  unsigned short* hmid2 = (unsigned short*)(ws + o_hmid2);
  unsigned short* qkvw_h = (unsigned short*)(ws + o_qkvw);
  unsigned short* outw_h = (unsigned short*)(ws + o_outw);
  unsigned short* ewA_h = (unsigned short*)(ws + o_ewA);
  unsigned short* ew2_h = (unsigned short*)(ws + o_ew2);
  unsigned short* swA_h = (unsigned short*)(ws + o_swA);
  unsigned short* sw2_h = (unsigned short*)(ws + o_sw2);
  unsigned short* nh2 = nh_h;
  // hmid (MPAD x 6912 fp16 = 70.8 MB) aliases qkvh..obf (73.4 MB), dead after out-proj
  unsigned short* hmid = qkvh;

  // 0) weight conversion f32 -> fp16 (+ w1/w3 interleave for fused swiglu)
  cvt_f16<<<2048, 256, 0, stream>>>(qkvw, qkvw_h, 7680 * 2560 / 8);
  cvt_f16<<<2048, 256, 0, stream>>>(outw, outw_h, 2560 * 2560 / 8);
  cvt_f16<<<2048, 256, 0, stream>>>(ew2, ew2_h, 4 * 2560 * HID_E / 8);
  cvt_f16<<<2048, 256, 0, stream>>>(sw2, sw2_h, 2560 * SHID_E / 8);
  for (int e = 0; e < 4; ++e) {
    cvt_pair<<<2 * HID_E, 256, 0, stream>>>(ew1 + (size_t)e * HID_E * DIM,
                                            ew3 + (size_t)e * HID_E * DIM,
                                            ewA_h + (size_t)e * 2 * HID_E * DIM);
  }
  cvt_pair<<<2 * SHID_E, 256, 0, stream>>>(sw1, sw3, swA_h);
  // 1) adaLN modulation
  silu_k<<<10, 256, 0, stream>>>(temb, ss);
  adaln_gemv<<<3840, 256, 0, stream>>>(ss, adaw, adab, mod);
  // 2) LN1 + modulate (fp16)
  ln_mod<<<T, 256, 0, stream>>>(hs, mod, mod + D, nh_h);
  // 3) qkv GEMM -> fp16 (256-tile)
  gemm256<4, 0><<<240, 512, 0, stream>>>(nh_h, qkvw_h, qkvb, qkvh,
                                         nullptr, nullptr, 2048, 7680, 2560);
  // 4) RMSNorm + RoPE
  rmsrope<<<T, 256, 0, stream>>>(qkvh, qnw, knw, rope, qh, kh);
  // 5) V transpose
  transpose_v<<<dim3(80, 64), dim3(32, 8), 0, stream>>>(qkvh, vt);
  // 6) MFMA flash attention
  fattn<<<dim3(32, 20), 256, 0, stream>>>(qh, kh, vt, obf);
  // 7) out proj + gate_msa residual -> h2 f32
  gemm128<1, 0><<<16 * 20, 256, 0, stream>>>(obf, outw_h, outb, h2,
                                             mod + 2 * D, hs, nullptr, nullptr,
                                             nullptr, nullptr, nullptr, 2048, 2560, 2560);
  // 8) LN2 + modulate + routing, then concatenated 256-padded compaction
  ln2_route<<<T, 256, 0, stream>>>(h2, mod + 3 * D, mod + 4 * D, gatew, nh2, wd);
  route_compact<<<1, 256, 0, stream>>>(wd, idxb, segp, slotAB, wAB);
  // 9) MoE experts: ONE fused w1w3+swiglu 256-tile GEMM + ONE w2 GEMM
  gemm256<5, 1><<<20 * 54, 512, 0, stream>>>(nh2, ewA_h, nullptr, hmid,
                                             idxb, segp, MPAD, 2 * HID_E, 2560);
  gemm128<4, 2><<<40 * 20, 256, 0, stream>>>(hmid, ew2_h, nullptr, yc,
                                             nullptr, nullptr, nullptr, segp,
                                             nullptr, nullptr, nullptr,
                                             MPAD, 2560, 6912);
  // 10) shared expert (256-tile fused w1w3+swiglu) + final combine w/ yc gather
  gemm256<5, 0><<<8 * 28, 512, 0, stream>>>(nh2, swA_h, nullptr, hmid2,
                                            nullptr, nullptr, 2048, 2 * SHID_E, 2560);
  gemm128<6, 0><<<16 * 20, 256, 0, stream>>>(hmid2, sw2_h, nullptr, out,
                                             mod + 5 * D, h2, nullptr, nullptr,
                                             slotAB, wAB, yc, 2048, 2560, 3584);
}

// Round 9
// 1383.193 us; speedup vs baseline: 3.8307x; 1.0289x over previous
//
#include <hip/hip_runtime.h>

#define DIM 2560
#define T_TOK 2048
#define NHEADS 20
#define HD 128
#define HID_E 6912
#define SHID_E 3584
#define MPAD 5120  // concat rows, segments padded to 256 (max 4096+4*255 <= 5120)

typedef _Float16 f16x8 __attribute__((ext_vector_type(8)));
typedef float f32x4 __attribute__((ext_vector_type(4)));
typedef unsigned short u16x8 __attribute__((ext_vector_type(8)));

#define MFMA16(a, b, c) __builtin_amdgcn_mfma_f32_16x16x32_f16((a), (b), (c), 0, 0, 0)

__device__ inline unsigned short f2h(float f) {
  return __builtin_bit_cast(unsigned short, (_Float16)f);
}
__device__ inline float h2f(unsigned short u) {
  return (float)__builtin_bit_cast(_Float16, u);
}
__device__ inline float wave_sum(float v) {
#pragma unroll
  for (int off = 32; off > 0; off >>= 1) v += __shfl_down(v, off, 64);
  return v;
}
// async global->LDS, 16B per lane; LDS dest = wave-uniform base + lane*16
__device__ inline void gld16(const void* g, void* l) {
  __builtin_amdgcn_global_load_lds((const __attribute__((address_space(1))) void*)g,
                                   (__attribute__((address_space(3))) void*)l, 16, 0, 0);
}

// ---------------- tiny kernels ----------------

__global__ __launch_bounds__(256) void silu_k(const float* __restrict__ t,
                                              float* __restrict__ ss) {
  int i = blockIdx.x * 256 + threadIdx.x;
  if (i < DIM) {
    float v = t[i];
    ss[i] = v / (1.f + expf(-v));
  }
}

__global__ __launch_bounds__(256) void cvt_f16(const float* __restrict__ in,
                                               unsigned short* __restrict__ outp, int n8) {
  const int stride = gridDim.x * 256;
  for (int i = blockIdx.x * 256 + threadIdx.x; i < n8; i += stride) {
    float4 a = *(const float4*)(in + (size_t)i * 8);
    float4 b = *(const float4*)(in + (size_t)i * 8 + 4);
    u16x8 u;
    u[0] = f2h(a.x); u[1] = f2h(a.y); u[2] = f2h(a.z); u[3] = f2h(a.w);
    u[4] = f2h(b.x); u[5] = f2h(b.y); u[6] = f2h(b.z); u[7] = f2h(b.w);
    *(u16x8*)&outp[(size_t)i * 8] = u;
  }
}

// interleave w1/w3 rows into B' : row j -> (j&31)<16 ? w1[(j>>5)*16+(j&15)]
//                                          : w3[(j>>5)*16+(j&15)]
__global__ __launch_bounds__(256) void cvt_pair(const float* __restrict__ w1,
                                                const float* __restrict__ w3,
                                                unsigned short* __restrict__ outp) {
  const int j = blockIdx.x;
  const int g = j >> 5, r = j & 31;
  const float* src = (r < 16) ? (w1 + (size_t)(g * 16 + r) * DIM)
                              : (w3 + (size_t)(g * 16 + (r & 15)) * DIM);
  unsigned short* dst = outp + (size_t)j * DIM;
  for (int i = threadIdx.x; i < 320; i += 256) {
    float4 a = *(const float4*)(src + i * 8);
    float4 b = *(const float4*)(src + i * 8 + 4);
    u16x8 u;
    u[0] = f2h(a.x); u[1] = f2h(a.y); u[2] = f2h(a.z); u[3] = f2h(a.w);
    u[4] = f2h(b.x); u[5] = f2h(b.y); u[6] = f2h(b.z); u[7] = f2h(b.w);
    *(u16x8*)&dst[i * 8] = u;
  }
}

// mod[j] = dot(silu(temb), adaln_w[j]) + adaln_b[j]; one wave per output
__global__ __launch_bounds__(256) void adaln_gemv(const float* __restrict__ ss,
                                                  const float* __restrict__ W,
                                                  const float* __restrict__ bias,
                                                  float* __restrict__ mod) {
  const int lane = threadIdx.x & 63;
  const int j = blockIdx.x * 4 + (threadIdx.x >> 6);
  const float* wr = W + (size_t)j * DIM;
  float p = 0.f;
  for (int i = lane; i < 640; i += 64) {
    float4 w = *(const float4*)(wr + i * 4);
    float4 x = *(const float4*)(ss + i * 4);
    p += w.x * x.x + w.y * x.y + w.z * x.z + w.w * x.w;
  }
  p = wave_sum(p);
  if (lane == 0) mod[j] = p + bias[j];
}

// LN (no affine) then *(1+scale)+shift, write fp16. One block per row.
__global__ __launch_bounds__(256) void ln_mod(const float* __restrict__ x,
                                              const float* __restrict__ shift,
                                              const float* __restrict__ scale,
                                              unsigned short* __restrict__ outp) {
  __shared__ float rbuf[8];
  const int t = blockIdx.x, tid = threadIdx.x, lane = tid & 63, wid = tid >> 6;
  const float* xr = x + (size_t)t * DIM;
  float s = 0.f, sq = 0.f;
  for (int i = tid; i < 640; i += 256) {
    float4 v = *(const float4*)(xr + i * 4);
    s += v.x + v.y + v.z + v.w;
    sq += v.x * v.x + v.y * v.y + v.z * v.z + v.w * v.w;
  }
  s = wave_sum(s);
  sq = wave_sum(sq);
  if (lane == 0) {
    rbuf[wid] = s;
    rbuf[4 + wid] = sq;
  }
  __syncthreads();
  float S = rbuf[0] + rbuf[1] + rbuf[2] + rbuf[3];
  float SQ = rbuf[4] + rbuf[5] + rbuf[6] + rbuf[7];
  float mean = S * (1.f / DIM);
  float rs = rsqrtf(SQ * (1.f / DIM) - mean * mean + 1e-6f);
  for (int i = tid; i < 640; i += 256) {
    float4 v = *(const float4*)(xr + i * 4);
    float4 sc4 = *(const float4*)(scale + i * 4);
    float4 sh4 = *(const float4*)(shift + i * 4);
    ushort4 u;
    u.x = f2h((v.x - mean) * rs * (1.f + sc4.x) + sh4.x);
    u.y = f2h((v.y - mean) * rs * (1.f + sc4.y) + sh4.y);
    u.z = f2h((v.z - mean) * rs * (1.f + sc4.z) + sh4.z);
    u.w = f2h((v.w - mean) * rs * (1.f + sc4.w) + sh4.w);
    *(ushort4*)&outp[(size_t)t * DIM + i * 4] = u;
  }
}

// RMSNorm(q),(k) over full 2560 + weight + RoPE -> qh (scaled by 1/sqrt(128)), kh
__global__ __launch_bounds__(256) void rmsrope(const unsigned short* __restrict__ qkv,
                                               const float* __restrict__ qn,
                                               const float* __restrict__ kn,
                                               const float* __restrict__ rope,
                                               unsigned short* __restrict__ qh,
                                               unsigned short* __restrict__ kh) {
  __shared__ float rbuf[8];
  const int t = blockIdx.x, tid = threadIdx.x, lane = tid & 63, wid = tid >> 6;
  const unsigned short* row = qkv + (size_t)t * 7680;
  float sq = 0.f, sk = 0.f;
  for (int i = tid; i < 320; i += 256) {
    f16x8 qv = *(const f16x8*)(row + i * 8);
    f16x8 kv = *(const f16x8*)(row + DIM + i * 8);
#pragma unroll
    for (int j = 0; j < 8; ++j) {
      float q = (float)qv[j], k = (float)kv[j];
      sq += q * q;
      sk += k * k;
    }
  }
  sq = wave_sum(sq);
  sk = wave_sum(sk);
  if (lane == 0) {
    rbuf[wid] = sq;
    rbuf[4 + wid] = sk;
  }
  __syncthreads();
  float SQ = rbuf[0] + rbuf[1] + rbuf[2] + rbuf[3];
  float SK = rbuf[4] + rbuf[5] + rbuf[6] + rbuf[7];
  float rq = rsqrtf(SQ * (1.f / DIM) + 1e-6f) * 0.08838834764831845f;
  float rk = rsqrtf(SK * (1.f / DIM) + 1e-6f);
  for (int pp = tid; pp < 1280; pp += 256) {
    int c = pp * 2;
    float qe = h2f(row[c]) * rq * qn[c], qo = h2f(row[c + 1]) * rq * qn[c + 1];
    float ke = h2f(row[DIM + c]) * rk * kn[c], ko = h2f(row[DIM + c + 1]) * rk * kn[c + 1];
    float4 rr = *(const float4*)(rope + (size_t)t * 256 + (pp & 63) * 4);
    unsigned qp = (unsigned)f2h(rr.x * qe + rr.y * qo) |
                  ((unsigned)f2h(rr.z * qe + rr.w * qo) << 16);
    unsigned kp = (unsigned)f2h(rr.x * ke + rr.y * ko) |
                  ((unsigned)f2h(rr.z * ke + rr.w * ko) << 16);
    *(unsigned*)&qh[(size_t)t * DIM + c] = qp;
    *(unsigned*)&kh[(size_t)t * DIM + c] = kp;
  }
}

// V part of qkv (fp16 [2048][7680] at col 5120) -> vt fp16 [2560][2048]
__global__ void transpose_v(const unsigned short* __restrict__ in,
                            unsigned short* __restrict__ outp) {
  __shared__ unsigned short tile[32][33];
  const int bx = blockIdx.x * 32;  // channel
  const int by = blockIdx.y * 32;  // token
  const int tx = threadIdx.x, ty = threadIdx.y;
  for (int j = ty; j < 32; j += 8)
    tile[j][tx] = in[(size_t)(by + j) * 7680 + 5120 + bx + tx];
  __syncthreads();
  for (int j = ty; j < 32; j += 8)
    outp[(size_t)(bx + j) * T_TOK + by + tx] = tile[tx][j];
}

// ---------------- MFMA flash attention ----------------
__global__ __launch_bounds__(256) void fattn(const unsigned short* __restrict__ qh,
                                             const unsigned short* __restrict__ kh,
                                             const unsigned short* __restrict__ vt,
                                             unsigned short* __restrict__ obuf) {
  __shared__ unsigned short sK[64 * 128];  // [k][d], slot = c ^ (r&15)
  __shared__ unsigned short sV[128 * 64];  // [d][k], slot = c ^ (r&7)
  __shared__ unsigned short sP[64 * 64];   // [q][k], slot = c ^ (r&7)
  __shared__ float sRedM[4][64];
  __shared__ float sRedL[4][64];
  __shared__ float sM[64];
  __shared__ float sL[64];
  const int tid = threadIdx.x, lane = tid & 63, wv = tid >> 6;
  const int g = lane >> 4, fr = lane & 15;
  const int h = blockIdx.y;
  const int q0 = blockIdx.x * 64;

  {
    const int r = tid >> 2, qt = tid & 3;
    const unsigned short* gp = qh + (size_t)(q0 + r) * DIM + h * HD + qt * 32;
    uint4 v0 = ((const uint4*)gp)[0];
    uint4 v1 = ((const uint4*)gp)[1];
    uint4 v2 = ((const uint4*)gp)[2];
    uint4 v3 = ((const uint4*)gp)[3];
    unsigned short* dst = &sK[r * 128];
    const int cb = qt * 4, rs = r & 15;
    *(uint4*)&dst[((cb + 0) ^ rs) * 8] = v0;
    *(uint4*)&dst[((cb + 1) ^ rs) * 8] = v1;
    *(uint4*)&dst[((cb + 2) ^ rs) * 8] = v2;
    *(uint4*)&dst[((cb + 3) ^ rs) * 8] = v3;
  }
  __syncthreads();
  f16x8 qfrag[4][4];
#pragma unroll
  for (int ni = 0; ni < 4; ++ni) {
#pragma unroll
    for (int kt = 0; kt < 4; ++kt) {
      int r = ni * 16 + fr;
      qfrag[ni][kt] = *(const f16x8*)&sK[r * 128 + (((kt * 4 + g) ^ (r & 15)) << 3)];
    }
  }
  __syncthreads();

  f32x4 acco[4][2];
  f32x4 mprev[4];
  float mrun[4], lrun[4];
#pragma unroll
  for (int i = 0; i < 4; ++i) {
    acco[i][0] = (f32x4)0.f;
    acco[i][1] = (f32x4)0.f;
    mprev[i] = (f32x4)(-1e30f);
    mrun[i] = -1e30f;
    lrun[i] = 0.f;
  }

  for (int kt0 = 0; kt0 < T_TOK; kt0 += 64) {
    {
      const int r = tid >> 2, qt = tid & 3;
      const unsigned short* gp = kh + (size_t)(kt0 + r) * DIM + h * HD + qt * 32;
      uint4 v0 = ((const uint4*)gp)[0];
      uint4 v1 = ((const uint4*)gp)[1];
      uint4 v2 = ((const uint4*)gp)[2];
      uint4 v3 = ((const uint4*)gp)[3];
      unsigned short* dst = &sK[r * 128];
      const int cb = qt * 4, rs = r & 15;
      *(uint4*)&dst[((cb + 0) ^ rs) * 8] = v0;
      *(uint4*)&dst[((cb + 1) ^ rs) * 8] = v1;
      *(uint4*)&dst[((cb + 2) ^ rs) * 8] = v2;
      *(uint4*)&dst[((cb + 3) ^ rs) * 8] = v3;
      const int rv = tid >> 1, hf = tid & 1;
      const unsigned short* gv = vt + (size_t)(h * HD + rv) * T_TOK + kt0 + hf * 32;
      uint4 w0 = ((const uint4*)gv)[0];
      uint4 w1 = ((const uint4*)gv)[1];
      uint4 w2 = ((const uint4*)gv)[2];
      uint4 w3 = ((const uint4*)gv)[3];
      unsigned short* dv = &sV[rv * 64];
      const int cv = hf * 4, rvs = rv & 7;
      *(uint4*)&dv[((cv + 0) ^ rvs) * 8] = w0;
      *(uint4*)&dv[((cv + 1) ^ rvs) * 8] = w1;
      *(uint4*)&dv[((cv + 2) ^ rvs) * 8] = w2;
      *(uint4*)&dv[((cv + 3) ^ rvs) * 8] = w3;
    }
    __syncthreads();  // B0

    f32x4 accs[4] = {(f32x4)0.f, (f32x4)0.f, (f32x4)0.f, (f32x4)0.f};
#pragma unroll
    for (int kt = 0; kt < 4; ++kt) {
      int r = wv * 16 + fr;
      f16x8 ak = *(const f16x8*)&sK[r * 128 + (((kt * 4 + g) ^ (r & 15)) << 3)];
#pragma unroll
      for (int ni = 0; ni < 4; ++ni) accs[ni] = MFMA16(ak, qfrag[ni][kt], accs[ni]);
    }

    float pm[4];
#pragma unroll
    for (int ni = 0; ni < 4; ++ni) {
      float m = fmaxf(fmaxf(accs[ni][0], accs[ni][1]), fmaxf(accs[ni][2], accs[ni][3]));
      m = fmaxf(m, __shfl_xor(m, 16));
      m = fmaxf(m, __shfl_xor(m, 32));
      pm[ni] = m;
    }
    if (g == 0) {
#pragma unroll
      for (int ni = 0; ni < 4; ++ni) sRedM[wv][ni * 16 + fr] = pm[ni];
    }
    __syncthreads();  // B1
    float mnew[4];
#pragma unroll
    for (int ni = 0; ni < 4; ++ni) {
      int q = ni * 16 + fr;
      float mt = fmaxf(fmaxf(sRedM[0][q], sRedM[1][q]), fmaxf(sRedM[2][q], sRedM[3][q]));
      mnew[ni] = fmaxf(mrun[ni], mt);
    }
    float lsum[4];
#pragma unroll
    for (int ni = 0; ni < 4; ++ni) {
      float l0 = 0.f;
#pragma unroll
      for (int i = 0; i < 4; ++i) {
        float p = __expf(accs[ni][i] - mnew[ni]);
        accs[ni][i] = p;
        l0 += p;
      }
      l0 += __shfl_xor(l0, 16);
      l0 += __shfl_xor(l0, 32);
      lsum[ni] = l0;
    }
    if (g == 0) {
#pragma unroll
      for (int ni = 0; ni < 4; ++ni) sRedL[wv][ni * 16 + fr] = lsum[ni];
      if (wv == 0) {
#pragma unroll
        for (int ni = 0; ni < 4; ++ni) sM[ni * 16 + fr] = mnew[ni];
      }
    }
#pragma unroll
    for (int ni = 0; ni < 4; ++ni) {
      int q = ni * 16 + fr;
      unsigned p01 = (unsigned)f2h(accs[ni][0]) | ((unsigned)f2h(accs[ni][1]) << 16);
      unsigned p23 = (unsigned)f2h(accs[ni][2]) | ((unsigned)f2h(accs[ni][3]) << 16);
      uint2 pk;
      pk.x = p01;
      pk.y = p23;
      *(uint2*)&sP[q * 64 + ((((wv << 1) | (g >> 1)) ^ (q & 7)) << 3) + ((g & 1) << 2)] = pk;
    }
    __syncthreads();  // B2
#pragma unroll
    for (int ni = 0; ni < 4; ++ni) {
      int q = ni * 16 + fr;
      float lt = sRedL[0][q] + sRedL[1][q] + sRedL[2][q] + sRedL[3][q];
      lrun[ni] = lrun[ni] * __expf(mrun[ni] - mnew[ni]) + lt;
      mrun[ni] = mnew[ni];
    }

#pragma unroll
    for (int mi = 0; mi < 4; ++mi) {
      f32x4 mn = *(const f32x4*)&sM[mi * 16 + g * 4];
      f32x4 sc;
#pragma unroll
      for (int i = 0; i < 4; ++i) sc[i] = __expf(mprev[mi][i] - mn[i]);
      acco[mi][0] *= sc;
      acco[mi][1] *= sc;
      mprev[mi] = mn;
    }
#pragma unroll
    for (int ktp = 0; ktp < 2; ++ktp) {
      f16x8 bv[2];
#pragma unroll
      for (int nd = 0; nd < 2; ++nd) {
        int r = wv * 32 + nd * 16 + fr;
        bv[nd] = *(const f16x8*)&sV[r * 64 + (((ktp * 4 + g) ^ (r & 7)) << 3)];
      }
#pragma unroll
      for (int mi = 0; mi < 4; ++mi) {
        int r = mi * 16 + fr;
        f16x8 ap = *(const f16x8*)&sP[r * 64 + (((ktp * 4 + g) ^ (r & 7)) << 3)];
        acco[mi][0] = MFMA16(ap, bv[0], acco[mi][0]);
        acco[mi][1] = MFMA16(ap, bv[1], acco[mi][1]);
      }
    }
    __syncthreads();  // B3
  }

  if (wv == 0 && g == 0) {
#pragma unroll
    for (int ni = 0; ni < 4; ++ni) sL[ni * 16 + fr] = 1.f / lrun[ni];
  }
  __syncthreads();
#pragma unroll
  for (int mi = 0; mi < 4; ++mi) {
    f32x4 li = *(const f32x4*)&sL[mi * 16 + g * 4];
#pragma unroll
    for (int nd = 0; nd < 2; ++nd) {
#pragma unroll
      for (int i = 0; i < 4; ++i) {
        float o = acco[mi][nd][i] * li[i];
        obuf[(size_t)(q0 + mi * 16 + g * 4 + i) * DIM + h * HD + wv * 32 + nd * 16 + fr] =
            f2h(o);
      }
    }
  }
}

// LN2 + modulate -> nh2 fp16, plus f32 routing (softmax over 4, top-2, unnormalized)
__global__ __launch_bounds__(256) void ln2_route(const float* __restrict__ x,
                                                 const float* __restrict__ shift,
                                                 const float* __restrict__ scale,
                                                 const float* __restrict__ gw,
                                                 unsigned short* __restrict__ nh2,
                                                 float* __restrict__ wd) {
  __shared__ float rbuf[8];
  __shared__ float gbuf[4][4];
  const int t = blockIdx.x, tid = threadIdx.x, lane = tid & 63, wid = tid >> 6;
  const float* xr = x + (size_t)t * DIM;
  float s = 0.f, sq = 0.f;
  for (int i = tid; i < 640; i += 256) {
    float4 v = *(const float4*)(xr + i * 4);
    s += v.x + v.y + v.z + v.w;
    sq += v.x * v.x + v.y * v.y + v.z * v.z + v.w * v.w;
  }
  s = wave_sum(s);
  sq = wave_sum(sq);
  if (lane == 0) {
    rbuf[wid] = s;
    rbuf[4 + wid] = sq;
  }
  __syncthreads();
  float S = rbuf[0] + rbuf[1] + rbuf[2] + rbuf[3];
  float SQ = rbuf[4] + rbuf[5] + rbuf[6] + rbuf[7];
  float mean = S * (1.f / DIM);
  float rs = rsqrtf(SQ * (1.f / DIM) - mean * mean + 1e-6f);
  float g0 = 0.f, g1 = 0.f, g2 = 0.f, g3 = 0.f;
  for (int i = tid; i < 640; i += 256) {
    float4 v = *(const float4*)(xr + i * 4);
    float4 sc4 = *(const float4*)(scale + i * 4);
    float4 sh4 = *(const float4*)(shift + i * 4);
    float y0 = (v.x - mean) * rs * (1.f + sc4.x) + sh4.x;
    float y1 = (v.y - mean) * rs * (1.f + sc4.y) + sh4.y;
    float y2 = (v.z - mean) * rs * (1.f + sc4.z) + sh4.z;
    float y3 = (v.w - mean) * rs * (1.f + sc4.w) + sh4.w;
    ushort4 u;
    u.x = f2h(y0); u.y = f2h(y1); u.z = f2h(y2); u.w = f2h(y3);
    *(ushort4*)&nh2[(size_t)t * DIM + i * 4] = u;
    float4 w0 = *(const float4*)(gw + i * 4);
    float4 w1 = *(const float4*)(gw + DIM + i * 4);
    float4 w2 = *(const float4*)(gw + 2 * DIM + i * 4);
    float4 w3 = *(const float4*)(gw + 3 * DIM + i * 4);
    g0 += y0 * w0.x + y1 * w0.y + y2 * w0.z + y3 * w0.w;
    g1 += y0 * w1.x + y1 * w1.y + y2 * w1.z + y3 * w1.w;
    g2 += y0 * w2.x + y1 * w2.y + y2 * w2.z + y3 * w2.w;
    g3 += y0 * w3.x + y1 * w3.y + y2 * w3.z + y3 * w3.w;
  }
  g0 = wave_sum(g0);
  g1 = wave_sum(g1);
  g2 = wave_sum(g2);
  g3 = wave_sum(g3);
  if (lane == 0) {
    gbuf[wid][0] = g0; gbuf[wid][1] = g1; gbuf[wid][2] = g2; gbuf[wid][3] = g3;
  }
  __syncthreads();
  if (tid == 0) {
    float l[4];
#pragma unroll
    for (int e = 0; e < 4; ++e) l[e] = gbuf[0][e] + gbuf[1][e] + gbuf[2][e] + gbuf[3][e];
    float mx = fmaxf(fmaxf(l[0], l[1]), fmaxf(l[2], l[3]));
    float ex[4], sum = 0.f;
#pragma unroll
    for (int e = 0; e < 4; ++e) { ex[e] = expf(l[e] - mx); sum += ex[e]; }
    float p[4];
#pragma unroll
    for (int e = 0; e < 4; ++e) p[e] = ex[e] / sum;
    int i1 = 0;
    for (int e = 1; e < 4; ++e)
      if (p[e] > p[i1]) i1 = e;
    int i2 = -1;
    for (int e = 0; e < 4; ++e) {
      if (e == i1) continue;
      if (i2 < 0 || p[e] > p[i2]) i2 = e;
    }
    float w[4] = {0.f, 0.f, 0.f, 0.f};
    w[i1] = p[i1];
    w[i2] = p[i2];
    *(float4*)&wd[(size_t)t * 4] = make_float4(w[0], w[1], w[2], w[3]);
  }
}

// Concatenated padded top-2 compaction. One block, 256 threads, 8 tokens each.
// Segments padded to 256 (for the 256-tile GEMM). idx pad rows point at token 0.
__global__ __launch_bounds__(256) void route_compact(const float* __restrict__ wd,
                                                     int* __restrict__ idx_all,
                                                     int* __restrict__ seg,
                                                     int* __restrict__ slotAB,
                                                     float* __restrict__ wAB) {
  __shared__ unsigned short c[256][4];
  __shared__ int offs[256][4];
  __shared__ int segs[5];
  const int t = threadIdx.x;
  for (int i = t; i < MPAD; i += 256) idx_all[i] = 0;
  unsigned char sel[8];
  float wv4[8][4];
  unsigned short lc[4] = {0, 0, 0, 0};
#pragma unroll
  for (int k = 0; k < 8; ++k) {
    int tok = t * 8 + k;
    float4 w = *(const float4*)&wd[(size_t)tok * 4];
    wv4[k][0] = w.x; wv4[k][1] = w.y; wv4[k][2] = w.z; wv4[k][3] = w.w;
    unsigned m = 0;
    if (w.x != 0.f) { m |= 1; lc[0]++; }
    if (w.y != 0.f) { m |= 2; lc[1]++; }
    if (w.z != 0.f) { m |= 4; lc[2]++; }
    if (w.w != 0.f) { m |= 8; lc[3]++; }
    sel[k] = (unsigned char)m;
  }
#pragma unroll
  for (int e = 0; e < 4; ++e) c[t][e] = lc[e];
  __syncthreads();
  if (t == 0) {
    int run[4] = {0, 0, 0, 0};
    for (int i = 0; i < 256; ++i) {
#pragma unroll
      for (int e = 0; e < 4; ++e) {
        offs[i][e] = run[e];
        run[e] += c[i][e];
      }
    }
    int s = 0;
    segs[0] = 0;
#pragma unroll
    for (int e = 0; e < 4; ++e) {
      s += (run[e] + 255) & ~255;
      segs[e + 1] = s;
    }
#pragma unroll
    for (int e = 0; e < 5; ++e) seg[e] = segs[e];
  }
  __syncthreads();
  int o[4];
#pragma unroll
  for (int e = 0; e < 4; ++e) o[e] = segs[e] + offs[t][e];
#pragma unroll
  for (int k = 0; k < 8; ++k) {
    int tok = t * 8 + k;
    unsigned m = sel[k];
    int sl[2] = {0, 0};
    float sw[2] = {0.f, 0.f};
    int ns = 0;
#pragma unroll
    for (int e = 0; e < 4; ++e) {
      if ((m >> e) & 1) {
        if (ns < 2) { sl[ns] = o[e]; sw[ns] = wv4[k][e]; }
        idx_all[o[e]++] = tok;
        ns++;
      }
    }
    if (ns == 1) { sl[1] = sl[0]; sw[1] = 0.f; }
    slotAB[tok * 2] = sl[0];
    slotAB[tok * 2 + 1] = sl[1];
    wAB[tok * 2] = sw[0];
    wAB[tok * 2 + 1] = sw[1];
  }
}

// ---------------- gemm128: kept for out-proj / final (epilogue-heavy) ----------------
// EPI: 1 f32 aux0[n]*(v+bias)+aux1 | 4 fp16(+bias) |
//      6 final: aux0[n]*(v + wA*yc[slA]+wB*yc[slB]) + aux1
// MODE: 0 dense | 2 concat-direct: A compact rows, B by seg, bound seg[4]
template <int EPI, int MODE>
__global__ __launch_bounds__(256) void gemm128(
    const unsigned short* __restrict__ A, const unsigned short* __restrict__ B,
    const float* __restrict__ bias, void* __restrict__ Cv,
    const float* __restrict__ aux0, const float* __restrict__ aux1,
    const int* __restrict__ idx, const int* __restrict__ seg,
    const int* __restrict__ slotAB, const float* __restrict__ wAB,
    const unsigned short* __restrict__ yc, int M, int N, int K) {
  __shared__ unsigned short smem[16384];  // 2 bufs x (A 4096 + B 4096)
  const int tid = threadIdx.x;
  const int lane = tid & 63;
  const int wv = tid >> 6;
  const int nwg = gridDim.x;
  const int bid = blockIdx.x;
  const int swzb = (bid & 7) * (nwg >> 3) + (bid >> 3);
  const int gm = M >> 7;
  const int m0 = (swzb % gm) * 128, n0 = (swzb / gm) * 128;
  if (MODE != 0 && m0 >= seg[4]) return;

  const unsigned short* Bp = B;
  if constexpr (MODE != 0) {
    int e = 0;
#pragma unroll
    for (int i = 1; i < 4; ++i)
      if (m0 >= seg[i]) e = i;
    Bp = B + (size_t)e * N * K;
  }

  const int wm = (wv >> 1) * 64, wn = (wv & 1) * 64;
  const int fr = lane & 15, fc = lane >> 4;

  const int rl = lane >> 2, ch = lane & 3;
  const int R1 = wv * 16 + rl;
  const int R2 = 64 + R1;
  const int co1 = ((ch ^ ((R1 >> 1) & 3)) << 3);
  const int co2 = ((ch ^ ((R2 >> 1) & 3)) << 3);
  const size_t ar1 = (size_t)(m0 + R1) * K;
  const size_t ar2 = (size_t)(m0 + R2) * K;
  const unsigned short* gA1 = A + ar1 + co1;
  const unsigned short* gA2 = A + ar2 + co2;
  const unsigned short* gB1 = Bp + (size_t)(n0 + R1) * K + co1;
  const unsigned short* gB2 = Bp + (size_t)(n0 + R2) * K + co2;
  const int lA1 = (wv * 16) * 32, lA2 = (64 + wv * 16) * 32;

  f32x4 acc[4][4];
#pragma unroll
  for (int i = 0; i < 4; ++i) {
#pragma unroll
    for (int j = 0; j < 4; ++j) acc[i][j] = (f32x4)0.f;
  }

  auto STAGE = [&](int buf, int kt) {
    unsigned short* base = smem + buf * 8192;
    gld16(gA1 + kt, base + lA1);
    gld16(gA2 + kt, base + lA2);
    gld16(gB1 + kt, base + 4096 + lA1);
    gld16(gB2 + kt, base + 4096 + lA2);
  };
  auto COMPUTE = [&](int buf) {
    const unsigned short* sA = smem + buf * 8192;
    const unsigned short* sB = sA + 4096;
    f16x8 a[4], b[4];
#pragma unroll
    for (int mi = 0; mi < 4; ++mi) {
      int r = wm + mi * 16 + fr;
      a[mi] = *(const f16x8*)&sA[r * 32 + ((fc ^ ((r >> 1) & 3)) << 3)];
    }
#pragma unroll
    for (int ni = 0; ni < 4; ++ni) {
      int r = wn + ni * 16 + fr;
      b[ni] = *(const f16x8*)&sB[r * 32 + ((fc ^ ((r >> 1) & 3)) << 3)];
    }
#pragma unroll
    for (int mi = 0; mi < 4; ++mi) {
#pragma unroll
      for (int ni = 0; ni < 4; ++ni) acc[mi][ni] = MFMA16(a[mi], b[ni], acc[mi][ni]);
    }
  };

  const int nk = K >> 5;
  STAGE(0, 0);
  __syncthreads();
  int cur = 0;
  for (int t = 1; t < nk; ++t) {
    STAGE(cur ^ 1, t << 5);
    COMPUTE(cur);
    __syncthreads();
    cur ^= 1;
  }
  COMPUTE(cur);

#pragma unroll
  for (int mi = 0; mi < 4; ++mi) {
#pragma unroll
    for (int ni = 0; ni < 4; ++ni) {
      const int n = n0 + wn + ni * 16 + fr;
      const int mb = m0 + wm + mi * 16 + fc * 4;
#pragma unroll
      for (int i = 0; i < 4; ++i) {
        const int m = mb + i;
        float v = acc[mi][ni][i];
        const size_t cidx = (size_t)m * N + n;
        if constexpr (EPI == 1) {
          ((float*)Cv)[cidx] = aux0[n] * (v + bias[n]) + aux1[cidx];
        } else if constexpr (EPI == 4) {
          if (bias) v += bias[n];
          ((unsigned short*)Cv)[cidx] = f2h(v);
        } else if constexpr (EPI == 6) {
          const int sA_ = slotAB[m * 2], sB_ = slotAB[m * 2 + 1];
          const float wA_ = wAB[m * 2], wB_ = wAB[m * 2 + 1];
          float vm = wA_ * h2f(yc[(size_t)sA_ * N + n]) + wB_ * h2f(yc[(size_t)sB_ * N + n]);
          ((float*)Cv)[cidx] = aux0[n] * (v + vm) + aux1[cidx];
        }
      }
    }
  }
}

// ---------------- gemm256: 256x256 tile, 8 waves, BK=32, depth-2 counted pipeline ----------
// LDS 96KB: 3 bufs. Per iteration: s_waitcnt vmcnt(4) + s_barrier; 4 MFMA phases with
// REGISTER FRAGMENT PREFETCH one phase ahead (ds_read latency hides under MFMA cluster).
// gld16 for tile t+2 issued in phases 0 (A) and 1 (B). vmcnt never drains in-loop (T4).
// MODE: 0 dense | 1 gather: A rows = idx[m], B by 256-aligned seg | 2 direct A, B by seg.
// EPI: 4 fp16(+bias) | 5 fused swiglu -> fp16, Nh=N/2
template <int EPI, int MODE>
__global__ __launch_bounds__(512) void gemm256(
    const unsigned short* __restrict__ A, const unsigned short* __restrict__ B,
    const float* __restrict__ bias, void* __restrict__ Cv,
    const int* __restrict__ idx, const int* __restrict__ seg,
    int M, int N, int K) {
  __shared__ unsigned short smem[49152];  // 3 bufs x 16384 shorts (32KB each)
  const int tid = threadIdx.x;
  const int lane = tid & 63;
  const int wv = tid >> 6;           // 0..7
  const int wr = wv >> 2;            // 0..1 (m half)
  const int wc = wv & 3;             // 0..3 (n quarter)
  const int fr = lane & 15, fc = lane >> 4;

  const int nwg = gridDim.x;
  const int bid = blockIdx.x;
  const int swzb = (bid & 7) * (nwg >> 3) + (bid >> 3);
  const int gm = M >> 8;
  const int m0 = (swzb % gm) * 256, n0 = (swzb / gm) * 256;
  if (MODE != 0 && m0 >= seg[4]) return;

  const unsigned short* Bp = B;
  if constexpr (MODE != 0) {
    int e = 0;
#pragma unroll
    for (int i = 1; i < 4; ++i)
      if (m0 >= seg[i]) e = i;
    Bp = B + (size_t)e * N * K;
  }

  // staging: per K-tile 4 gld16/wave: A rows [wv*16,+16) of each 128-half, same for B.
  const int srow = (lane >> 2);            // 0..15 within 16-row group
  const int srcc = ((lane & 3) ^ ((lane >> 3) & 3)) << 3;  // pre-swizzled chunk (shorts)
  int mr0, mr1;
  if constexpr (MODE == 1) {
    mr0 = idx[m0 + wv * 16 + srow];
    mr1 = idx[m0 + 128 + wv * 16 + srow];
  } else {
    mr0 = m0 + wv * 16 + srow;
    mr1 = m0 + 128 + wv * 16 + srow;
  }
  const unsigned short* gA0 = A + (size_t)mr0 * K + srcc;
  const unsigned short* gA1 = A + (size_t)mr1 * K + srcc;
  const unsigned short* gB0 = Bp + (size_t)(n0 + wv * 16 + srow) * K + srcc;
  const unsigned short* gB1 = Bp + (size_t)(n0 + 128 + wv * 16 + srow) * K + srcc;
  const int lw = wv << 9;  // wv*16 rows * 32 shorts

  // fragment read offsets (shorts); frag stride = 16 rows * 32 = 512
  const int sw = (fr >> 1) & 3;
  const int fo = ((fc ^ sw) << 3);
  const int aoff = (wr * 128 + fr) * 32 + fo;
  const int boff = (wc * 64 + fr) * 32 + fo;

  f32x4 acc[8][4];
#pragma unroll
  for (int i = 0; i < 8; ++i) {
#pragma unroll
    for (int j = 0; j < 4; ++j) acc[i][j] = (f32x4)0.f;
  }

  const int nk = K >> 5;
  // prologue: stage K-tiles 0 (buf0) and 1 (buf1)
  gld16(gA0, &smem[lw]);
  gld16(gA1, &smem[4096 + lw]);
  gld16(gB0, &smem[8192 + lw]);
  gld16(gB1, &smem[12288 + lw]);
  gld16(gA0 + 32, &smem[16384 + lw]);
  gld16(gA1 + 32, &smem[16384 + 4096 + lw]);
  gld16(gB0 + 32, &smem[16384 + 8192 + lw]);
  gld16(gB1 + 32, &smem[16384 + 12288 + lw]);

  int cur = 0;
  for (int t = 0; t < nk; ++t) {
    // tile t's 4 loads complete; tile t+1's 4 may remain in flight
    if (t < nk - 1)
      asm volatile("s_waitcnt vmcnt(4)" ::: "memory");
    else
      asm volatile("s_waitcnt vmcnt(0)" ::: "memory");
    __builtin_amdgcn_s_barrier();
    __builtin_amdgcn_sched_barrier(0);

    const unsigned short* sA = smem + cur * 16384;
    const unsigned short* sB = sA + 8192;
    int nxt = cur + 2;
    if (nxt >= 3) nxt -= 3;
    unsigned short* nbase = smem + nxt * 16384;
    const bool more = (t + 2) < nk;
    const int kn = (t + 2) << 5;

    // entry reads: all B frags + phase-0 A frags (exposed latency, once per tile)
    f16x8 b0 = *(const f16x8*)&sB[boff];
    f16x8 b1 = *(const f16x8*)&sB[boff + 512];
    f16x8 b2 = *(const f16x8*)&sB[boff + 1024];
    f16x8 b3 = *(const f16x8*)&sB[boff + 1536];
    f16x8 p0a = *(const f16x8*)&sA[aoff];
    f16x8 p0b = *(const f16x8*)&sA[aoff + 512];

    // ---- phase 0: prefetch phase-1 frags; issue next A; MFMA phase-0 ----
    f16x8 p1a = *(const f16x8*)&sA[aoff + 1024];
    f16x8 p1b = *(const f16x8*)&sA[aoff + 1536];
    if (more) {
      gld16(gA0 + kn, nbase + lw);
      gld16(gA1 + kn, nbase + 4096 + lw);
    }
    __builtin_amdgcn_sched_barrier(0);
    __builtin_amdgcn_s_setprio(1);
    acc[0][0] = MFMA16(p0a, b0, acc[0][0]);
    acc[0][1] = MFMA16(p0a, b1, acc[0][1]);
    acc[0][2] = MFMA16(p0a, b2, acc[0][2]);
    acc[0][3] = MFMA16(p0a, b3, acc[0][3]);
    acc[1][0] = MFMA16(p0b, b0, acc[1][0]);
    acc[1][1] = MFMA16(p0b, b1, acc[1][1]);
    acc[1][2] = MFMA16(p0b, b2, acc[1][2]);
    acc[1][3] = MFMA16(p0b, b3, acc[1][3]);
    __builtin_amdgcn_s_setprio(0);
    __builtin_amdgcn_sched_barrier(0);

    // ---- phase 1: prefetch phase-2 frags; issue next B; MFMA phase-1 ----
    f16x8 p2a = *(const f16x8*)&sA[aoff + 2048];
    f16x8 p2b = *(const f16x8*)&sA[aoff + 2560];
    if (more) {
      gld16(gB0 + kn, nbase + 8192 + lw);
      gld16(gB1 + kn, nbase + 12288 + lw);
    }
    __builtin_amdgcn_sched_barrier(0);
    __builtin_amdgcn_s_setprio(1);
    acc[2][0] = MFMA16(p1a, b0, acc[2][0]);
    acc[2][1] = MFMA16(p1a, b1, acc[2][1]);
    acc[2][2] = MFMA16(p1a, b2, acc[2][2]);
    acc[2][3] = MFMA16(p1a, b3, acc[2][3]);
    acc[3][0] = MFMA16(p1b, b0, acc[3][0]);
    acc[3][1] = MFMA16(p1b, b1, acc[3][1]);
    acc[3][2] = MFMA16(p1b, b2, acc[3][2]);
    acc[3][3] = MFMA16(p1b, b3, acc[3][3]);
    __builtin_amdgcn_s_setprio(0);
    __builtin_amdgcn_sched_barrier(0);

    // ---- phase 2: prefetch phase-3 frags; MFMA phase-2 ----
    f16x8 p3a = *(const f16x8*)&sA[aoff + 3072];
    f16x8 p3b = *(const f16x8*)&sA[aoff + 3584];
    __builtin_amdgcn_sched_barrier(0);
    __builtin_amdgcn_s_setprio(1);
    acc[4][0] = MFMA16(p2a, b0, acc[4][0]);
    acc[4][1] = MFMA16(p2a, b1, acc[4][1]);
    acc[4][2] = MFMA16(p2a, b2, acc[4][2]);
    acc[4][3] = MFMA16(p2a, b3, acc[4][3]);
    acc[5][0] = MFMA16(p2b, b0, acc[5][0]);
    acc[5][1] = MFMA16(p2b, b1, acc[5][1]);
    acc[5][2] = MFMA16(p2b, b2, acc[5][2]);
    acc[5][3] = MFMA16(p2b, b3, acc[5][3]);
    __builtin_amdgcn_s_setprio(0);
    __builtin_amdgcn_sched_barrier(0);

    // ---- phase 3: MFMA phase-3 ----
    __builtin_amdgcn_s_setprio(1);
    acc[6][0] = MFMA16(p3a, b0, acc[6][0]);
    acc[6][1] = MFMA16(p3a, b1, acc[6][1]);
    acc[6][2] = MFMA16(p3a, b2, acc[6][2]);
    acc[6][3] = MFMA16(p3a, b3, acc[6][3]);
    acc[7][0] = MFMA16(p3b, b0, acc[7][0]);
    acc[7][1] = MFMA16(p3b, b1, acc[7][1]);
    acc[7][2] = MFMA16(p3b, b2, acc[7][2]);
    acc[7][3] = MFMA16(p3b, b3, acc[7][3]);
    __builtin_amdgcn_s_setprio(0);
    __builtin_amdgcn_sched_barrier(0);

    cur += 1;
    if (cur >= 3) cur -= 3;
  }

  // epilogue; frag: D[row=fc*4+i][col=fr]
  if constexpr (EPI == 5) {
    unsigned short* Ch = (unsigned short*)Cv;
    const int Nh = N >> 1;
#pragma unroll
    for (int mi = 0; mi < 8; ++mi) {
#pragma unroll
      for (int p = 0; p < 2; ++p) {
        const int hcol = (((n0 + wc * 64) >> 5) + p) * 16 + fr;
        const int mb = m0 + wr * 128 + mi * 16 + fc * 4;
#pragma unroll
        for (int i = 0; i < 4; ++i) {
          const int m = mb + i;
          float v1 = acc[mi][2 * p][i];
          float v3 = acc[mi][2 * p + 1][i];
          float y = v1 / (1.f + __expf(-v1)) * v3;
          Ch[(size_t)m * Nh + hcol] = f2h(y);
        }
      }
    }
  } else {
    unsigned short* Ch = (unsigned short*)Cv;
#pragma unroll
    for (int mi = 0; mi < 8; ++mi) {
#pragma unroll
      for (int ni = 0; ni < 4; ++ni) {
        const int n = n0 + wc * 64 + ni * 16 + fr;
        const int mb = m0 + wr * 128 + mi * 16 + fc * 4;
#pragma unroll
        for (int i = 0; i < 4; ++i) {
          const int m = mb + i;
          float v = acc[mi][ni][i];
          if (bias) v += bias[n];
          Ch[(size_t)m * N + n] = f2h(v);
        }
      }
    }
  }
}

// ---------------- host ----------------

extern "C" void kernel_launch(void* const* d_in, const int* in_sizes, int n_in,
                              void* d_out, int out_size, void* d_ws, size_t ws_size,
                              hipStream_t stream) {
  (void)in_sizes; (void)n_in; (void)out_size; (void)ws_size;
  const float* hs = (const float*)d_in[0];
  const float* temb = (const float*)d_in[1];
  const float* rope = (const float*)d_in[2];
  const float* adaw = (const float*)d_in[3];
  const float* adab = (const float*)d_in[4];
  const float* qkvw = (const float*)d_in[5];
  const float* qkvb = (const float*)d_in[6];
  const float* qnw = (const float*)d_in[7];
  const float* knw = (const float*)d_in[8];
  const float* outw = (const float*)d_in[9];
  const float* outb = (const float*)d_in[10];
  const float* gatew = (const float*)d_in[11];
  const float* ew1 = (const float*)d_in[12];
  const float* ew2 = (const float*)d_in[13];
  const float* ew3 = (const float*)d_in[14];
  const float* sw1 = (const float*)d_in[15];
  const float* sw2 = (const float*)d_in[16];
  const float* sw3 = (const float*)d_in[17];
  float* out = (float*)d_out;
  char* ws = (char*)d_ws;

  size_t off = 0;
  auto give = [&](size_t nbytes) {
    size_t r = off;
    off += (nbytes + 255) & ~(size_t)255;
    return r;
  };
  const size_t T = T_TOK, D = DIM;
  size_t o_mod = give(15360 * 4);
  size_t o_ss = give(D * 4);
  size_t o_wd = give(T * 4 * 4);
  size_t o_idx = give(MPAD * 4);
  size_t o_seg = give(8 * 4);
  size_t o_slot = give(T * 2 * 4);
  size_t o_wab = give(T * 2 * 4);
  size_t o_nh = give(T * D * 2);      // nh fp16; later nh2
  size_t o_qkvh = give(T * 7680 * 2); // qkv fp16; region later reused as hmid
  size_t o_qh = give(T * D * 2);
  size_t o_kh = give(T * D * 2);
  size_t o_vt = give(T * D * 2);
  size_t o_obf = give(T * D * 2);
  size_t o_h2 = give(T * D * 4);
  size_t o_yc = give((size_t)MPAD * D * 2);       // compact expert outputs fp16
  size_t o_hmid2 = give(T * SHID_E * 2);          // shared-expert mid
  // fp16 weights
  size_t o_qkvw = give((size_t)7680 * 2560 * 2);
  size_t o_outw = give((size_t)2560 * 2560 * 2);
  size_t o_ewA = give((size_t)4 * 2 * HID_E * 2560 * 2);  // interleaved w1/w3
  size_t o_ew2 = give((size_t)4 * 2560 * HID_E * 2);
  size_t o_swA = give((size_t)2 * SHID_E * 2560 * 2);     // interleaved sw1/sw3
  size_t o_sw2 = give((size_t)2560 * SHID_E * 2);

  float* mod = (float*)(ws + o_mod);
  float* ss = (float*)(ws + o_ss);
  float* wd = (float*)(ws + o_wd);
  int* idxb = (int*)(ws + o_idx);
  int* segp = (int*)(ws + o_seg);
  int* slotAB = (int*)(ws + o_slot);
  float* wAB = (float*)(ws + o_wab);
  unsigned short* nh_h = (unsigned short*)(ws + o_nh);
  unsigned short* qkvh = (unsigned short*)(ws + o_qkvh);
  unsigned short* qh = (unsigned short*)(ws + o_qh);
  unsigned short* kh = (unsigned short*)(ws + o_kh);
  unsigned short* vt = (unsigned short*)(ws + o_vt);
  unsigned short* obf = (unsigned short*)(ws + o_obf);
  float* h2 = (float*)(ws + o_h2);
  unsigned short* yc = (unsigned short*)(ws + o_yc);
  unsigned short* hmid2 = (unsigned short*)(ws + o_hmid2);
  unsigned short* qkvw_h = (unsigned short*)(ws + o_qkvw);
  unsigned short* outw_h = (unsigned short*)(ws + o_outw);
  unsigned short* ewA_h = (unsigned short*)(ws + o_ewA);
  unsigned short* ew2_h = (unsigned short*)(ws + o_ew2);
  unsigned short* swA_h = (unsigned short*)(ws + o_swA);
  unsigned short* sw2_h = (unsigned short*)(ws + o_sw2);
  unsigned short* nh2 = nh_h;
  // hmid (MPAD x 6912 fp16 = 70.8 MB) aliases qkvh..obf (73.4 MB), dead after out-proj
  unsigned short* hmid = qkvh;

  // 0) weight conversion f32 -> fp16 (+ w1/w3 interleave for fused swiglu)
  cvt_f16<<<2048, 256, 0, stream>>>(qkvw, qkvw_h, 7680 * 2560 / 8);
  cvt_f16<<<2048, 256, 0, stream>>>(outw, outw_h, 2560 * 2560 / 8);
  cvt_f16<<<2048, 256, 0, stream>>>(ew2, ew2_h, 4 * 2560 * HID_E / 8);
  cvt_f16<<<2048, 256, 0, stream>>>(sw2, sw2_h, 2560 * SHID_E / 8);
  for (int e = 0; e < 4; ++e) {
    cvt_pair<<<2 * HID_E, 256, 0, stream>>>(ew1 + (size_t)e * HID_E * DIM,
                                            ew3 + (size_t)e * HID_E * DIM,
                                            ewA_h + (size_t)e * 2 * HID_E * DIM);
  }
  cvt_pair<<<2 * SHID_E, 256, 0, stream>>>(sw1, sw3, swA_h);
  // 1) adaLN modulation
  silu_k<<<10, 256, 0, stream>>>(temb, ss);
  adaln_gemv<<<3840, 256, 0, stream>>>(ss, adaw, adab, mod);
  // 2) LN1 + modulate (fp16)
  ln_mod<<<T, 256, 0, stream>>>(hs, mod, mod + D, nh_h);
  // 3) qkv GEMM -> fp16 (256-tile)
  gemm256<4, 0><<<240, 512, 0, stream>>>(nh_h, qkvw_h, qkvb, qkvh,
                                         nullptr, nullptr, 2048, 7680, 2560);
  // 4) RMSNorm + RoPE
  rmsrope<<<T, 256, 0, stream>>>(qkvh, qnw, knw, rope, qh, kh);
  // 5) V transpose
  transpose_v<<<dim3(80, 64), dim3(32, 8), 0, stream>>>(qkvh, vt);
  // 6) MFMA flash attention
  fattn<<<dim3(32, 20), 256, 0, stream>>>(qh, kh, vt, obf);
  // 7) out proj + gate_msa residual -> h2 f32
  gemm128<1, 0><<<16 * 20, 256, 0, stream>>>(obf, outw_h, outb, h2,
                                             mod + 2 * D, hs, nullptr, nullptr,
                                             nullptr, nullptr, nullptr, 2048, 2560, 2560);
  // 8) LN2 + modulate + routing, then concatenated 256-padded compaction
  ln2_route<<<T, 256, 0, stream>>>(h2, mod + 3 * D, mod + 4 * D, gatew, nh2, wd);
  route_compact<<<1, 256, 0, stream>>>(wd, idxb, segp, slotAB, wAB);
  // 9) MoE experts: fused w1w3+swiglu 256-tile GEMM + w2 256-tile GEMM
  gemm256<5, 1><<<20 * 54, 512, 0, stream>>>(nh2, ewA_h, nullptr, hmid,
                                             idxb, segp, MPAD, 2 * HID_E, 2560);
  gemm256<4, 2><<<20 * 10, 512, 0, stream>>>(hmid, ew2_h, nullptr, yc,
                                             nullptr, segp, MPAD, 2560, 6912);
  // 10) shared expert (256-tile fused w1w3+swiglu) + final combine w/ yc gather
  gemm256<5, 0><<<8 * 28, 512, 0, stream>>>(nh2, swA_h, nullptr, hmid2,
                                            nullptr, nullptr, 2048, 2 * SHID_E, 2560);
  gemm128<6, 0><<<16 * 20, 256, 0, stream>>>(hmid2, sw2_h, nullptr, out,
                                             mod + 5 * D, h2, nullptr, nullptr,
                                             slotAB, wAB, yc, 2048, 2560, 3584);
}